// Round 1
// 1864.914 us; speedup vs baseline: 1.0365x; 1.0365x over previous
//
#include <hip/hip_runtime.h>

typedef __attribute__((ext_vector_type(8))) short bf16x8;
typedef __attribute__((ext_vector_type(4))) float f32x4;

#define DEV __device__ __forceinline__
#define MF(A, B, CACC) CACC = __builtin_amdgcn_mfma_f32_16x16x32_bf16(A, B, CACC, 0, 0, 0)

DEV ushort f2b(float f) {
  unsigned u = __float_as_uint(f);
  u += 0x7fffu + ((u >> 16) & 1u);   // RNE to bf16
  return (ushort)(u >> 16);
}
DEV float b2f(ushort u) { return __uint_as_float(((unsigned)u) << 16); }

// async global->LDS, 16B per lane; lds base must be wave-uniform (HW adds lane*16)
DEV void gl_lds16(ushort* lds_base, const ushort* gp) {
  __builtin_amdgcn_global_load_lds(
      (__attribute__((address_space(1))) const void*)gp,
      (__attribute__((address_space(3))) void*)lds_base, 16, 0, 0);
}

// ---------------- zero scalar slots ----------------
__global__ void k_zero(unsigned* p, int n) {
  int i = blockIdx.x * blockDim.x + threadIdx.x;
  if (i < n) p[i] = 0u;
}

// ------------- weight transpose fp32 W[K][N] -> bf16 WT[N][K] -------------
__global__ __launch_bounds__(256) void k_wt(const float* __restrict__ W,
                                            ushort* __restrict__ WT, int K, int N) {
  __shared__ float T[32][33];
  int k0 = blockIdx.y * 32, n0 = blockIdx.x * 32;
  int tx = threadIdx.x & 31, ty = threadIdx.x >> 5;
  #pragma unroll
  for (int r = ty; r < 32; r += 8) {
    int k = k0 + r, n = n0 + tx;
    T[r][tx] = (k < K && n < N) ? W[(size_t)k * N + n] : 0.f;
  }
  __syncthreads();
  #pragma unroll
  for (int r = ty; r < 32; r += 8) {
    int n = n0 + r, k = k0 + tx;
    if (n < N && k < K) WT[(size_t)n * K + k] = f2b(T[tx][r]);
  }
}

// ---------------- f32 -> bf16 elementwise ----------------
__global__ void k_cvt(const float* __restrict__ in, ushort* __restrict__ out, int n) {
  int i = blockIdx.x * 256 + threadIdx.x;
  if (i < n) out[i] = f2b(in[i]);
}

// ---------------- layernorm (C==1280), out bf16 ----------------
__global__ __launch_bounds__(256) void k_ln(const float* __restrict__ x,
    const float* __restrict__ g, const float* __restrict__ b,
    ushort* __restrict__ out) {
  const int C = 1280;
  int row = blockIdx.x, tid = threadIdx.x;
  const float* xr = x + (size_t)row * C;
  float v0 = xr[tid], v1 = xr[tid + 256], v2 = xr[tid + 512],
        v3 = xr[tid + 768], v4 = xr[tid + 1024];
  float s = v0 + v1 + v2 + v3 + v4;
  float ss = v0 * v0 + v1 * v1 + v2 * v2 + v3 * v3 + v4 * v4;
  #pragma unroll
  for (int off = 32; off; off >>= 1) {
    s += __shfl_down(s, off);
    ss += __shfl_down(ss, off);
  }
  __shared__ float red[8];
  __shared__ float mu_s, rstd_s;
  int wave = tid >> 6, lane = tid & 63;
  if (lane == 0) { red[wave] = s; red[4 + wave] = ss; }
  __syncthreads();
  if (tid == 0) {
    float S = red[0] + red[1] + red[2] + red[3];
    float SS = red[4] + red[5] + red[6] + red[7];
    float mu = S / C;
    float var = SS / C - mu * mu;
    mu_s = mu;
    rstd_s = rsqrtf(var + 1e-5f);
  }
  __syncthreads();
  float mu = mu_s, rstd = rstd_s;
  size_t o = (size_t)row * C + tid;
  out[o]        = f2b((v0 - mu) * rstd * g[tid]        + b[tid]);
  out[o + 256]  = f2b((v1 - mu) * rstd * g[tid + 256]  + b[tid + 256]);
  out[o + 512]  = f2b((v2 - mu) * rstd * g[tid + 512]  + b[tid + 512]);
  out[o + 768]  = f2b((v3 - mu) * rstd * g[tid + 768]  + b[tid + 768]);
  out[o + 1024] = f2b((v4 - mu) * rstd * g[tid + 1024] + b[tid + 1024]);
}

// ---- GEMM epilogue helpers (by-value f32x4, constant swizzles: SROA-proof) ----
DEV void st1(float v, int r_, int c_, int ldc, const float* resid,
             float* Cf, ushort* Cb) {
  size_t o = (size_t)r_ * ldc + c_;
  if (resid) v += resid[o];
  if (Cf) Cf[o] = v;
  if (Cb) Cb[o] = f2b(v);
}
DEV float epi4(f32x4 v, int rbase, int c_, int M, int N, int ldc,
               const float* bias, const float* resid, float* Cf, ushort* Cb) {
  float v0 = v.x, v1 = v.y, v2 = v.z, v3 = v.w;
  float am = fmaxf(fmaxf(fabsf(v0), fabsf(v1)), fmaxf(fabsf(v2), fabsf(v3)));
  if (c_ < N) {
    float bb = bias ? bias[c_] : 0.f;
    v0 += bb; v1 += bb; v2 += bb; v3 += bb;
    if (rbase + 0 < M) st1(v0, rbase + 0, c_, ldc, resid, Cf, Cb);
    if (rbase + 1 < M) st1(v1, rbase + 1, c_, ldc, resid, Cf, Cb);
    if (rbase + 2 < M) st1(v2, rbase + 2, c_, ldc, resid, Cf, Cb);
    if (rbase + 3 < M) st1(v3, rbase + 3, c_, ldc, resid, Cf, Cb);
  }
  return am;
}

// ---------------- bf16 NT GEMM: C[M,N] = A[M,K] @ BT[N,K]^T ----------------
// 128x128 tile, 4 waves (2x2 of 64x64), 16x16x32 MFMA, BK=32,
// global_load_lds width=16 staging, NAMED scalar accumulators (no reg arrays).
__global__ __launch_bounds__(256) void k_gemm(
    const ushort* __restrict__ A, int lda,
    const ushort* __restrict__ BT, int ldb,
    float* __restrict__ Cf, ushort* __restrict__ Cb, int ldc,
    const float* __restrict__ bias, const float* __restrict__ resid,
    unsigned* am_slot, int M, int N, int K) {
  __shared__ __align__(16) ushort SAB[8192];  // A[128][32] @0, B[128][32] @4096
  int tid = threadIdx.x;
  int wave = tid >> 6, lane = tid & 63;
  int q = lane >> 4, mi = lane & 15;
  int wr = (wave >> 1) * 64, wc = (wave & 1) * 64;
  int bm0 = blockIdx.y * 128, bn0 = blockIdx.x * 128;
  f32x4 c00 = {}, c01 = {}, c02 = {}, c03 = {};
  f32x4 c10 = {}, c11 = {}, c12 = {}, c13 = {};
  f32x4 c20 = {}, c21 = {}, c22 = {}, c23 = {};
  f32x4 c30 = {}, c31 = {}, c32 = {}, c33 = {};
  for (int k0 = 0; k0 < K; k0 += 32) {
    __syncthreads();
    #pragma unroll
    for (int t = 0; t < 4; t++) {
      int c = wave * 256 + t * 64 + lane;
      const ushort* gp;
      if (c < 512) {
        int r = c >> 2, kc = (c & 3) << 3;
        int gr = bm0 + r; if (gr >= M) gr = M - 1;
        gp = A + (size_t)gr * lda + k0 + kc;
      } else {
        int c2 = c - 512;
        int r = c2 >> 2, kc = (c2 & 3) << 3;
        int gn = bn0 + r; if (gn >= N) gn = N - 1;
        gp = BT + (size_t)gn * ldb + k0 + kc;
      }
      gl_lds16(&SAB[(wave * 256 + t * 64) * 8], gp);
    }
    __syncthreads();
    const ushort* Ab = &SAB[(wr + mi) * 32 + q * 8];
    const ushort* Bb = &SAB[4096 + (wc + mi) * 32 + q * 8];
    bf16x8 a0 = *(const bf16x8*)(Ab);
    bf16x8 a1 = *(const bf16x8*)(Ab + 512);
    bf16x8 a2 = *(const bf16x8*)(Ab + 1024);
    bf16x8 a3 = *(const bf16x8*)(Ab + 1536);
    bf16x8 b0 = *(const bf16x8*)(Bb);
    bf16x8 b1 = *(const bf16x8*)(Bb + 512);
    bf16x8 b2 = *(const bf16x8*)(Bb + 1024);
    bf16x8 b3 = *(const bf16x8*)(Bb + 1536);
    MF(a0, b0, c00); MF(a0, b1, c01); MF(a0, b2, c02); MF(a0, b3, c03);
    MF(a1, b0, c10); MF(a1, b1, c11); MF(a1, b2, c12); MF(a1, b3, c13);
    MF(a2, b0, c20); MF(a2, b1, c21); MF(a2, b2, c22); MF(a2, b3, c23);
    MF(a3, b0, c30); MF(a3, b1, c31); MF(a3, b2, c32); MF(a3, b3, c33);
  }
  int rb = bm0 + wr + q * 4, cb = bn0 + wc + mi;
  float am = 0.f;
  am = fmaxf(am, epi4(c00, rb +  0, cb +  0, M, N, ldc, bias, resid, Cf, Cb));
  am = fmaxf(am, epi4(c01, rb +  0, cb + 16, M, N, ldc, bias, resid, Cf, Cb));
  am = fmaxf(am, epi4(c02, rb +  0, cb + 32, M, N, ldc, bias, resid, Cf, Cb));
  am = fmaxf(am, epi4(c03, rb +  0, cb + 48, M, N, ldc, bias, resid, Cf, Cb));
  am = fmaxf(am, epi4(c10, rb + 16, cb +  0, M, N, ldc, bias, resid, Cf, Cb));
  am = fmaxf(am, epi4(c11, rb + 16, cb + 16, M, N, ldc, bias, resid, Cf, Cb));
  am = fmaxf(am, epi4(c12, rb + 16, cb + 32, M, N, ldc, bias, resid, Cf, Cb));
  am = fmaxf(am, epi4(c13, rb + 16, cb + 48, M, N, ldc, bias, resid, Cf, Cb));
  am = fmaxf(am, epi4(c20, rb + 32, cb +  0, M, N, ldc, bias, resid, Cf, Cb));
  am = fmaxf(am, epi4(c21, rb + 32, cb + 16, M, N, ldc, bias, resid, Cf, Cb));
  am = fmaxf(am, epi4(c22, rb + 32, cb + 32, M, N, ldc, bias, resid, Cf, Cb));
  am = fmaxf(am, epi4(c23, rb + 32, cb + 48, M, N, ldc, bias, resid, Cf, Cb));
  am = fmaxf(am, epi4(c30, rb + 48, cb +  0, M, N, ldc, bias, resid, Cf, Cb));
  am = fmaxf(am, epi4(c31, rb + 48, cb + 16, M, N, ldc, bias, resid, Cf, Cb));
  am = fmaxf(am, epi4(c32, rb + 48, cb + 32, M, N, ldc, bias, resid, Cf, Cb));
  am = fmaxf(am, epi4(c33, rb + 48, cb + 48, M, N, ldc, bias, resid, Cf, Cb));
  if (am_slot) {
    #pragma unroll
    for (int off = 32; off; off >>= 1) am = fmaxf(am, __shfl_down(am, off));
    if (lane == 0) atomicMax(am_slot, __float_as_uint(am));
  }
}

// ---------------- symmetric fake-quant, in-place on bf16 ----------------
__global__ void k_quant(const ushort* __restrict__ in, ushort* __restrict__ out,
                        const unsigned* __restrict__ slot, int n) {
  int i = blockIdx.x * 256 + threadIdx.x;
  if (i >= n) return;
  float delta = fmaxf(__uint_as_float(*slot), 1e-8f) * (1.f / 127.f);
  float x = b2f(in[i]);
  float y = fminf(fmaxf(rintf(x / delta), -128.f), 127.f) * delta;
  out[i] = f2b(y);
}

// ------- V transpose per head: vq[b*Mr+m][h*64+d] -> vT[bh][d][m] (zero-pad) -------
__global__ __launch_bounds__(256) void k_vt(const ushort* __restrict__ vq,
    ushort* __restrict__ vT, int H, int Mr, int Mpad) {
  const int C = 1280;
  __shared__ __align__(16) ushort T[64][72];
  int bh = blockIdx.y, b = bh / H, h = bh % H;
  int m0 = blockIdx.x * 64;
  int tid = threadIdx.x;
  #pragma unroll
  for (int c = tid; c < 512; c += 256) {
    int mm = c >> 3, dc = (c & 7) << 3;
    int m = m0 + mm;
    int4 val = make_int4(0, 0, 0, 0);
    if (m < Mr) val = *(const int4*)(vq + ((size_t)b * Mr + m) * C + h * 64 + dc);
    *(int4*)&T[mm][dc] = val;
  }
  __syncthreads();
  #pragma unroll
  for (int c = tid; c < 512; c += 256) {
    int dd = c >> 3, mc = (c & 7) << 3;
    unsigned w0 = (unsigned)T[mc + 0][dd] | ((unsigned)T[mc + 1][dd] << 16);
    unsigned w1 = (unsigned)T[mc + 2][dd] | ((unsigned)T[mc + 3][dd] << 16);
    unsigned w2 = (unsigned)T[mc + 4][dd] | ((unsigned)T[mc + 5][dd] << 16);
    unsigned w3 = (unsigned)T[mc + 6][dd] | ((unsigned)T[mc + 7][dd] << 16);
    int4 val = make_int4((int)w0, (int)w1, (int)w2, (int)w3);
    *(int4*)(vT + ((size_t)bh * 64 + dd) * Mpad + m0 + mc) = val;
  }
}

// ------- attention phase 1: per-row smax & Z, global max(1/Z) -> pmax -------
__global__ __launch_bounds__(256) void k_attn1(
    const ushort* __restrict__ qq, const ushort* __restrict__ kq,
    float2* __restrict__ rs, unsigned* __restrict__ pmax,
    int H, int N, int Mr, float scale) {
  const int C = 1280;
  __shared__ __align__(16) ushort Qs[64][72];
  __shared__ __align__(16) ushort Ks[64][72];
  __shared__ float Ss[64][68];
  __shared__ float mq4[64][4], zq4[64][4];
  int tid = threadIdx.x;
  int wave = tid >> 6, lane = tid & 63;
  int q = lane >> 4, mi = lane & 15;
  int bh = blockIdx.y, b = bh / H, h = bh % H;
  int r0 = blockIdx.x * 64;
  #pragma unroll
  for (int c = tid; c < 512; c += 256) {
    int r = c >> 3, dc = (c & 7) << 3;
    *(int4*)&Qs[r][dc] = *(const int4*)(qq + ((size_t)b * N + r0 + r) * C + h * 64 + dc);
  }
  float m_run = -1e30f, z_run = 0.f;
  int row = tid >> 2, qt = tid & 3;
  int nt = (Mr + 63) >> 6;
  for (int mt = 0; mt < nt; mt++) {
    __syncthreads();
    #pragma unroll
    for (int c = tid; c < 512; c += 256) {
      int mm = c >> 3, dc = (c & 7) << 3;
      int m = mt * 64 + mm;
      int4 val = make_int4(0, 0, 0, 0);
      if (m < Mr) val = *(const int4*)(kq + ((size_t)b * Mr + m) * C + h * 64 + dc);
      *(int4*)&Ks[mm][dc] = val;
    }
    __syncthreads();
    f32x4 s0 = {}, s1 = {}, s2 = {}, s3 = {};
    #pragma unroll
    for (int kc = 0; kc < 2; kc++) {
      bf16x8 aq = *(const bf16x8*)&Qs[wave * 16 + mi][kc * 32 + q * 8];
      bf16x8 k0v = *(const bf16x8*)&Ks[mi][kc * 32 + q * 8];
      bf16x8 k1v = *(const bf16x8*)&Ks[16 + mi][kc * 32 + q * 8];
      bf16x8 k2v = *(const bf16x8*)&Ks[32 + mi][kc * 32 + q * 8];
      bf16x8 k3v = *(const bf16x8*)&Ks[48 + mi][kc * 32 + q * 8];
      MF(aq, k0v, s0); MF(aq, k1v, s1); MF(aq, k2v, s2); MF(aq, k3v, s3);
    }
    int rr = wave * 16 + q * 4;
    Ss[rr + 0][mi]      = s0.x * scale; Ss[rr + 1][mi]      = s0.y * scale;
    Ss[rr + 2][mi]      = s0.z * scale; Ss[rr + 3][mi]      = s0.w * scale;
    Ss[rr + 0][16 + mi] = s1.x * scale; Ss[rr + 1][16 + mi] = s1.y * scale;
    Ss[rr + 2][16 + mi] = s1.z * scale; Ss[rr + 3][16 + mi] = s1.w * scale;
    Ss[rr + 0][32 + mi] = s2.x * scale; Ss[rr + 1][32 + mi] = s2.y * scale;
    Ss[rr + 2][32 + mi] = s2.z * scale; Ss[rr + 3][32 + mi] = s2.w * scale;
    Ss[rr + 0][48 + mi] = s3.x * scale; Ss[rr + 1][48 + mi] = s3.y * scale;
    Ss[rr + 2][48 + mi] = s3.z * scale; Ss[rr + 3][48 + mi] = s3.w * scale;
    __syncthreads();
    #pragma unroll
    for (int cc = 0; cc < 16; cc++) {
      int col = qt * 16 + cc;
      int mg = mt * 64 + col;
      if (mg < Mr) {
        float sv = Ss[row][col];
        if (sv <= m_run) {
          z_run += __expf(sv - m_run);
        } else {
          z_run = z_run * __expf(m_run - sv) + 1.f;
          m_run = sv;
        }
      }
    }
  }
  __syncthreads();
  mq4[row][qt] = m_run; zq4[row][qt] = z_run;
  __syncthreads();
  if (tid < 64) {
    float M0 = mq4[tid][0], M1 = mq4[tid][1], M2 = mq4[tid][2], M3 = mq4[tid][3];
    float M_ = fmaxf(fmaxf(M0, M1), fmaxf(M2, M3));
    float Z = zq4[tid][0] * __expf(M0 - M_) + zq4[tid][1] * __expf(M1 - M_) +
              zq4[tid][2] * __expf(M2 - M_) + zq4[tid][3] * __expf(M3 - M_);
    float2 st; st.x = M_; st.y = Z;
    rs[(size_t)bh * N + r0 + tid] = st;
    float pm = 1.f / Z;
    #pragma unroll
    for (int off = 32; off; off >>= 1) pm = fmaxf(pm, __shfl_down(pm, off));
    if (tid == 0) atomicMax(pmax, __float_as_uint(pm));
  }
}

// ------- attention phase 2: recompute S, quantize probs, P@V -> ao (bf16) -------
__global__ __launch_bounds__(256) void k_attn2(
    const ushort* __restrict__ qq, const ushort* __restrict__ kq,
    const ushort* __restrict__ vT, const float2* __restrict__ rs,
    const unsigned* __restrict__ pmax, ushort* __restrict__ ao,
    int H, int N, int Mr, int Mpad, float scale) {
  const int C = 1280;
  __shared__ __align__(16) ushort Qs[64][72];
  __shared__ __align__(16) ushort Ks[64][72];
  __shared__ __align__(16) ushort Vs[64][72];
  __shared__ __align__(16) ushort Ps[64][72];
  __shared__ float Ss[64][68];
  int tid = threadIdx.x;
  int wave = tid >> 6, lane = tid & 63;
  int q = lane >> 4, mi = lane & 15;
  int bh = blockIdx.y, b = bh / H, h = bh % H;
  int r0 = blockIdx.x * 64;
  #pragma unroll
  for (int c = tid; c < 512; c += 256) {
    int r = c >> 3, dc = (c & 7) << 3;
    *(int4*)&Qs[r][dc] = *(const int4*)(qq + ((size_t)b * N + r0 + r) * C + h * 64 + dc);
  }
  int row = tid >> 2, qt = tid & 3;
  float2 st = rs[(size_t)bh * N + r0 + row];
  float delta = fmaxf(__uint_as_float(*pmax), 1e-8f) * (1.f / 255.f);
  float invd = 1.f / delta;
  f32x4 o0 = {}, o1 = {}, o2 = {}, o3 = {};
  int nt = (Mr + 63) >> 6;
  for (int mt = 0; mt < nt; mt++) {
    __syncthreads();
    #pragma unroll
    for (int c = tid; c < 512; c += 256) {
      int mm = c >> 3, dc = (c & 7) << 3;
      int m = mt * 64 + mm;
      int4 val = make_int4(0, 0, 0, 0);
      if (m < Mr) val = *(const int4*)(kq + ((size_t)b * Mr + m) * C + h * 64 + dc);
      *(int4*)&Ks[mm][dc] = val;
      *(int4*)&Vs[mm][dc] = *(const int4*)(vT + ((size_t)bh * 64 + mm) * Mpad + mt * 64 + dc);
    }
    __syncthreads();
    f32x4 s0 = {}, s1 = {}, s2 = {}, s3 = {};
    #pragma unroll
    for (int kc = 0; kc < 2; kc++) {
      bf16x8 aq = *(const bf16x8*)&Qs[wave * 16 + mi][kc * 32 + q * 8];
      bf16x8 k0v = *(const bf16x8*)&Ks[mi][kc * 32 + q * 8];
      bf16x8 k1v = *(const bf16x8*)&Ks[16 + mi][kc * 32 + q * 8];
      bf16x8 k2v = *(const bf16x8*)&Ks[32 + mi][kc * 32 + q * 8];
      bf16x8 k3v = *(const bf16x8*)&Ks[48 + mi][kc * 32 + q * 8];
      MF(aq, k0v, s0); MF(aq, k1v, s1); MF(aq, k2v, s2); MF(aq, k3v, s3);
    }
    int rr = wave * 16 + q * 4;
    Ss[rr + 0][mi]      = s0.x * scale; Ss[rr + 1][mi]      = s0.y * scale;
    Ss[rr + 2][mi]      = s0.z * scale; Ss[rr + 3][mi]      = s0.w * scale;
    Ss[rr + 0][16 + mi] = s1.x * scale; Ss[rr + 1][16 + mi] = s1.y * scale;
    Ss[rr + 2][16 + mi] = s1.z * scale; Ss[rr + 3][16 + mi] = s1.w * scale;
    Ss[rr + 0][32 + mi] = s2.x * scale; Ss[rr + 1][32 + mi] = s2.y * scale;
    Ss[rr + 2][32 + mi] = s2.z * scale; Ss[rr + 3][32 + mi] = s2.w * scale;
    Ss[rr + 0][48 + mi] = s3.x * scale; Ss[rr + 1][48 + mi] = s3.y * scale;
    Ss[rr + 2][48 + mi] = s3.z * scale; Ss[rr + 3][48 + mi] = s3.w * scale;
    __syncthreads();
    #pragma unroll
    for (int cc = 0; cc < 16; cc++) {
      int col = qt * 16 + cc;
      int mg = mt * 64 + col;
      float p = 0.f;
      if (mg < Mr) {
        float sv = Ss[row][col];
        p = __expf(sv - st.x) / st.y;
        p = fminf(rintf(p * invd), 255.f) * delta;
      }
      Ps[row][col] = f2b(p);
    }
    __syncthreads();
    #pragma unroll
    for (int kc = 0; kc < 2; kc++) {
      bf16x8 ap = *(const bf16x8*)&Ps[wave * 16 + mi][kc * 32 + q * 8];
      bf16x8 v0 = *(const bf16x8*)&Vs[mi][kc * 32 + q * 8];
      bf16x8 v1 = *(const bf16x8*)&Vs[16 + mi][kc * 32 + q * 8];
      bf16x8 v2 = *(const bf16x8*)&Vs[32 + mi][kc * 32 + q * 8];
      bf16x8 v3 = *(const bf16x8*)&Vs[48 + mi][kc * 32 + q * 8];
      MF(ap, v0, o0); MF(ap, v1, o1); MF(ap, v2, o2); MF(ap, v3, o3);
    }
  }
  int rr = r0 + wave * 16 + q * 4;
  size_t base = ((size_t)b * N + rr) * C + h * 64 + mi;
  ao[base]             = f2b(o0.x); ao[base + C]         = f2b(o0.y);
  ao[base + 2 * C]     = f2b(o0.z); ao[base + 3 * C]     = f2b(o0.w);
  ao[base + 16]        = f2b(o1.x); ao[base + C + 16]    = f2b(o1.y);
  ao[base + 2 * C + 16] = f2b(o1.z); ao[base + 3 * C + 16] = f2b(o1.w);
  ao[base + 32]        = f2b(o2.x); ao[base + C + 32]    = f2b(o2.y);
  ao[base + 2 * C + 32] = f2b(o2.z); ao[base + 3 * C + 32] = f2b(o2.w);
  ao[base + 48]        = f2b(o3.x); ao[base + C + 48]    = f2b(o3.y);
  ao[base + 2 * C + 48] = f2b(o3.z); ao[base + 3 * C + 48] = f2b(o3.w);
}

// =====================================================================
// fused FF1 + GEGLU, 256x128(GG) tile, BK=64, 8 waves, 8-phase schedule
// (T2 xor-swizzle + T3/T4 counted vmcnt + T5 setprio), 128 KiB LDS dbuf.
// GG[r][c] = (A@Wa^T + ba) * gelu(A@Wg^T + bg); Wa=BT rows [0,5120),
// Wg=BT rows [5120,10240). M=8192, K=1280 (20 K-tiles), GGcols=5120.
// =====================================================================
#define BAR __builtin_amdgcn_s_barrier()
#define LGKM0 do { asm volatile("s_waitcnt lgkmcnt(0)" ::: "memory"); \
                   __builtin_amdgcn_sched_barrier(0); } while (0)
#define VM6 asm volatile("s_waitcnt vmcnt(6)" ::: "memory")
#define PRIO1 __builtin_amdgcn_s_setprio(1)
#define PRIO0 __builtin_amdgcn_s_setprio(0)

#define RDA01(P) do { \
  fa00 = *(const bf16x8*)&(P)[c0];        fa01 = *(const bf16x8*)&(P)[c1]; \
  fa10 = *(const bf16x8*)&(P)[1024 + c0]; fa11 = *(const bf16x8*)&(P)[1024 + c1]; } while (0)
#define RDA23(P) do { \
  fa20 = *(const bf16x8*)&(P)[2048 + c0]; fa21 = *(const bf16x8*)&(P)[2048 + c1]; \
  fa30 = *(const bf16x8*)&(P)[3072 + c0]; fa31 = *(const bf16x8*)&(P)[3072 + c1]; } while (0)
#define RDB(P, H) do { \
  b00 = *(const bf16x8*)&(P)[(H) + c0];        b01 = *(const bf16x8*)&(P)[(H) + c1]; \
  b10 = *(const bf16x8*)&(P)[(H) + 1024 + c0]; b11 = *(const bf16x8*)&(P)[(H) + 1024 + c1]; \
  b20 = *(const bf16x8*)&(P)[(H) + 2048 + c0]; b21 = *(const bf16x8*)&(P)[(H) + 2048 + c1]; \
  b30 = *(const bf16x8*)&(P)[(H) + 3072 + c0]; b31 = *(const bf16x8*)&(P)[(H) + 3072 + c1]; } while (0)

#define MM8(AX0, AX1, AY0, AY1, C0, C1, C2, C3, D0, D1, D2, D3) \
  MF(AX0, b00, C0); MF(AX1, b01, C0); MF(AX0, b10, C1); MF(AX1, b11, C1); \
  MF(AX0, b20, C2); MF(AX1, b21, C2); MF(AX0, b30, C3); MF(AX1, b31, C3); \
  MF(AY0, b00, D0); MF(AY1, b01, D0); MF(AY0, b10, D1); MF(AY1, b11, D1); \
  MF(AY0, b20, D2); MF(AY1, b21, D2); MF(AY0, b30, D3); MF(AY1, b31, D3)

// gelu-tanh via sigmoid identity: 0.5*(1+tanh(x)) == sigmoid(2x)
DEV ushort ggel(float a, float g) {
  float u = 1.5957691216057308f * g * (1.f + 0.044715f * g * g);
  float s = 1.f / (1.f + __expf(-u));
  return f2b(a * g * s);
}
DEV void epi4g(f32x4 va, f32x4 vg, size_t base, float ba, float bg,
               ushort* __restrict__ GG) {
  GG[base]         = ggel(va.x + ba, vg.x + bg);
  GG[base + 5120]  = ggel(va.y + ba, vg.y + bg);
  GG[base + 10240] = ggel(va.z + ba, vg.z + bg);
  GG[base + 15360] = ggel(va.w + ba, vg.w + bg);
}
#define EPIN(nn, P0, Q0, P1, Q1, P2, Q2, P3, Q3) do { \
  int cg = colBase + nn * 16 + mi; \
  float ba = bias[cg], bg = bias[5120 + cg]; \
  size_t b0_ = (size_t)rowBase * 5120 + cg; \
  epi4g(P0, Q0, b0_,             ba, bg, GG); \
  epi4g(P1, Q1, b0_ + 16 * 5120, ba, bg, GG); \
  epi4g(P2, Q2, b0_ + 32 * 5120, ba, bg, GG); \
  epi4g(P3, Q3, b0_ + 48 * 5120, ba, bg, GG); \
} while (0)

__global__ __launch_bounds__(512) void k_ff1_8p(
    const ushort* __restrict__ A,    // LN [8192][1280]
    const ushort* __restrict__ BT,   // WF1T [10240][1280]
    const float* __restrict__ bias,  // bff1 [10240]
    ushort* __restrict__ GG) {       // [8192][5120]
  // LDS: buf b at b*32768; A region [256][64] @ +0, B region [256][64] @ +16384
  // (B rows 0-127 = a-half, 128-255 = g-half). Swizzle: elem col ^= (row&7)*8.
  __shared__ __align__(16) ushort SAB[65536];  // 128 KiB
  int tid = threadIdx.x;
  int wave = tid >> 6, lane = tid & 63;
  int q = lane >> 4, mi = lane & 15;
  int wm = wave >> 1, wn = wave & 1;
  int lr = lane >> 3;
  int lc = ((lane & 7) ^ lr) * 8;  // inverse-swizzled source col (elems)

  // XCD-aware swizzle over 1280 blocks (1280 % 8 == 0); bm fastest in chunk
  int wg = blockIdx.x;
  int swz = (wg & 7) * 160 + (wg >> 3);
  int bm0 = (swz & 31) * 256, bn0 = (swz >> 5) * 128;

  const int swzr = (mi & 7) * 8;
  int c0 = (q * 8) ^ swzr, c1 = (32 + q * 8) ^ swzr;
  const ushort* A0p = &SAB[(wm * 64 + mi) * 64];
  const ushort* B0p = &SAB[16384 + (wn * 64 + mi) * 64];
  const ushort* A1p = A0p + 32768;
  const ushort* B1p = B0p + 32768;

  const ushort* gA  = A  + (size_t)(bm0 + wave * 8 + lr) * 1280 + lc;
  const ushort* gBa = BT + (size_t)(bn0 + wave * 8 + lr) * 1280 + lc;
  const ushort* gBg = BT + (size_t)(5120 + bn0 + wave * 8 + lr) * 1280 + lc;
  ushort* lA = &SAB[wave * 512];
  ushort* lB = &SAB[16384 + wave * 512];

  auto stA = [&](int bb, int kt, int call) {  // call 0..3 (64 rows each)
    gl_lds16(lA + bb * 32768 + call * 4096,
             gA + (size_t)call * 81920 + (size_t)kt * 64);
  };
  auto stBa = [&](int bb, int kt, int call) {  // call 0,1 -> B rows 0..127
    gl_lds16(lB + bb * 32768 + call * 4096,
             gBa + (size_t)call * 81920 + (size_t)kt * 64);
  };
  auto stBg = [&](int bb, int kt, int call) {  // call 0,1 -> B rows 128..255
    gl_lds16(lB + bb * 32768 + (call + 2) * 4096,
             gBg + (size_t)call * 81920 + (size_t)kt * 64);
  };

  f32x4 cA00 = {}, cA01 = {}, cA02 = {}, cA03 = {};
  f32x4 cA10 = {}, cA11 = {}, cA12 = {}, cA13 = {};
  f32x4 cA20 = {}, cA21 = {}, cA22 = {}, cA23 = {};
  f32x4 cA30 = {}, cA31 = {}, cA32 = {}, cA33 = {};
  f32x4 cG00 = {}, cG01 = {}, cG02 = {}, cG03 = {};
  f32x4 cG10 = {}, cG11 = {}, cG12 = {}, cG13 = {};
  f32x4 cG20 = {}, cG21 = {}, cG22 = {}, cG23 = {};
  f32x4 cG30 = {}, cG31 = {}, cG32 = {}, cG33 = {};
  bf16x8 fa00, fa01, fa10, fa11, fa20, fa21, fa30, fa31;
  bf16x8 b00, b01, b10, b11, b20, b21, b30, b31;

  // prologue: tile0 fully -> buf0 (8 loads), tile1 Ba+A -> buf1 (6 loads)
  stBa(0, 0, 0); stBa(0, 0, 1); stBg(0, 0, 0); stBg(0, 0, 1);
  stA(0, 0, 0); stA(0, 0, 1); stA(0, 0, 2); stA(0, 0, 3);
  stBa(1, 1, 0); stBa(1, 1, 1);
  stA(1, 1, 0); stA(1, 1, 1); stA(1, 1, 2); stA(1, 1, 3);
  VM6; BAR;

  for (int it = 0; it < 10; ++it) {
    int t1 = 2 * it + 1;
    int s0 = t1 + 1; if (s0 > 19) s0 = 19;
    int s1 = t1 + 2; if (s1 > 19) s1 = 19;
    // ---- P1: buf0 m01 x Ba ----
    RDA01(A0p); RDB(B0p, 0);
    stBg(1, t1, 0); stBg(1, t1, 1);
    BAR; LGKM0;
    PRIO1; MM8(fa00, fa01, fa10, fa11, cA00, cA01, cA02, cA03,
               cA10, cA11, cA12, cA13); PRIO0;
    BAR;
    // ---- P2: buf0 m23 x Ba ----
    RDA23(A0p);
    stBa(0, s0, 0); stBa(0, s0, 1);
    BAR; LGKM0;
    PRIO1; MM8(fa20, fa21, fa30, fa31, cA20, cA21, cA22, cA23,
               cA30, cA31, cA32, cA33); PRIO0;
    BAR;
    // ---- P3: buf0 m01 x Bg ----
    RDB(B0p, 8192);
    stA(0, s0, 0); stA(0, s0, 1);
    BAR; LGKM0;
    PRIO1; MM8(fa00, fa01, fa10, fa11, cG00, cG01, cG02, cG03,
               cG10, cG11, cG12, cG13); PRIO0;
    BAR;
    // ---- P4: buf0 m23 x Bg ----
    stA(0, s0, 2); stA(0, s0, 3);
    BAR;
    PRIO1; MM8(fa20, fa21, fa30, fa31, cG20, cG21, cG22, cG23,
               cG30, cG31, cG32, cG33); PRIO0;
    VM6; BAR;
    // ---- P5: buf1 m01 x Ba ----
    RDA01(A1p); RDB(B1p, 0);
    stBg(0, s0, 0); stBg(0, s0, 1);
    BAR; LGKM0;
    PRIO1; MM8(fa00, fa01, fa10, fa11, cA00, cA01, cA02, cA03,
               cA10, cA11, cA12, cA13); PRIO0;
    BAR;
    // ---- P6: buf1 m23 x Ba ----
    RDA23(A1p);
    stBa(1, s1, 0); stBa(1, s1, 1);
    BAR; LGKM0;
    PRIO1; MM8(fa20, fa21, fa30, fa31, cA20, cA21, cA22, cA23,
               cA30, cA31, cA32, cA33); PRIO0;
    BAR;
    // ---- P7: buf1 m01 x Bg ----
    RDB(B1p, 8192);
    stA(1, s1, 0); stA(1, s1, 1);
    BAR; LGKM0;
    PRIO1; MM8(fa00, fa01, fa10, fa11, cG00, cG01, cG02, cG03,
               cG10, cG11, cG12, cG13); PRIO0;
    BAR;
    // ---- P8: buf1 m23 x Bg ----
    stA(1, s1, 2); stA(1, s1, 3);
    BAR;
    PRIO1; MM8(fa20, fa21, fa30, fa31, cG20, cG21, cG22, cG23,
               cG30, cG31, cG32, cG33); PRIO0;
    VM6; BAR;
  }

  int colBase = bn0 + wn * 64;
  int rowBase = bm0 + wm * 64 + q * 4;
  EPIN(0, cA00, cG00, cA10, cG10, cA20, cG20, cA30, cG30);
  EPIN(1, cA01, cG01, cA11, cG11, cA21, cG21, cA31, cG31);
  EPIN(2, cA02, cG02, cA12, cG12, cA22, cG22, cA32, cG32);
  EPIN(3, cA03, cG03, cA13, cG13, cA23, cG23, cA33, cG33);
}

extern "C" void kernel_launch(void* const* d_in, const int* in_sizes, int n_in,
                              void* d_out, int out_size, void* d_ws, size_t ws_size,
                              hipStream_t stream) {
  const float* x_in = (const float*)d_in[0];
  const float* ctx  = (const float*)d_in[1];
  const float* ln1g = (const float*)d_in[2];
  const float* ln1b = (const float*)d_in[3];
  const float* ln2g = (const float*)d_in[4];
  const float* ln2b = (const float*)d_in[5];
  const float* ln3g = (const float*)d_in[6];
  const float* ln3b = (const float*)d_in[7];
  const float* Wq1  = (const float*)d_in[8];
  const float* Wk1  = (const float*)d_in[9];
  const float* Wv1  = (const float*)d_in[10];
  const float* Wo1  = (const float*)d_in[11];
  const float* bo1  = (const float*)d_in[12];
  const float* Wq2  = (const float*)d_in[13];
  const float* Wk2  = (const float*)d_in[14];
  const float* Wv2  = (const float*)d_in[15];
  const float* Wo2  = (const float*)d_in[16];
  const float* bo2  = (const float*)d_in[17];
  const float* Wff1 = (const float*)d_in[18];
  const float* bff1 = (const float*)d_in[19];
  const float* Wff2 = (const float*)d_in[20];
  const float* bff2 = (const float*)d_in[21];
  float* out = (float*)d_out;   // also doubles as the fp32 residual stream "xcur"

  const int NR = 8192;   // B*N
  const int C = 1280, H = 20, Nseq = 1024, CC = 768;
  const int MR2 = 616;   // B*M (cross rows)

  char* ws = (char*)d_ws;
  size_t off = 0;
  auto alloc = [&](size_t bytes) -> void* {
    void* p = ws + off;
    off += (bytes + 255) & ~(size_t)255;
    return p;
  };
  unsigned* scal = (unsigned*)alloc(64);
  ushort* Wq1T  = (ushort*)alloc((size_t)C * C * 2);
  ushort* Wk1T  = (ushort*)alloc((size_t)C * C * 2);
  ushort* Wv1T  = (ushort*)alloc((size_t)C * C * 2);
  ushort* Wo1T  = (ushort*)alloc((size_t)C * C * 2);
  ushort* Wq2T  = (ushort*)alloc((size_t)C * C * 2);
  ushort* Wk2T  = (ushort*)alloc((size_t)C * CC * 2);
  ushort* Wv2T  = (ushort*)alloc((size_t)C * CC * 2);
  ushort* Wo2T  = (ushort*)alloc((size_t)C * C * 2);
  ushort* WF1T  = (ushort*)alloc((size_t)10240 * C * 2);
  ushort* WF2T  = (ushort*)alloc((size_t)C * 5120 * 2);
  ushort* LN    = (ushort*)alloc((size_t)NR * C * 2);
  size_t regionR = off;  // attention region; stage-3 GG overlays it
  ushort* QQ    = (ushort*)alloc((size_t)NR * C * 2);
  ushort* KQ    = (ushort*)alloc((size_t)NR * C * 2);
  ushort* VQ    = (ushort*)alloc((size_t)NR * C * 2);  // also AO after k_vt
  ushort* VT    = (ushort*)alloc((size_t)160 * 64 * 1024 * 2);
  float2* RS    = (float2*)alloc((size_t)160 * 1024 * 8);
  ushort* CTXB  = (ushort*)alloc((size_t)MR2 * CC * 2);
  size_t need = off;
  ushort* AO = VQ;                       // alias: VQ dead once VT is built
  ushort* GG = (ushort*)(ws + regionR);  // 84 MB, overlays QQ..VT in stage 3
  if (ws_size < need) return;  // diagnostic: absmax==poison => ws too small

  // --- init & weight prep ---
  k_zero<<<1, 64, 0, stream>>>(scal, 8);
  k_wt<<<dim3(40, 40), 256, 0, stream>>>(Wq1, Wq1T, C, C);
  k_wt<<<dim3(40, 40), 256, 0, stream>>>(Wk1, Wk1T, C, C);
  k_wt<<<dim3(40, 40), 256, 0, stream>>>(Wv1, Wv1T, C, C);
  k_wt<<<dim3(40, 40), 256, 0, stream>>>(Wo1, Wo1T, C, C);
  k_wt<<<dim3(40, 40), 256, 0, stream>>>(Wq2, Wq2T, C, C);
  k_wt<<<dim3(40, 24), 256, 0, stream>>>(Wk2, Wk2T, CC, C);
  k_wt<<<dim3(40, 24), 256, 0, stream>>>(Wv2, Wv2T, CC, C);
  k_wt<<<dim3(40, 40), 256, 0, stream>>>(Wo2, Wo2T, C, C);
  k_wt<<<dim3(320, 40), 256, 0, stream>>>(Wff1, WF1T, C, 10240);
  k_wt<<<dim3(40, 160), 256, 0, stream>>>(Wff2, WF2T, 5120, C);

  // ================= stage 1: self-attention =================
  k_ln<<<NR, 256, 0, stream>>>(x_in, ln1g, ln1b, LN);
  k_gemm<<<dim3(10, 64), 256, 0, stream>>>(LN, C, Wq1T, C, nullptr, QQ, C,
                                           nullptr, nullptr, scal + 0, NR, C, C);
  k_quant<<<(NR * C + 255) / 256, 256, 0, stream>>>(QQ, QQ, scal + 0, NR * C);
  k_gemm<<<dim3(10, 64), 256, 0, stream>>>(LN, C, Wk1T, C, nullptr, KQ, C,
                                           nullptr, nullptr, scal + 1, NR, C, C);
  k_quant<<<(NR * C + 255) / 256, 256, 0, stream>>>(KQ, KQ, scal + 1, NR * C);
  k_gemm<<<dim3(10, 64), 256, 0, stream>>>(LN, C, Wv1T, C, nullptr, VQ, C,
                                           nullptr, nullptr, scal + 2, NR, C, C);
  k_quant<<<(NR * C + 255) / 256, 256, 0, stream>>>(VQ, VQ, scal + 2, NR * C);
  k_vt<<<dim3(16, 160), 256, 0, stream>>>(VQ, VT, H, 1024, 1024);
  k_attn1<<<dim3(16, 160), 256, 0, stream>>>(QQ, KQ, RS, scal + 3, H, Nseq, 1024, 0.125f);
  k_attn2<<<dim3(16, 160), 256, 0, stream>>>(QQ, KQ, VT, RS, scal + 3, AO,
                                             H, Nseq, 1024, 1024, 0.125f);
  k_gemm<<<dim3(10, 64), 256, 0, stream>>>(AO, C, Wo1T, C, out, nullptr, C,
                                           bo1, x_in, nullptr, NR, C, C);

  // ================= stage 2: cross-attention =================
  k_ln<<<NR, 256, 0, stream>>>(out, ln2g, ln2b, LN);
  k_gemm<<<dim3(10, 64), 256, 0, stream>>>(LN, C, Wq2T, C, nullptr, QQ, C,
                                           nullptr, nullptr, scal + 4, NR, C, C);
  k_quant<<<(NR * C + 255) / 256, 256, 0, stream>>>(QQ, QQ, scal + 4, NR * C);
  k_cvt<<<(MR2 * CC + 255) / 256, 256, 0, stream>>>(ctx, CTXB, MR2 * CC);
  k_gemm<<<dim3(10, 5), 256, 0, stream>>>(CTXB, CC, Wk2T, CC, nullptr, KQ, C,
                                          nullptr, nullptr, scal + 5, MR2, C, CC);
  k_quant<<<(MR2 * C + 255) / 256, 256, 0, stream>>>(KQ, KQ, scal + 5, MR2 * C);
  k_gemm<<<dim3(10, 5), 256, 0, stream>>>(CTXB, CC, Wv2T, CC, nullptr, VQ, C,
                                          nullptr, nullptr, scal + 6, MR2, C, CC);
  k_quant<<<(MR2 * C + 255) / 256, 256, 0, stream>>>(VQ, VQ, scal + 6, MR2 * C);
  k_vt<<<dim3(2, 160), 256, 0, stream>>>(VQ, VT, H, 77, 128);
  k_attn1<<<dim3(16, 160), 256, 0, stream>>>(QQ, KQ, RS, scal + 7, H, Nseq, 77, 0.125f);
  k_attn2<<<dim3(16, 160), 256, 0, stream>>>(QQ, KQ, VT, RS, scal + 7, AO,
                                             H, Nseq, 77, 128, 0.125f);
  k_gemm<<<dim3(10, 64), 256, 0, stream>>>(AO, C, Wo2T, C, out, nullptr, C,
                                           bo2, out, nullptr, NR, C, C);

  // ================= stage 3: GEGLU FF (fused, 8-phase) =================
  k_ln<<<NR, 256, 0, stream>>>(out, ln3g, ln3b, LN);
  k_ff1_8p<<<dim3(1280), 512, 0, stream>>>(LN, WF1T, bff1, GG);
  k_gemm<<<dim3(10, 64), 256, 0, stream>>>(GG, 5120, WF2T, 5120, out, nullptr, C,
                                           bff2, out, nullptr, NR, C, 5120);
}

// Round 2
// 1789.136 us; speedup vs baseline: 1.0803x; 1.0424x over previous
//
#include <hip/hip_runtime.h>

typedef __attribute__((ext_vector_type(8))) short bf16x8;
typedef __attribute__((ext_vector_type(4))) float f32x4;

#define DEV __device__ __forceinline__
#define MF(A, B, CACC) CACC = __builtin_amdgcn_mfma_f32_16x16x32_bf16(A, B, CACC, 0, 0, 0)

DEV ushort f2b(float f) {
  unsigned u = __float_as_uint(f);
  u += 0x7fffu + ((u >> 16) & 1u);   // RNE to bf16
  return (ushort)(u >> 16);
}
DEV float b2f(ushort u) { return __uint_as_float(((unsigned)u) << 16); }

// async global->LDS, 16B per lane; lds base must be wave-uniform (HW adds lane*16)
DEV void gl_lds16(ushort* lds_base, const ushort* gp) {
  __builtin_amdgcn_global_load_lds(
      (__attribute__((address_space(1))) const void*)gp,
      (__attribute__((address_space(3))) void*)lds_base, 16, 0, 0);
}

// ---------------- zero scalar slots ----------------
__global__ void k_zero(unsigned* p, int n) {
  int i = blockIdx.x * blockDim.x + threadIdx.x;
  if (i < n) p[i] = 0u;
}

// ------------- weight transpose fp32 W[K][N] -> bf16 WT[N][K] -------------
__global__ __launch_bounds__(256) void k_wt(const float* __restrict__ W,
                                            ushort* __restrict__ WT, int K, int N) {
  __shared__ float T[32][33];
  int k0 = blockIdx.y * 32, n0 = blockIdx.x * 32;
  int tx = threadIdx.x & 31, ty = threadIdx.x >> 5;
  #pragma unroll
  for (int r = ty; r < 32; r += 8) {
    int k = k0 + r, n = n0 + tx;
    T[r][tx] = (k < K && n < N) ? W[(size_t)k * N + n] : 0.f;
  }
  __syncthreads();
  #pragma unroll
  for (int r = ty; r < 32; r += 8) {
    int n = n0 + r, k = k0 + tx;
    if (n < N && k < K) WT[(size_t)n * K + k] = f2b(T[tx][r]);
  }
}

// ---------------- f32 -> bf16 elementwise ----------------
__global__ void k_cvt(const float* __restrict__ in, ushort* __restrict__ out, int n) {
  int i = blockIdx.x * 256 + threadIdx.x;
  if (i < n) out[i] = f2b(in[i]);
}

// ---------------- layernorm (C==1280), out bf16 ----------------
__global__ __launch_bounds__(256) void k_ln(const float* __restrict__ x,
    const float* __restrict__ g, const float* __restrict__ b,
    ushort* __restrict__ out) {
  const int C = 1280;
  int row = blockIdx.x, tid = threadIdx.x;
  const float* xr = x + (size_t)row * C;
  float v0 = xr[tid], v1 = xr[tid + 256], v2 = xr[tid + 512],
        v3 = xr[tid + 768], v4 = xr[tid + 1024];
  float s = v0 + v1 + v2 + v3 + v4;
  float ss = v0 * v0 + v1 * v1 + v2 * v2 + v3 * v3 + v4 * v4;
  #pragma unroll
  for (int off = 32; off; off >>= 1) {
    s += __shfl_down(s, off);
    ss += __shfl_down(ss, off);
  }
  __shared__ float red[8];
  __shared__ float mu_s, rstd_s;
  int wave = tid >> 6, lane = tid & 63;
  if (lane == 0) { red[wave] = s; red[4 + wave] = ss; }
  __syncthreads();
  if (tid == 0) {
    float S = red[0] + red[1] + red[2] + red[3];
    float SS = red[4] + red[5] + red[6] + red[7];
    float mu = S / C;
    float var = SS / C - mu * mu;
    mu_s = mu;
    rstd_s = rsqrtf(var + 1e-5f);
  }
  __syncthreads();
  float mu = mu_s, rstd = rstd_s;
  size_t o = (size_t)row * C + tid;
  out[o]        = f2b((v0 - mu) * rstd * g[tid]        + b[tid]);
  out[o + 256]  = f2b((v1 - mu) * rstd * g[tid + 256]  + b[tid + 256]);
  out[o + 512]  = f2b((v2 - mu) * rstd * g[tid + 512]  + b[tid + 512]);
  out[o + 768]  = f2b((v3 - mu) * rstd * g[tid + 768]  + b[tid + 768]);
  out[o + 1024] = f2b((v4 - mu) * rstd * g[tid + 1024] + b[tid + 1024]);
}

// ---- GEMM epilogue helpers (by-value f32x4, constant swizzles: SROA-proof) ----
DEV void st1(float v, int r_, int c_, int ldc, const float* resid,
             float* Cf, ushort* Cb) {
  size_t o = (size_t)r_ * ldc + c_;
  if (resid) v += resid[o];
  if (Cf) Cf[o] = v;
  if (Cb) Cb[o] = f2b(v);
}
DEV float epi4(f32x4 v, int rbase, int c_, int M, int N, int ldc,
               const float* bias, const float* resid, float* Cf, ushort* Cb) {
  float v0 = v.x, v1 = v.y, v2 = v.z, v3 = v.w;
  float am = fmaxf(fmaxf(fabsf(v0), fabsf(v1)), fmaxf(fabsf(v2), fabsf(v3)));
  if (c_ < N) {
    float bb = bias ? bias[c_] : 0.f;
    v0 += bb; v1 += bb; v2 += bb; v3 += bb;
    if (rbase + 0 < M) st1(v0, rbase + 0, c_, ldc, resid, Cf, Cb);
    if (rbase + 1 < M) st1(v1, rbase + 1, c_, ldc, resid, Cf, Cb);
    if (rbase + 2 < M) st1(v2, rbase + 2, c_, ldc, resid, Cf, Cb);
    if (rbase + 3 < M) st1(v3, rbase + 3, c_, ldc, resid, Cf, Cb);
  }
  return am;
}

// ---------------- bf16 NT GEMM: C[M,N] = A[M,K] @ BT[N,K]^T ----------------
// 128x128 tile, 4 waves (2x2 of 64x64), 16x16x32 MFMA, BK=32,
// global_load_lds width=16 staging, NAMED scalar accumulators (no reg arrays).
__global__ __launch_bounds__(256) void k_gemm(
    const ushort* __restrict__ A, int lda,
    const ushort* __restrict__ BT, int ldb,
    float* __restrict__ Cf, ushort* __restrict__ Cb, int ldc,
    const float* __restrict__ bias, const float* __restrict__ resid,
    unsigned* am_slot, int M, int N, int K) {
  __shared__ __align__(16) ushort SAB[8192];  // A[128][32] @0, B[128][32] @4096
  int tid = threadIdx.x;
  int wave = tid >> 6, lane = tid & 63;
  int q = lane >> 4, mi = lane & 15;
  int wr = (wave >> 1) * 64, wc = (wave & 1) * 64;
  int bm0 = blockIdx.y * 128, bn0 = blockIdx.x * 128;
  f32x4 c00 = {}, c01 = {}, c02 = {}, c03 = {};
  f32x4 c10 = {}, c11 = {}, c12 = {}, c13 = {};
  f32x4 c20 = {}, c21 = {}, c22 = {}, c23 = {};
  f32x4 c30 = {}, c31 = {}, c32 = {}, c33 = {};
  for (int k0 = 0; k0 < K; k0 += 32) {
    __syncthreads();
    #pragma unroll
    for (int t = 0; t < 4; t++) {
      int c = wave * 256 + t * 64 + lane;
      const ushort* gp;
      if (c < 512) {
        int r = c >> 2, kc = (c & 3) << 3;
        int gr = bm0 + r; if (gr >= M) gr = M - 1;
        gp = A + (size_t)gr * lda + k0 + kc;
      } else {
        int c2 = c - 512;
        int r = c2 >> 2, kc = (c2 & 3) << 3;
        int gn = bn0 + r; if (gn >= N) gn = N - 1;
        gp = BT + (size_t)gn * ldb + k0 + kc;
      }
      gl_lds16(&SAB[(wave * 256 + t * 64) * 8], gp);
    }
    __syncthreads();
    const ushort* Ab = &SAB[(wr + mi) * 32 + q * 8];
    const ushort* Bb = &SAB[4096 + (wc + mi) * 32 + q * 8];
    bf16x8 a0 = *(const bf16x8*)(Ab);
    bf16x8 a1 = *(const bf16x8*)(Ab + 512);
    bf16x8 a2 = *(const bf16x8*)(Ab + 1024);
    bf16x8 a3 = *(const bf16x8*)(Ab + 1536);
    bf16x8 b0 = *(const bf16x8*)(Bb);
    bf16x8 b1 = *(const bf16x8*)(Bb + 512);
    bf16x8 b2 = *(const bf16x8*)(Bb + 1024);
    bf16x8 b3 = *(const bf16x8*)(Bb + 1536);
    MF(a0, b0, c00); MF(a0, b1, c01); MF(a0, b2, c02); MF(a0, b3, c03);
    MF(a1, b0, c10); MF(a1, b1, c11); MF(a1, b2, c12); MF(a1, b3, c13);
    MF(a2, b0, c20); MF(a2, b1, c21); MF(a2, b2, c22); MF(a2, b3, c23);
    MF(a3, b0, c30); MF(a3, b1, c31); MF(a3, b2, c32); MF(a3, b3, c33);
  }
  int rb = bm0 + wr + q * 4, cb = bn0 + wc + mi;
  float am = 0.f;
  am = fmaxf(am, epi4(c00, rb +  0, cb +  0, M, N, ldc, bias, resid, Cf, Cb));
  am = fmaxf(am, epi4(c01, rb +  0, cb + 16, M, N, ldc, bias, resid, Cf, Cb));
  am = fmaxf(am, epi4(c02, rb +  0, cb + 32, M, N, ldc, bias, resid, Cf, Cb));
  am = fmaxf(am, epi4(c03, rb +  0, cb + 48, M, N, ldc, bias, resid, Cf, Cb));
  am = fmaxf(am, epi4(c10, rb + 16, cb +  0, M, N, ldc, bias, resid, Cf, Cb));
  am = fmaxf(am, epi4(c11, rb + 16, cb + 16, M, N, ldc, bias, resid, Cf, Cb));
  am = fmaxf(am, epi4(c12, rb + 16, cb + 32, M, N, ldc, bias, resid, Cf, Cb));
  am = fmaxf(am, epi4(c13, rb + 16, cb + 48, M, N, ldc, bias, resid, Cf, Cb));
  am = fmaxf(am, epi4(c20, rb + 32, cb +  0, M, N, ldc, bias, resid, Cf, Cb));
  am = fmaxf(am, epi4(c21, rb + 32, cb + 16, M, N, ldc, bias, resid, Cf, Cb));
  am = fmaxf(am, epi4(c22, rb + 32, cb + 32, M, N, ldc, bias, resid, Cf, Cb));
  am = fmaxf(am, epi4(c23, rb + 32, cb + 48, M, N, ldc, bias, resid, Cf, Cb));
  am = fmaxf(am, epi4(c30, rb + 48, cb +  0, M, N, ldc, bias, resid, Cf, Cb));
  am = fmaxf(am, epi4(c31, rb + 48, cb + 16, M, N, ldc, bias, resid, Cf, Cb));
  am = fmaxf(am, epi4(c32, rb + 48, cb + 32, M, N, ldc, bias, resid, Cf, Cb));
  am = fmaxf(am, epi4(c33, rb + 48, cb + 48, M, N, ldc, bias, resid, Cf, Cb));
  if (am_slot) {
    #pragma unroll
    for (int off = 32; off; off >>= 1) am = fmaxf(am, __shfl_down(am, off));
    if (lane == 0) atomicMax(am_slot, __float_as_uint(am));
  }
}

// ---------------- symmetric fake-quant, in-place on bf16 ----------------
__global__ void k_quant(const ushort* __restrict__ in, ushort* __restrict__ out,
                        const unsigned* __restrict__ slot, int n) {
  int i = blockIdx.x * 256 + threadIdx.x;
  if (i >= n) return;
  float delta = fmaxf(__uint_as_float(*slot), 1e-8f) * (1.f / 127.f);
  float x = b2f(in[i]);
  float y = fminf(fmaxf(rintf(x / delta), -128.f), 127.f) * delta;
  out[i] = f2b(y);
}

// ------- V transpose per head: vq[b*Mr+m][h*64+d] -> vT[bh][d][m] (zero-pad) -------
__global__ __launch_bounds__(256) void k_vt(const ushort* __restrict__ vq,
    ushort* __restrict__ vT, int H, int Mr, int Mpad) {
  const int C = 1280;
  __shared__ __align__(16) ushort T[64][72];
  int bh = blockIdx.y, b = bh / H, h = bh % H;
  int m0 = blockIdx.x * 64;
  int tid = threadIdx.x;
  #pragma unroll
  for (int c = tid; c < 512; c += 256) {
    int mm = c >> 3, dc = (c & 7) << 3;
    int m = m0 + mm;
    int4 val = make_int4(0, 0, 0, 0);
    if (m < Mr) val = *(const int4*)(vq + ((size_t)b * Mr + m) * C + h * 64 + dc);
    *(int4*)&T[mm][dc] = val;
  }
  __syncthreads();
  #pragma unroll
  for (int c = tid; c < 512; c += 256) {
    int dd = c >> 3, mc = (c & 7) << 3;
    unsigned w0 = (unsigned)T[mc + 0][dd] | ((unsigned)T[mc + 1][dd] << 16);
    unsigned w1 = (unsigned)T[mc + 2][dd] | ((unsigned)T[mc + 3][dd] << 16);
    unsigned w2 = (unsigned)T[mc + 4][dd] | ((unsigned)T[mc + 5][dd] << 16);
    unsigned w3 = (unsigned)T[mc + 6][dd] | ((unsigned)T[mc + 7][dd] << 16);
    int4 val = make_int4((int)w0, (int)w1, (int)w2, (int)w3);
    *(int4*)(vT + ((size_t)bh * 64 + dd) * Mpad + m0 + mc) = val;
  }
}

// ------- attention phase 1: per-row smax & Z (log2 domain), max(1/Z) -> pmax -------
// Swapped QK^T: MF(k, q, s) => lane owns ONE q-row (mi); k = mt*64 + 16t + q*4 + reg.
// Online max/sum fully in registers; cross-q combine via shfl_xor(16/32) at end.
__global__ __launch_bounds__(256) void k_attn1(
    const ushort* __restrict__ qq, const ushort* __restrict__ kq,
    float2* __restrict__ rs, unsigned* __restrict__ pmax,
    int H, int N, int Mr, float cs) {   // cs = scale * log2(e)
  const int C = 1280;
  __shared__ __align__(16) ushort Qs[64][72];
  __shared__ __align__(16) ushort Ks[64][72];
  int tid = threadIdx.x;
  int wave = tid >> 6, lane = tid & 63;
  int q = lane >> 4, mi = lane & 15;
  int bh = blockIdx.y, b = bh / H, h = bh % H;
  int r0 = blockIdx.x * 64;
  #pragma unroll
  for (int c = tid; c < 512; c += 256) {
    int r = c >> 3, dc = (c & 7) << 3;
    *(int4*)&Qs[r][dc] = *(const int4*)(qq + ((size_t)b * N + r0 + r) * C + h * 64 + dc);
  }
  float m_run = -3.0e38f, z_run = 0.f;
  int nt = (Mr + 63) >> 6;
  for (int mt = 0; mt < nt; mt++) {
    __syncthreads();
    #pragma unroll
    for (int c = tid; c < 512; c += 256) {
      int mm = c >> 3, dc = (c & 7) << 3;
      int m = mt * 64 + mm;
      int4 val = make_int4(0, 0, 0, 0);
      if (m < Mr) val = *(const int4*)(kq + ((size_t)b * Mr + m) * C + h * 64 + dc);
      *(int4*)&Ks[mm][dc] = val;
    }
    __syncthreads();
    f32x4 s0 = {}, s1 = {}, s2 = {}, s3 = {};
    #pragma unroll
    for (int kc = 0; kc < 2; kc++) {
      bf16x8 qv  = *(const bf16x8*)&Qs[wave * 16 + mi][kc * 32 + q * 8];
      bf16x8 k0v = *(const bf16x8*)&Ks[mi][kc * 32 + q * 8];
      bf16x8 k1v = *(const bf16x8*)&Ks[16 + mi][kc * 32 + q * 8];
      bf16x8 k2v = *(const bf16x8*)&Ks[32 + mi][kc * 32 + q * 8];
      bf16x8 k3v = *(const bf16x8*)&Ks[48 + mi][kc * 32 + q * 8];
      MF(k0v, qv, s0); MF(k1v, qv, s1); MF(k2v, qv, s2); MF(k3v, qv, s3);
    }
    int kb = mt * 64 + q * 4;
    float e0  = (kb + 0  < Mr) ? s0.x * cs : -3.0e38f;
    float e1  = (kb + 1  < Mr) ? s0.y * cs : -3.0e38f;
    float e2  = (kb + 2  < Mr) ? s0.z * cs : -3.0e38f;
    float e3  = (kb + 3  < Mr) ? s0.w * cs : -3.0e38f;
    float e4  = (kb + 16 < Mr) ? s1.x * cs : -3.0e38f;
    float e5  = (kb + 17 < Mr) ? s1.y * cs : -3.0e38f;
    float e6  = (kb + 18 < Mr) ? s1.z * cs : -3.0e38f;
    float e7  = (kb + 19 < Mr) ? s1.w * cs : -3.0e38f;
    float e8  = (kb + 32 < Mr) ? s2.x * cs : -3.0e38f;
    float e9  = (kb + 33 < Mr) ? s2.y * cs : -3.0e38f;
    float e10 = (kb + 34 < Mr) ? s2.z * cs : -3.0e38f;
    float e11 = (kb + 35 < Mr) ? s2.w * cs : -3.0e38f;
    float e12 = (kb + 48 < Mr) ? s3.x * cs : -3.0e38f;
    float e13 = (kb + 49 < Mr) ? s3.y * cs : -3.0e38f;
    float e14 = (kb + 50 < Mr) ? s3.z * cs : -3.0e38f;
    float e15 = (kb + 51 < Mr) ? s3.w * cs : -3.0e38f;
    float tm = fmaxf(fmaxf(fmaxf(fmaxf(e0, e1), fmaxf(e2, e3)),
                           fmaxf(fmaxf(e4, e5), fmaxf(e6, e7))),
                     fmaxf(fmaxf(fmaxf(e8, e9), fmaxf(e10, e11)),
                           fmaxf(fmaxf(e12, e13), fmaxf(e14, e15))));
    float mn = fmaxf(m_run, tm);
    float zs = exp2f(e0 - mn)  + exp2f(e1 - mn)  + exp2f(e2 - mn)  + exp2f(e3 - mn)
             + exp2f(e4 - mn)  + exp2f(e5 - mn)  + exp2f(e6 - mn)  + exp2f(e7 - mn)
             + exp2f(e8 - mn)  + exp2f(e9 - mn)  + exp2f(e10 - mn) + exp2f(e11 - mn)
             + exp2f(e12 - mn) + exp2f(e13 - mn) + exp2f(e14 - mn) + exp2f(e15 - mn);
    z_run = z_run * exp2f(m_run - mn) + zs;
    m_run = mn;
  }
  // cross-q combine (4 lanes share a q-row: lane, lane^16, lane^32, lane^48)
  float mo = fmaxf(m_run, __shfl_xor(m_run, 16));
  mo = fmaxf(mo, __shfl_xor(mo, 32));
  float zz = z_run * exp2f(m_run - mo);
  zz += __shfl_xor(zz, 16);
  zz += __shfl_xor(zz, 32);
  if (q == 0) {
    float2 st; st.x = mo; st.y = zz;
    rs[(size_t)bh * N + r0 + wave * 16 + mi] = st;
  }
  float pm = 1.f / zz;
  #pragma unroll
  for (int off = 32; off; off >>= 1) pm = fmaxf(pm, __shfl_down(pm, off));
  if (lane == 0) atomicMax(pmax, __float_as_uint(pm));
}

// quantized-prob level: q8 = min(rint(2^(s*cs - mc)), 255), exact in bf16 via shift
DEV ushort q8lvl(float s, float cs, float mc) {
  float p = fminf(rintf(exp2f(fmaf(s, cs, -mc))), 255.f);
  return (ushort)(__float_as_uint(p) >> 16);
}

// ------- attention phase 2: recompute S, quantize probs IN REGISTER, P@V -------
// P levels (0..255) written straight from MFMA C-layout into Ps (wave-local rows);
// O accumulates q-levels @ V, scaled by delta once at the store.
__global__ __launch_bounds__(256) void k_attn2(
    const ushort* __restrict__ qq, const ushort* __restrict__ kq,
    const ushort* __restrict__ vT, const float2* __restrict__ rs,
    const unsigned* __restrict__ pmax, ushort* __restrict__ ao,
    int H, int N, int Mr, int Mpad, float cs) {
  const int C = 1280;
  __shared__ __align__(16) ushort Qs[64][72];
  __shared__ __align__(16) ushort Ks[64][72];
  __shared__ __align__(16) ushort Vs[64][72];
  __shared__ __align__(16) ushort Ps[64][72];
  int tid = threadIdx.x;
  int wave = tid >> 6, lane = tid & 63;
  int q = lane >> 4, mi = lane & 15;
  int bh = blockIdx.y, b = bh / H, h = bh % H;
  int r0 = blockIdx.x * 64;
  #pragma unroll
  for (int c = tid; c < 512; c += 256) {
    int r = c >> 3, dc = (c & 7) << 3;
    *(int4*)&Qs[r][dc] = *(const int4*)(qq + ((size_t)b * N + r0 + r) * C + h * 64 + dc);
  }
  int rbase = wave * 16 + q * 4;   // local q-row base of this lane's C-tile rows
  float delta = fmaxf(__uint_as_float(*pmax), 1e-8f) * (1.f / 255.f);
  float ld = __log2f(delta);
  float2 st0 = rs[(size_t)bh * N + r0 + rbase + 0];
  float2 st1 = rs[(size_t)bh * N + r0 + rbase + 1];
  float2 st2 = rs[(size_t)bh * N + r0 + rbase + 2];
  float2 st3 = rs[(size_t)bh * N + r0 + rbase + 3];
  float mc0 = st0.x + __log2f(st0.y) + ld;
  float mc1 = st1.x + __log2f(st1.y) + ld;
  float mc2 = st2.x + __log2f(st2.y) + ld;
  float mc3 = st3.x + __log2f(st3.y) + ld;
  f32x4 o0 = {}, o1 = {}, o2 = {}, o3 = {};
  int nt = (Mr + 63) >> 6;
  for (int mt = 0; mt < nt; mt++) {
    __syncthreads();
    #pragma unroll
    for (int c = tid; c < 512; c += 256) {
      int mm = c >> 3, dc = (c & 7) << 3;
      int m = mt * 64 + mm;
      int4 val = make_int4(0, 0, 0, 0);
      if (m < Mr) val = *(const int4*)(kq + ((size_t)b * Mr + m) * C + h * 64 + dc);
      *(int4*)&Ks[mm][dc] = val;
      *(int4*)&Vs[mm][dc] = *(const int4*)(vT + ((size_t)bh * 64 + mm) * Mpad + mt * 64 + dc);
    }
    __syncthreads();
    f32x4 s0 = {}, s1 = {}, s2 = {}, s3 = {};
    #pragma unroll
    for (int kc = 0; kc < 2; kc++) {
      bf16x8 aq  = *(const bf16x8*)&Qs[wave * 16 + mi][kc * 32 + q * 8];
      bf16x8 k0v = *(const bf16x8*)&Ks[mi][kc * 32 + q * 8];
      bf16x8 k1v = *(const bf16x8*)&Ks[16 + mi][kc * 32 + q * 8];
      bf16x8 k2v = *(const bf16x8*)&Ks[32 + mi][kc * 32 + q * 8];
      bf16x8 k3v = *(const bf16x8*)&Ks[48 + mi][kc * 32 + q * 8];
      MF(aq, k0v, s0); MF(aq, k1v, s1); MF(aq, k2v, s2); MF(aq, k3v, s3);
    }
    // in-register quantize: s_t[reg] = S[rbase+reg][16t+mi]
    int mlim = Mr - mt * 64;
    bool ok0 = (mi      < mlim);
    bool ok1 = (16 + mi < mlim);
    bool ok2 = (32 + mi < mlim);
    bool ok3 = (48 + mi < mlim);
    Ps[rbase + 0][mi]      = ok0 ? q8lvl(s0.x, cs, mc0) : (ushort)0;
    Ps[rbase + 1][mi]      = ok0 ? q8lvl(s0.y, cs, mc1) : (ushort)0;
    Ps[rbase + 2][mi]      = ok0 ? q8lvl(s0.z, cs, mc2) : (ushort)0;
    Ps[rbase + 3][mi]      = ok0 ? q8lvl(s0.w, cs, mc3) : (ushort)0;
    Ps[rbase + 0][16 + mi] = ok1 ? q8lvl(s1.x, cs, mc0) : (ushort)0;
    Ps[rbase + 1][16 + mi] = ok1 ? q8lvl(s1.y, cs, mc1) : (ushort)0;
    Ps[rbase + 2][16 + mi] = ok1 ? q8lvl(s1.z, cs, mc2) : (ushort)0;
    Ps[rbase + 3][16 + mi] = ok1 ? q8lvl(s1.w, cs, mc3) : (ushort)0;
    Ps[rbase + 0][32 + mi] = ok2 ? q8lvl(s2.x, cs, mc0) : (ushort)0;
    Ps[rbase + 1][32 + mi] = ok2 ? q8lvl(s2.y, cs, mc1) : (ushort)0;
    Ps[rbase + 2][32 + mi] = ok2 ? q8lvl(s2.z, cs, mc2) : (ushort)0;
    Ps[rbase + 3][32 + mi] = ok2 ? q8lvl(s2.w, cs, mc3) : (ushort)0;
    Ps[rbase + 0][48 + mi] = ok3 ? q8lvl(s3.x, cs, mc0) : (ushort)0;
    Ps[rbase + 1][48 + mi] = ok3 ? q8lvl(s3.y, cs, mc1) : (ushort)0;
    Ps[rbase + 2][48 + mi] = ok3 ? q8lvl(s3.z, cs, mc2) : (ushort)0;
    Ps[rbase + 3][48 + mi] = ok3 ? q8lvl(s3.w, cs, mc3) : (ushort)0;
    // wave-local RAW through LDS: rows 16w..16w+15 written & read by wave w only.
    asm volatile("s_waitcnt lgkmcnt(0)" ::: "memory");
    __builtin_amdgcn_sched_barrier(0);
    #pragma unroll
    for (int kc = 0; kc < 2; kc++) {
      bf16x8 ap = *(const bf16x8*)&Ps[wave * 16 + mi][kc * 32 + q * 8];
      bf16x8 v0 = *(const bf16x8*)&Vs[mi][kc * 32 + q * 8];
      bf16x8 v1 = *(const bf16x8*)&Vs[16 + mi][kc * 32 + q * 8];
      bf16x8 v2 = *(const bf16x8*)&Vs[32 + mi][kc * 32 + q * 8];
      bf16x8 v3 = *(const bf16x8*)&Vs[48 + mi][kc * 32 + q * 8];
      MF(ap, v0, o0); MF(ap, v1, o1); MF(ap, v2, o2); MF(ap, v3, o3);
    }
  }
  int rr = r0 + wave * 16 + q * 4;
  size_t base = ((size_t)b * N + rr) * C + h * 64 + mi;
  ao[base]              = f2b(o0.x * delta); ao[base + C]          = f2b(o0.y * delta);
  ao[base + 2 * C]      = f2b(o0.z * delta); ao[base + 3 * C]      = f2b(o0.w * delta);
  ao[base + 16]         = f2b(o1.x * delta); ao[base + C + 16]     = f2b(o1.y * delta);
  ao[base + 2 * C + 16] = f2b(o1.z * delta); ao[base + 3 * C + 16] = f2b(o1.w * delta);
  ao[base + 32]         = f2b(o2.x * delta); ao[base + C + 32]     = f2b(o2.y * delta);
  ao[base + 2 * C + 32] = f2b(o2.z * delta); ao[base + 3 * C + 32] = f2b(o2.w * delta);
  ao[base + 48]         = f2b(o3.x * delta); ao[base + C + 48]     = f2b(o3.y * delta);
  ao[base + 2 * C + 48] = f2b(o3.z * delta); ao[base + 3 * C + 48] = f2b(o3.w * delta);
}

// =====================================================================
// fused FF1 + GEGLU, 256x128(GG) tile, BK=64, 8 waves, 8-phase schedule
// (T2 xor-swizzle + T3/T4 counted vmcnt + T5 setprio), 128 KiB LDS dbuf.
// =====================================================================
#define BAR __builtin_amdgcn_s_barrier()
#define LGKM0 do { asm volatile("s_waitcnt lgkmcnt(0)" ::: "memory"); \
                   __builtin_amdgcn_sched_barrier(0); } while (0)
#define VM6 asm volatile("s_waitcnt vmcnt(6)" ::: "memory")
#define PRIO1 __builtin_amdgcn_s_setprio(1)
#define PRIO0 __builtin_amdgcn_s_setprio(0)

#define RDA01(P) do { \
  fa00 = *(const bf16x8*)&(P)[c0];        fa01 = *(const bf16x8*)&(P)[c1]; \
  fa10 = *(const bf16x8*)&(P)[1024 + c0]; fa11 = *(const bf16x8*)&(P)[1024 + c1]; } while (0)
#define RDA23(P) do { \
  fa20 = *(const bf16x8*)&(P)[2048 + c0]; fa21 = *(const bf16x8*)&(P)[2048 + c1]; \
  fa30 = *(const bf16x8*)&(P)[3072 + c0]; fa31 = *(const bf16x8*)&(P)[3072 + c1]; } while (0)
#define RDB(P, H) do { \
  b00 = *(const bf16x8*)&(P)[(H) + c0];        b01 = *(const bf16x8*)&(P)[(H) + c1]; \
  b10 = *(const bf16x8*)&(P)[(H) + 1024 + c0]; b11 = *(const bf16x8*)&(P)[(H) + 1024 + c1]; \
  b20 = *(const bf16x8*)&(P)[(H) + 2048 + c0]; b21 = *(const bf16x8*)&(P)[(H) + 2048 + c1]; \
  b30 = *(const bf16x8*)&(P)[(H) + 3072 + c0]; b31 = *(const bf16x8*)&(P)[(H) + 3072 + c1]; } while (0)

#define MM8(AX0, AX1, AY0, AY1, C0, C1, C2, C3, D0, D1, D2, D3) \
  MF(AX0, b00, C0); MF(AX1, b01, C0); MF(AX0, b10, C1); MF(AX1, b11, C1); \
  MF(AX0, b20, C2); MF(AX1, b21, C2); MF(AX0, b30, C3); MF(AX1, b31, C3); \
  MF(AY0, b00, D0); MF(AY1, b01, D0); MF(AY0, b10, D1); MF(AY1, b11, D1); \
  MF(AY0, b20, D2); MF(AY1, b21, D2); MF(AY0, b30, D3); MF(AY1, b31, D3)

// gelu-tanh via sigmoid identity: 0.5*(1+tanh(x)) == sigmoid(2x)
DEV ushort ggel(float a, float g) {
  float u = 1.5957691216057308f * g * (1.f + 0.044715f * g * g);
  float s = 1.f / (1.f + __expf(-u));
  return f2b(a * g * s);
}
DEV void epi4g(f32x4 va, f32x4 vg, size_t base, float ba, float bg,
               ushort* __restrict__ GG) {
  GG[base]         = ggel(va.x + ba, vg.x + bg);
  GG[base + 5120]  = ggel(va.y + ba, vg.y + bg);
  GG[base + 10240] = ggel(va.z + ba, vg.z + bg);
  GG[base + 15360] = ggel(va.w + ba, vg.w + bg);
}
#define EPIN(nn, P0, Q0, P1, Q1, P2, Q2, P3, Q3) do { \
  int cg = colBase + nn * 16 + mi; \
  float ba = bias[cg], bg = bias[5120 + cg]; \
  size_t b0_ = (size_t)rowBase * 5120 + cg; \
  epi4g(P0, Q0, b0_,             ba, bg, GG); \
  epi4g(P1, Q1, b0_ + 16 * 5120, ba, bg, GG); \
  epi4g(P2, Q2, b0_ + 32 * 5120, ba, bg, GG); \
  epi4g(P3, Q3, b0_ + 48 * 5120, ba, bg, GG); \
} while (0)

__global__ __launch_bounds__(512) void k_ff1_8p(
    const ushort* __restrict__ A,    // LN [8192][1280]
    const ushort* __restrict__ BT,   // WF1T [10240][1280]
    const float* __restrict__ bias,  // bff1 [10240]
    ushort* __restrict__ GG) {       // [8192][5120]
  __shared__ __align__(16) ushort SAB[65536];  // 128 KiB
  int tid = threadIdx.x;
  int wave = tid >> 6, lane = tid & 63;
  int q = lane >> 4, mi = lane & 15;
  int wm = wave >> 1, wn = wave & 1;
  int lr = lane >> 3;
  int lc = ((lane & 7) ^ lr) * 8;  // inverse-swizzled source col (elems)

  int wg = blockIdx.x;
  int swz = (wg & 7) * 160 + (wg >> 3);
  int bm0 = (swz & 31) * 256, bn0 = (swz >> 5) * 128;

  const int swzr = (mi & 7) * 8;
  int c0 = (q * 8) ^ swzr, c1 = (32 + q * 8) ^ swzr;
  const ushort* A0p = &SAB[(wm * 64 + mi) * 64];
  const ushort* B0p = &SAB[16384 + (wn * 64 + mi) * 64];
  const ushort* A1p = A0p + 32768;
  const ushort* B1p = B0p + 32768;

  const ushort* gA  = A  + (size_t)(bm0 + wave * 8 + lr) * 1280 + lc;
  const ushort* gBa = BT + (size_t)(bn0 + wave * 8 + lr) * 1280 + lc;
  const ushort* gBg = BT + (size_t)(5120 + bn0 + wave * 8 + lr) * 1280 + lc;
  ushort* lA = &SAB[wave * 512];
  ushort* lB = &SAB[16384 + wave * 512];

  auto stA = [&](int bb, int kt, int call) {
    gl_lds16(lA + bb * 32768 + call * 4096,
             gA + (size_t)call * 81920 + (size_t)kt * 64);
  };
  auto stBa = [&](int bb, int kt, int call) {
    gl_lds16(lB + bb * 32768 + call * 4096,
             gBa + (size_t)call * 81920 + (size_t)kt * 64);
  };
  auto stBg = [&](int bb, int kt, int call) {
    gl_lds16(lB + bb * 32768 + (call + 2) * 4096,
             gBg + (size_t)call * 81920 + (size_t)kt * 64);
  };

  f32x4 cA00 = {}, cA01 = {}, cA02 = {}, cA03 = {};
  f32x4 cA10 = {}, cA11 = {}, cA12 = {}, cA13 = {};
  f32x4 cA20 = {}, cA21 = {}, cA22 = {}, cA23 = {};
  f32x4 cA30 = {}, cA31 = {}, cA32 = {}, cA33 = {};
  f32x4 cG00 = {}, cG01 = {}, cG02 = {}, cG03 = {};
  f32x4 cG10 = {}, cG11 = {}, cG12 = {}, cG13 = {};
  f32x4 cG20 = {}, cG21 = {}, cG22 = {}, cG23 = {};
  f32x4 cG30 = {}, cG31 = {}, cG32 = {}, cG33 = {};
  bf16x8 fa00, fa01, fa10, fa11, fa20, fa21, fa30, fa31;
  bf16x8 b00, b01, b10, b11, b20, b21, b30, b31;

  stBa(0, 0, 0); stBa(0, 0, 1); stBg(0, 0, 0); stBg(0, 0, 1);
  stA(0, 0, 0); stA(0, 0, 1); stA(0, 0, 2); stA(0, 0, 3);
  stBa(1, 1, 0); stBa(1, 1, 1);
  stA(1, 1, 0); stA(1, 1, 1); stA(1, 1, 2); stA(1, 1, 3);
  VM6; BAR;

  for (int it = 0; it < 10; ++it) {
    int t1 = 2 * it + 1;
    int s0 = t1 + 1; if (s0 > 19) s0 = 19;
    int s1 = t1 + 2; if (s1 > 19) s1 = 19;
    // ---- P1: buf0 m01 x Ba ----
    RDA01(A0p); RDB(B0p, 0);
    stBg(1, t1, 0); stBg(1, t1, 1);
    BAR; LGKM0;
    PRIO1; MM8(fa00, fa01, fa10, fa11, cA00, cA01, cA02, cA03,
               cA10, cA11, cA12, cA13); PRIO0;
    BAR;
    // ---- P2: buf0 m23 x Ba ----
    RDA23(A0p);
    stBa(0, s0, 0); stBa(0, s0, 1);
    BAR; LGKM0;
    PRIO1; MM8(fa20, fa21, fa30, fa31, cA20, cA21, cA22, cA23,
               cA30, cA31, cA32, cA33); PRIO0;
    BAR;
    // ---- P3: buf0 m01 x Bg ----
    RDB(B0p, 8192);
    stA(0, s0, 0); stA(0, s0, 1);
    BAR; LGKM0;
    PRIO1; MM8(fa00, fa01, fa10, fa11, cG00, cG01, cG02, cG03,
               cG10, cG11, cG12, cG13); PRIO0;
    BAR;
    // ---- P4: buf0 m23 x Bg ----
    stA(0, s0, 2); stA(0, s0, 3);
    BAR;
    PRIO1; MM8(fa20, fa21, fa30, fa31, cG20, cG21, cG22, cG23,
               cG30, cG31, cG32, cG33); PRIO0;
    VM6; BAR;
    // ---- P5: buf1 m01 x Ba ----
    RDA01(A1p); RDB(B1p, 0);
    stBg(0, s0, 0); stBg(0, s0, 1);
    BAR; LGKM0;
    PRIO1; MM8(fa00, fa01, fa10, fa11, cA00, cA01, cA02, cA03,
               cA10, cA11, cA12, cA13); PRIO0;
    BAR;
    // ---- P6: buf1 m23 x Ba ----
    RDA23(A1p);
    stBa(1, s1, 0); stBa(1, s1, 1);
    BAR; LGKM0;
    PRIO1; MM8(fa20, fa21, fa30, fa31, cA20, cA21, cA22, cA23,
               cA30, cA31, cA32, cA33); PRIO0;
    BAR;
    // ---- P7: buf1 m01 x Bg ----
    RDB(B1p, 8192);
    stA(1, s1, 0); stA(1, s1, 1);
    BAR; LGKM0;
    PRIO1; MM8(fa00, fa01, fa10, fa11, cG00, cG01, cG02, cG03,
               cG10, cG11, cG12, cG13); PRIO0;
    BAR;
    // ---- P8: buf1 m23 x Bg ----
    stA(1, s1, 2); stA(1, s1, 3);
    BAR;
    PRIO1; MM8(fa20, fa21, fa30, fa31, cG20, cG21, cG22, cG23,
               cG30, cG31, cG32, cG33); PRIO0;
    VM6; BAR;
  }

  int colBase = bn0 + wn * 64;
  int rowBase = bm0 + wm * 64 + q * 4;
  EPIN(0, cA00, cG00, cA10, cG10, cA20, cG20, cA30, cG30);
  EPIN(1, cA01, cG01, cA11, cG11, cA21, cG21, cA31, cG31);
  EPIN(2, cA02, cG02, cA12, cG12, cA22, cG22, cA32, cG32);
  EPIN(3, cA03, cG03, cA13, cG13, cA23, cG23, cA33, cG33);
}

extern "C" void kernel_launch(void* const* d_in, const int* in_sizes, int n_in,
                              void* d_out, int out_size, void* d_ws, size_t ws_size,
                              hipStream_t stream) {
  const float* x_in = (const float*)d_in[0];
  const float* ctx  = (const float*)d_in[1];
  const float* ln1g = (const float*)d_in[2];
  const float* ln1b = (const float*)d_in[3];
  const float* ln2g = (const float*)d_in[4];
  const float* ln2b = (const float*)d_in[5];
  const float* ln3g = (const float*)d_in[6];
  const float* ln3b = (const float*)d_in[7];
  const float* Wq1  = (const float*)d_in[8];
  const float* Wk1  = (const float*)d_in[9];
  const float* Wv1  = (const float*)d_in[10];
  const float* Wo1  = (const float*)d_in[11];
  const float* bo1  = (const float*)d_in[12];
  const float* Wq2  = (const float*)d_in[13];
  const float* Wk2  = (const float*)d_in[14];
  const float* Wv2  = (const float*)d_in[15];
  const float* Wo2  = (const float*)d_in[16];
  const float* bo2  = (const float*)d_in[17];
  const float* Wff1 = (const float*)d_in[18];
  const float* bff1 = (const float*)d_in[19];
  const float* Wff2 = (const float*)d_in[20];
  const float* bff2 = (const float*)d_in[21];
  float* out = (float*)d_out;   // also doubles as the fp32 residual stream "xcur"

  const int NR = 8192;   // B*N
  const int C = 1280, H = 20, Nseq = 1024, CC = 768;
  const int MR2 = 616;   // B*M (cross rows)
  const float CS = 0.18033688011112042f;  // 0.125 * log2(e)

  char* ws = (char*)d_ws;
  size_t off = 0;
  auto alloc = [&](size_t bytes) -> void* {
    void* p = ws + off;
    off += (bytes + 255) & ~(size_t)255;
    return p;
  };
  unsigned* scal = (unsigned*)alloc(64);
  ushort* Wq1T  = (ushort*)alloc((size_t)C * C * 2);
  ushort* Wk1T  = (ushort*)alloc((size_t)C * C * 2);
  ushort* Wv1T  = (ushort*)alloc((size_t)C * C * 2);
  ushort* Wo1T  = (ushort*)alloc((size_t)C * C * 2);
  ushort* Wq2T  = (ushort*)alloc((size_t)C * C * 2);
  ushort* Wk2T  = (ushort*)alloc((size_t)C * CC * 2);
  ushort* Wv2T  = (ushort*)alloc((size_t)C * CC * 2);
  ushort* Wo2T  = (ushort*)alloc((size_t)C * C * 2);
  ushort* WF1T  = (ushort*)alloc((size_t)10240 * C * 2);
  ushort* WF2T  = (ushort*)alloc((size_t)C * 5120 * 2);
  ushort* LN    = (ushort*)alloc((size_t)NR * C * 2);
  size_t regionR = off;  // attention region; stage-3 GG overlays it
  ushort* QQ    = (ushort*)alloc((size_t)NR * C * 2);
  ushort* KQ    = (ushort*)alloc((size_t)NR * C * 2);
  ushort* VQ    = (ushort*)alloc((size_t)NR * C * 2);  // also AO after k_vt
  ushort* VT    = (ushort*)alloc((size_t)160 * 64 * 1024 * 2);
  float2* RS    = (float2*)alloc((size_t)160 * 1024 * 8);
  ushort* CTXB  = (ushort*)alloc((size_t)MR2 * CC * 2);
  size_t need = off;
  ushort* AO = VQ;                       // alias: VQ dead once VT is built
  ushort* GG = (ushort*)(ws + regionR);  // 84 MB, overlays QQ..VT in stage 3
  if (ws_size < need) return;  // diagnostic: absmax==poison => ws too small

  // --- init & weight prep ---
  k_zero<<<1, 64, 0, stream>>>(scal, 8);
  k_wt<<<dim3(40, 40), 256, 0, stream>>>(Wq1, Wq1T, C, C);
  k_wt<<<dim3(40, 40), 256, 0, stream>>>(Wk1, Wk1T, C, C);
  k_wt<<<dim3(40, 40), 256, 0, stream>>>(Wv1, Wv1T, C, C);
  k_wt<<<dim3(40, 40), 256, 0, stream>>>(Wo1, Wo1T, C, C);
  k_wt<<<dim3(40, 40), 256, 0, stream>>>(Wq2, Wq2T, C, C);
  k_wt<<<dim3(40, 24), 256, 0, stream>>>(Wk2, Wk2T, CC, C);
  k_wt<<<dim3(40, 24), 256, 0, stream>>>(Wv2, Wv2T, CC, C);
  k_wt<<<dim3(40, 40), 256, 0, stream>>>(Wo2, Wo2T, C, C);
  k_wt<<<dim3(320, 40), 256, 0, stream>>>(Wff1, WF1T, C, 10240);
  k_wt<<<dim3(40, 160), 256, 0, stream>>>(Wff2, WF2T, 5120, C);

  // ================= stage 1: self-attention =================
  k_ln<<<NR, 256, 0, stream>>>(x_in, ln1g, ln1b, LN);
  k_gemm<<<dim3(10, 64), 256, 0, stream>>>(LN, C, Wq1T, C, nullptr, QQ, C,
                                           nullptr, nullptr, scal + 0, NR, C, C);
  k_quant<<<(NR * C + 255) / 256, 256, 0, stream>>>(QQ, QQ, scal + 0, NR * C);
  k_gemm<<<dim3(10, 64), 256, 0, stream>>>(LN, C, Wk1T, C, nullptr, KQ, C,
                                           nullptr, nullptr, scal + 1, NR, C, C);
  k_quant<<<(NR * C + 255) / 256, 256, 0, stream>>>(KQ, KQ, scal + 1, NR * C);
  k_gemm<<<dim3(10, 64), 256, 0, stream>>>(LN, C, Wv1T, C, nullptr, VQ, C,
                                           nullptr, nullptr, scal + 2, NR, C, C);
  k_quant<<<(NR * C + 255) / 256, 256, 0, stream>>>(VQ, VQ, scal + 2, NR * C);
  k_vt<<<dim3(16, 160), 256, 0, stream>>>(VQ, VT, H, 1024, 1024);
  k_attn1<<<dim3(16, 160), 256, 0, stream>>>(QQ, KQ, RS, scal + 3, H, Nseq, 1024, CS);
  k_attn2<<<dim3(16, 160), 256, 0, stream>>>(QQ, KQ, VT, RS, scal + 3, AO,
                                             H, Nseq, 1024, 1024, CS);
  k_gemm<<<dim3(10, 64), 256, 0, stream>>>(AO, C, Wo1T, C, out, nullptr, C,
                                           bo1, x_in, nullptr, NR, C, C);

  // ================= stage 2: cross-attention =================
  k_ln<<<NR, 256, 0, stream>>>(out, ln2g, ln2b, LN);
  k_gemm<<<dim3(10, 64), 256, 0, stream>>>(LN, C, Wq2T, C, nullptr, QQ, C,
                                           nullptr, nullptr, scal + 4, NR, C, C);
  k_quant<<<(NR * C + 255) / 256, 256, 0, stream>>>(QQ, QQ, scal + 4, NR * C);
  k_cvt<<<(MR2 * CC + 255) / 256, 256, 0, stream>>>(ctx, CTXB, MR2 * CC);
  k_gemm<<<dim3(10, 5), 256, 0, stream>>>(CTXB, CC, Wk2T, CC, nullptr, KQ, C,
                                          nullptr, nullptr, scal + 5, MR2, C, CC);
  k_quant<<<(MR2 * C + 255) / 256, 256, 0, stream>>>(KQ, KQ, scal + 5, MR2 * C);
  k_gemm<<<dim3(10, 5), 256, 0, stream>>>(CTXB, CC, Wv2T, CC, nullptr, VQ, C,
                                          nullptr, nullptr, scal + 6, MR2, C, CC);
  k_quant<<<(MR2 * C + 255) / 256, 256, 0, stream>>>(VQ, VQ, scal + 6, MR2 * C);
  k_vt<<<dim3(2, 160), 256, 0, stream>>>(VQ, VT, H, 77, 128);
  k_attn1<<<dim3(16, 160), 256, 0, stream>>>(QQ, KQ, RS, scal + 7, H, Nseq, 77, CS);
  k_attn2<<<dim3(16, 160), 256, 0, stream>>>(QQ, KQ, VT, RS, scal + 7, AO,
                                             H, Nseq, 77, 128, CS);
  k_gemm<<<dim3(10, 64), 256, 0, stream>>>(AO, C, Wo2T, C, out, nullptr, C,
                                           bo2, out, nullptr, NR, C, C);

  // ================= stage 3: GEGLU FF (fused, 8-phase) =================
  k_ln<<<NR, 256, 0, stream>>>(out, ln3g, ln3b, LN);
  k_ff1_8p<<<dim3(1280), 512, 0, stream>>>(LN, WF1T, bff1, GG);
  k_gemm<<<dim3(10, 64), 256, 0, stream>>>(GG, 5120, WF2T, 5120, out, nullptr, C,
                                           bff2, out, nullptr, NR, C, 5120);
}

// Round 4
// 1742.130 us; speedup vs baseline: 1.1095x; 1.0270x over previous
//
#include <hip/hip_runtime.h>

typedef __attribute__((ext_vector_type(8))) short bf16x8;
typedef __attribute__((ext_vector_type(4))) float f32x4;

#define DEV __device__ __forceinline__
#define MF(A, B, CACC) CACC = __builtin_amdgcn_mfma_f32_16x16x32_bf16(A, B, CACC, 0, 0, 0)

DEV ushort f2b(float f) {
  unsigned u = __float_as_uint(f);
  u += 0x7fffu + ((u >> 16) & 1u);   // RNE to bf16
  return (ushort)(u >> 16);
}
DEV float b2f(ushort u) { return __uint_as_float(((unsigned)u) << 16); }

// async global->LDS, 16B per lane; lds base must be wave-uniform (HW adds lane*16)
DEV void gl_lds16(ushort* lds_base, const ushort* gp) {
  __builtin_amdgcn_global_load_lds(
      (__attribute__((address_space(1))) const void*)gp,
      (__attribute__((address_space(3))) void*)lds_base, 16, 0, 0);
}

// ---------------- zero scalar slots ----------------
__global__ void k_zero(unsigned* p, int n) {
  int i = blockIdx.x * blockDim.x + threadIdx.x;
  if (i < n) p[i] = 0u;
}

// ------------- weight transpose fp32 W[K][N] -> bf16 WT[N][K] -------------
__global__ __launch_bounds__(256) void k_wt(const float* __restrict__ W,
                                            ushort* __restrict__ WT, int K, int N) {
  __shared__ float T[32][33];
  int k0 = blockIdx.y * 32, n0 = blockIdx.x * 32;
  int tx = threadIdx.x & 31, ty = threadIdx.x >> 5;
  #pragma unroll
  for (int r = ty; r < 32; r += 8) {
    int k = k0 + r, n = n0 + tx;
    T[r][tx] = (k < K && n < N) ? W[(size_t)k * N + n] : 0.f;
  }
  __syncthreads();
  #pragma unroll
  for (int r = ty; r < 32; r += 8) {
    int n = n0 + r, k = k0 + tx;
    if (n < N && k < K) WT[(size_t)n * K + k] = f2b(T[tx][r]);
  }
}

// ---------------- f32 -> bf16 elementwise ----------------
__global__ void k_cvt(const float* __restrict__ in, ushort* __restrict__ out, int n) {
  int i = blockIdx.x * 256 + threadIdx.x;
  if (i < n) out[i] = f2b(in[i]);
}

// ---------------- layernorm (C==1280), out bf16 ----------------
__global__ __launch_bounds__(256) void k_ln(const float* __restrict__ x,
    const float* __restrict__ g, const float* __restrict__ b,
    ushort* __restrict__ out) {
  const int C = 1280;
  int row = blockIdx.x, tid = threadIdx.x;
  const float* xr = x + (size_t)row * C;
  float v0 = xr[tid], v1 = xr[tid + 256], v2 = xr[tid + 512],
        v3 = xr[tid + 768], v4 = xr[tid + 1024];
  float s = v0 + v1 + v2 + v3 + v4;
  float ss = v0 * v0 + v1 * v1 + v2 * v2 + v3 * v3 + v4 * v4;
  #pragma unroll
  for (int off = 32; off; off >>= 1) {
    s += __shfl_down(s, off);
    ss += __shfl_down(ss, off);
  }
  __shared__ float red[8];
  __shared__ float mu_s, rstd_s;
  int wave = tid >> 6, lane = tid & 63;
  if (lane == 0) { red[wave] = s; red[4 + wave] = ss; }
  __syncthreads();
  if (tid == 0) {
    float S = red[0] + red[1] + red[2] + red[3];
    float SS = red[4] + red[5] + red[6] + red[7];
    float mu = S / C;
    float var = SS / C - mu * mu;
    mu_s = mu;
    rstd_s = rsqrtf(var + 1e-5f);
  }
  __syncthreads();
  float mu = mu_s, rstd = rstd_s;
  size_t o = (size_t)row * C + tid;
  out[o]        = f2b((v0 - mu) * rstd * g[tid]        + b[tid]);
  out[o + 256]  = f2b((v1 - mu) * rstd * g[tid + 256]  + b[tid + 256]);
  out[o + 512]  = f2b((v2 - mu) * rstd * g[tid + 512]  + b[tid + 512]);
  out[o + 768]  = f2b((v3 - mu) * rstd * g[tid + 768]  + b[tid + 768]);
  out[o + 1024] = f2b((v4 - mu) * rstd * g[tid + 1024] + b[tid + 1024]);
}

// ---- GEMM epilogue helpers (by-value f32x4, constant swizzles: SROA-proof) ----
DEV void st1(float v, int r_, int c_, int ldc, const float* resid,
             float* Cf, ushort* Cb) {
  size_t o = (size_t)r_ * ldc + c_;
  if (resid) v += resid[o];
  if (Cf) Cf[o] = v;
  if (Cb) Cb[o] = f2b(v);
}
DEV float epi4(f32x4 v, int rbase, int c_, int M, int N, int ldc,
               const float* bias, const float* resid, float* Cf, ushort* Cb) {
  float v0 = v.x, v1 = v.y, v2 = v.z, v3 = v.w;
  float am = fmaxf(fmaxf(fabsf(v0), fabsf(v1)), fmaxf(fabsf(v2), fabsf(v3)));
  if (c_ < N) {
    float bb = bias ? bias[c_] : 0.f;
    v0 += bb; v1 += bb; v2 += bb; v3 += bb;
    if (rbase + 0 < M) st1(v0, rbase + 0, c_, ldc, resid, Cf, Cb);
    if (rbase + 1 < M) st1(v1, rbase + 1, c_, ldc, resid, Cf, Cb);
    if (rbase + 2 < M) st1(v2, rbase + 2, c_, ldc, resid, Cf, Cb);
    if (rbase + 3 < M) st1(v3, rbase + 3, c_, ldc, resid, Cf, Cb);
  }
  return am;
}

// ---------------- bf16 NT GEMM: C[M,N] = A[M,K] @ BT[N,K]^T ----------------
// 128x128 tile, 4 waves (2x2 of 64x64), 16x16x32 MFMA, BK=32,
// global_load_lds width=16 staging. Used for odd-shaped (M=616) GEMMs.
__global__ __launch_bounds__(256) void k_gemm(
    const ushort* __restrict__ A, int lda,
    const ushort* __restrict__ BT, int ldb,
    float* __restrict__ Cf, ushort* __restrict__ Cb, int ldc,
    const float* __restrict__ bias, const float* __restrict__ resid,
    unsigned* am_slot, int M, int N, int K) {
  __shared__ __align__(16) ushort SAB[8192];  // A[128][32] @0, B[128][32] @4096
  int tid = threadIdx.x;
  int wave = tid >> 6, lane = tid & 63;
  int q = lane >> 4, mi = lane & 15;
  int wr = (wave >> 1) * 64, wc = (wave & 1) * 64;
  int bm0 = blockIdx.y * 128, bn0 = blockIdx.x * 128;
  f32x4 c00 = {}, c01 = {}, c02 = {}, c03 = {};
  f32x4 c10 = {}, c11 = {}, c12 = {}, c13 = {};
  f32x4 c20 = {}, c21 = {}, c22 = {}, c23 = {};
  f32x4 c30 = {}, c31 = {}, c32 = {}, c33 = {};
  for (int k0 = 0; k0 < K; k0 += 32) {
    __syncthreads();
    #pragma unroll
    for (int t = 0; t < 4; t++) {
      int c = wave * 256 + t * 64 + lane;
      const ushort* gp;
      if (c < 512) {
        int r = c >> 2, kc = (c & 3) << 3;
        int gr = bm0 + r; if (gr >= M) gr = M - 1;
        gp = A + (size_t)gr * lda + k0 + kc;
      } else {
        int c2 = c - 512;
        int r = c2 >> 2, kc = (c2 & 3) << 3;
        int gn = bn0 + r; if (gn >= N) gn = N - 1;
        gp = BT + (size_t)gn * ldb + k0 + kc;
      }
      gl_lds16(&SAB[(wave * 256 + t * 64) * 8], gp);
    }
    __syncthreads();
    const ushort* Ab = &SAB[(wr + mi) * 32 + q * 8];
    const ushort* Bb = &SAB[4096 + (wc + mi) * 32 + q * 8];
    bf16x8 a0 = *(const bf16x8*)(Ab);
    bf16x8 a1 = *(const bf16x8*)(Ab + 512);
    bf16x8 a2 = *(const bf16x8*)(Ab + 1024);
    bf16x8 a3 = *(const bf16x8*)(Ab + 1536);
    bf16x8 b0 = *(const bf16x8*)(Bb);
    bf16x8 b1 = *(const bf16x8*)(Bb + 512);
    bf16x8 b2 = *(const bf16x8*)(Bb + 1024);
    bf16x8 b3 = *(const bf16x8*)(Bb + 1536);
    MF(a0, b0, c00); MF(a0, b1, c01); MF(a0, b2, c02); MF(a0, b3, c03);
    MF(a1, b0, c10); MF(a1, b1, c11); MF(a1, b2, c12); MF(a1, b3, c13);
    MF(a2, b0, c20); MF(a2, b1, c21); MF(a2, b2, c22); MF(a2, b3, c23);
    MF(a3, b0, c30); MF(a3, b1, c31); MF(a3, b2, c32); MF(a3, b3, c33);
  }
  int rb = bm0 + wr + q * 4, cb = bn0 + wc + mi;
  float am = 0.f;
  am = fmaxf(am, epi4(c00, rb +  0, cb +  0, M, N, ldc, bias, resid, Cf, Cb));
  am = fmaxf(am, epi4(c01, rb +  0, cb + 16, M, N, ldc, bias, resid, Cf, Cb));
  am = fmaxf(am, epi4(c02, rb +  0, cb + 32, M, N, ldc, bias, resid, Cf, Cb));
  am = fmaxf(am, epi4(c03, rb +  0, cb + 48, M, N, ldc, bias, resid, Cf, Cb));
  am = fmaxf(am, epi4(c10, rb + 16, cb +  0, M, N, ldc, bias, resid, Cf, Cb));
  am = fmaxf(am, epi4(c11, rb + 16, cb + 16, M, N, ldc, bias, resid, Cf, Cb));
  am = fmaxf(am, epi4(c12, rb + 16, cb + 32, M, N, ldc, bias, resid, Cf, Cb));
  am = fmaxf(am, epi4(c13, rb + 16, cb + 48, M, N, ldc, bias, resid, Cf, Cb));
  am = fmaxf(am, epi4(c20, rb + 32, cb +  0, M, N, ldc, bias, resid, Cf, Cb));
  am = fmaxf(am, epi4(c21, rb + 32, cb + 16, M, N, ldc, bias, resid, Cf, Cb));
  am = fmaxf(am, epi4(c22, rb + 32, cb + 32, M, N, ldc, bias, resid, Cf, Cb));
  am = fmaxf(am, epi4(c23, rb + 32, cb + 48, M, N, ldc, bias, resid, Cf, Cb));
  am = fmaxf(am, epi4(c30, rb + 48, cb +  0, M, N, ldc, bias, resid, Cf, Cb));
  am = fmaxf(am, epi4(c31, rb + 48, cb + 16, M, N, ldc, bias, resid, Cf, Cb));
  am = fmaxf(am, epi4(c32, rb + 48, cb + 32, M, N, ldc, bias, resid, Cf, Cb));
  am = fmaxf(am, epi4(c33, rb + 48, cb + 48, M, N, ldc, bias, resid, Cf, Cb));
  if (am_slot) {
    #pragma unroll
    for (int off = 32; off; off >>= 1) am = fmaxf(am, __shfl_down(am, off));
    if (lane == 0) atomicMax(am_slot, __float_as_uint(am));
  }
}

// ---------------- symmetric fake-quant, in-place on bf16 ----------------
__global__ void k_quant(const ushort* __restrict__ in, ushort* __restrict__ out,
                        const unsigned* __restrict__ slot, int n) {
  int i = blockIdx.x * 256 + threadIdx.x;
  if (i >= n) return;
  float delta = fmaxf(__uint_as_float(*slot), 1e-8f) * (1.f / 127.f);
  float x = b2f(in[i]);
  float y = fminf(fmaxf(rintf(x / delta), -128.f), 127.f) * delta;
  out[i] = f2b(y);
}

// ------- V transpose per head: vq[b*Mr+m][h*64+d] -> vT[bh][d][m] (zero-pad) -------
__global__ __launch_bounds__(256) void k_vt(const ushort* __restrict__ vq,
    ushort* __restrict__ vT, int H, int Mr, int Mpad) {
  const int C = 1280;
  __shared__ __align__(16) ushort T[64][72];
  int bh = blockIdx.y, b = bh / H, h = bh % H;
  int m0 = blockIdx.x * 64;
  int tid = threadIdx.x;
  #pragma unroll
  for (int c = tid; c < 512; c += 256) {
    int mm = c >> 3, dc = (c & 7) << 3;
    int m = m0 + mm;
    int4 val = make_int4(0, 0, 0, 0);
    if (m < Mr) val = *(const int4*)(vq + ((size_t)b * Mr + m) * C + h * 64 + dc);
    *(int4*)&T[mm][dc] = val;
  }
  __syncthreads();
  #pragma unroll
  for (int c = tid; c < 512; c += 256) {
    int dd = c >> 3, mc = (c & 7) << 3;
    unsigned w0 = (unsigned)T[mc + 0][dd] | ((unsigned)T[mc + 1][dd] << 16);
    unsigned w1 = (unsigned)T[mc + 2][dd] | ((unsigned)T[mc + 3][dd] << 16);
    unsigned w2 = (unsigned)T[mc + 4][dd] | ((unsigned)T[mc + 5][dd] << 16);
    unsigned w3 = (unsigned)T[mc + 6][dd] | ((unsigned)T[mc + 7][dd] << 16);
    int4 val = make_int4((int)w0, (int)w1, (int)w2, (int)w3);
    *(int4*)(vT + ((size_t)bh * 64 + dd) * Mpad + m0 + mc) = val;
  }
}

// ------- attention phase 1: per-row smax & Z (log2 domain), max(1/Z) -> pmax -------
__global__ __launch_bounds__(256) void k_attn1(
    const ushort* __restrict__ qq, const ushort* __restrict__ kq,
    float2* __restrict__ rs, unsigned* __restrict__ pmax,
    int H, int N, int Mr, float cs) {   // cs = scale * log2(e)
  const int C = 1280;
  __shared__ __align__(16) ushort Qs[64][72];
  __shared__ __align__(16) ushort Ks[64][72];
  int tid = threadIdx.x;
  int wave = tid >> 6, lane = tid & 63;
  int q = lane >> 4, mi = lane & 15;
  int bh = blockIdx.y, b = bh / H, h = bh % H;
  int r0 = blockIdx.x * 64;
  #pragma unroll
  for (int c = tid; c < 512; c += 256) {
    int r = c >> 3, dc = (c & 7) << 3;
    *(int4*)&Qs[r][dc] = *(const int4*)(qq + ((size_t)b * N + r0 + r) * C + h * 64 + dc);
  }
  float m_run = -3.0e38f, z_run = 0.f;
  int nt = (Mr + 63) >> 6;
  for (int mt = 0; mt < nt; mt++) {
    __syncthreads();
    #pragma unroll
    for (int c = tid; c < 512; c += 256) {
      int mm = c >> 3, dc = (c & 7) << 3;
      int m = mt * 64 + mm;
      int4 val = make_int4(0, 0, 0, 0);
      if (m < Mr) val = *(const int4*)(kq + ((size_t)b * Mr + m) * C + h * 64 + dc);
      *(int4*)&Ks[mm][dc] = val;
    }
    __syncthreads();
    f32x4 s0 = {}, s1 = {}, s2 = {}, s3 = {};
    #pragma unroll
    for (int kc = 0; kc < 2; kc++) {
      bf16x8 qv  = *(const bf16x8*)&Qs[wave * 16 + mi][kc * 32 + q * 8];
      bf16x8 k0v = *(const bf16x8*)&Ks[mi][kc * 32 + q * 8];
      bf16x8 k1v = *(const bf16x8*)&Ks[16 + mi][kc * 32 + q * 8];
      bf16x8 k2v = *(const bf16x8*)&Ks[32 + mi][kc * 32 + q * 8];
      bf16x8 k3v = *(const bf16x8*)&Ks[48 + mi][kc * 32 + q * 8];
      MF(k0v, qv, s0); MF(k1v, qv, s1); MF(k2v, qv, s2); MF(k3v, qv, s3);
    }
    int kb = mt * 64 + q * 4;
    float e0  = (kb + 0  < Mr) ? s0.x * cs : -3.0e38f;
    float e1  = (kb + 1  < Mr) ? s0.y * cs : -3.0e38f;
    float e2  = (kb + 2  < Mr) ? s0.z * cs : -3.0e38f;
    float e3  = (kb + 3  < Mr) ? s0.w * cs : -3.0e38f;
    float e4  = (kb + 16 < Mr) ? s1.x * cs : -3.0e38f;
    float e5  = (kb + 17 < Mr) ? s1.y * cs : -3.0e38f;
    float e6  = (kb + 18 < Mr) ? s1.z * cs : -3.0e38f;
    float e7  = (kb + 19 < Mr) ? s1.w * cs : -3.0e38f;
    float e8  = (kb + 32 < Mr) ? s2.x * cs : -3.0e38f;
    float e9  = (kb + 33 < Mr) ? s2.y * cs : -3.0e38f;
    float e10 = (kb + 34 < Mr) ? s2.z * cs : -3.0e38f;
    float e11 = (kb + 35 < Mr) ? s2.w * cs : -3.0e38f;
    float e12 = (kb + 48 < Mr) ? s3.x * cs : -3.0e38f;
    float e13 = (kb + 49 < Mr) ? s3.y * cs : -3.0e38f;
    float e14 = (kb + 50 < Mr) ? s3.z * cs : -3.0e38f;
    float e15 = (kb + 51 < Mr) ? s3.w * cs : -3.0e38f;
    float tm = fmaxf(fmaxf(fmaxf(fmaxf(e0, e1), fmaxf(e2, e3)),
                           fmaxf(fmaxf(e4, e5), fmaxf(e6, e7))),
                     fmaxf(fmaxf(fmaxf(e8, e9), fmaxf(e10, e11)),
                           fmaxf(fmaxf(e12, e13), fmaxf(e14, e15))));
    float mn = fmaxf(m_run, tm);
    float zs = exp2f(e0 - mn)  + exp2f(e1 - mn)  + exp2f(e2 - mn)  + exp2f(e3 - mn)
             + exp2f(e4 - mn)  + exp2f(e5 - mn)  + exp2f(e6 - mn)  + exp2f(e7 - mn)
             + exp2f(e8 - mn)  + exp2f(e9 - mn)  + exp2f(e10 - mn) + exp2f(e11 - mn)
             + exp2f(e12 - mn) + exp2f(e13 - mn) + exp2f(e14 - mn) + exp2f(e15 - mn);
    z_run = z_run * exp2f(m_run - mn) + zs;
    m_run = mn;
  }
  // cross-q combine (4 lanes share a q-row: lane, lane^16, lane^32, lane^48)
  float mo = fmaxf(m_run, __shfl_xor(m_run, 16));
  mo = fmaxf(mo, __shfl_xor(mo, 32));
  float zz = z_run * exp2f(m_run - mo);
  zz += __shfl_xor(zz, 16);
  zz += __shfl_xor(zz, 32);
  if (q == 0) {
    float2 st; st.x = mo; st.y = zz;
    rs[(size_t)bh * N + r0 + wave * 16 + mi] = st;
  }
  float pm = 1.f / zz;
  #pragma unroll
  for (int off = 32; off; off >>= 1) pm = fmaxf(pm, __shfl_down(pm, off));
  if (lane == 0) atomicMax(pmax, __float_as_uint(pm));
}

// quantized-prob level: q8 = min(rint(2^(s*cs - mc)), 255), exact in bf16 via shift
DEV ushort q8lvl(float s, float cs, float mc) {
  float p = fminf(rintf(exp2f(fmaf(s, cs, -mc))), 255.f);
  return (ushort)(__float_as_uint(p) >> 16);
}

// ------- attention phase 2: recompute S, quantize probs IN REGISTER, P@V -------
__global__ __launch_bounds__(256) void k_attn2(
    const ushort* __restrict__ qq, const ushort* __restrict__ kq,
    const ushort* __restrict__ vT, const float2* __restrict__ rs,
    const unsigned* __restrict__ pmax, ushort* __restrict__ ao,
    int H, int N, int Mr, int Mpad, float cs) {
  const int C = 1280;
  __shared__ __align__(16) ushort Qs[64][72];
  __shared__ __align__(16) ushort Ks[64][72];
  __shared__ __align__(16) ushort Vs[64][72];
  __shared__ __align__(16) ushort Ps[64][72];
  int tid = threadIdx.x;
  int wave = tid >> 6, lane = tid & 63;
  int q = lane >> 4, mi = lane & 15;
  int bh = blockIdx.y, b = bh / H, h = bh % H;
  int r0 = blockIdx.x * 64;
  #pragma unroll
  for (int c = tid; c < 512; c += 256) {
    int r = c >> 3, dc = (c & 7) << 3;
    *(int4*)&Qs[r][dc] = *(const int4*)(qq + ((size_t)b * N + r0 + r) * C + h * 64 + dc);
  }
  int rbase = wave * 16 + q * 4;   // local q-row base of this lane's C-tile rows
  float delta = fmaxf(__uint_as_float(*pmax), 1e-8f) * (1.f / 255.f);
  float ld = __log2f(delta);
  float2 st0 = rs[(size_t)bh * N + r0 + rbase + 0];
  float2 st1 = rs[(size_t)bh * N + r0 + rbase + 1];
  float2 st2 = rs[(size_t)bh * N + r0 + rbase + 2];
  float2 st3 = rs[(size_t)bh * N + r0 + rbase + 3];
  float mc0 = st0.x + __log2f(st0.y) + ld;
  float mc1 = st1.x + __log2f(st1.y) + ld;
  float mc2 = st2.x + __log2f(st2.y) + ld;
  float mc3 = st3.x + __log2f(st3.y) + ld;
  f32x4 o0 = {}, o1 = {}, o2 = {}, o3 = {};
  int nt = (Mr + 63) >> 6;
  for (int mt = 0; mt < nt; mt++) {
    __syncthreads();
    #pragma unroll
    for (int c = tid; c < 512; c += 256) {
      int mm = c >> 3, dc = (c & 7) << 3;
      int m = mt * 64 + mm;
      int4 val = make_int4(0, 0, 0, 0);
      if (m < Mr) val = *(const int4*)(kq + ((size_t)b * Mr + m) * C + h * 64 + dc);
      *(int4*)&Ks[mm][dc] = val;
      *(int4*)&Vs[mm][dc] = *(const int4*)(vT + ((size_t)bh * 64 + mm) * Mpad + mt * 64 + dc);
    }
    __syncthreads();
    f32x4 s0 = {}, s1 = {}, s2 = {}, s3 = {};
    #pragma unroll
    for (int kc = 0; kc < 2; kc++) {
      bf16x8 aq  = *(const bf16x8*)&Qs[wave * 16 + mi][kc * 32 + q * 8];
      bf16x8 k0v = *(const bf16x8*)&Ks[mi][kc * 32 + q * 8];
      bf16x8 k1v = *(const bf16x8*)&Ks[16 + mi][kc * 32 + q * 8];
      bf16x8 k2v = *(const bf16x8*)&Ks[32 + mi][kc * 32 + q * 8];
      bf16x8 k3v = *(const bf16x8*)&Ks[48 + mi][kc * 32 + q * 8];
      MF(aq, k0v, s0); MF(aq, k1v, s1); MF(aq, k2v, s2); MF(aq, k3v, s3);
    }
    // in-register quantize: s_t[reg] = S[rbase+reg][16t+mi]
    int mlim = Mr - mt * 64;
    bool ok0 = (mi      < mlim);
    bool ok1 = (16 + mi < mlim);
    bool ok2 = (32 + mi < mlim);
    bool ok3 = (48 + mi < mlim);
    Ps[rbase + 0][mi]      = ok0 ? q8lvl(s0.x, cs, mc0) : (ushort)0;
    Ps[rbase + 1][mi]      = ok0 ? q8lvl(s0.y, cs, mc1) : (ushort)0;
    Ps[rbase + 2][mi]      = ok0 ? q8lvl(s0.z, cs, mc2) : (ushort)0;
    Ps[rbase + 3][mi]      = ok0 ? q8lvl(s0.w, cs, mc3) : (ushort)0;
    Ps[rbase + 0][16 + mi] = ok1 ? q8lvl(s1.x, cs, mc0) : (ushort)0;
    Ps[rbase + 1][16 + mi] = ok1 ? q8lvl(s1.y, cs, mc1) : (ushort)0;
    Ps[rbase + 2][16 + mi] = ok1 ? q8lvl(s1.z, cs, mc2) : (ushort)0;
    Ps[rbase + 3][16 + mi] = ok1 ? q8lvl(s1.w, cs, mc3) : (ushort)0;
    Ps[rbase + 0][32 + mi] = ok2 ? q8lvl(s2.x, cs, mc0) : (ushort)0;
    Ps[rbase + 1][32 + mi] = ok2 ? q8lvl(s2.y, cs, mc1) : (ushort)0;
    Ps[rbase + 2][32 + mi] = ok2 ? q8lvl(s2.z, cs, mc2) : (ushort)0;
    Ps[rbase + 3][32 + mi] = ok2 ? q8lvl(s2.w, cs, mc3) : (ushort)0;
    Ps[rbase + 0][48 + mi] = ok3 ? q8lvl(s3.x, cs, mc0) : (ushort)0;
    Ps[rbase + 1][48 + mi] = ok3 ? q8lvl(s3.y, cs, mc1) : (ushort)0;
    Ps[rbase + 2][48 + mi] = ok3 ? q8lvl(s3.z, cs, mc2) : (ushort)0;
    Ps[rbase + 3][48 + mi] = ok3 ? q8lvl(s3.w, cs, mc3) : (ushort)0;
    // wave-local RAW through LDS: rows 16w..16w+15 written & read by wave w only.
    asm volatile("s_waitcnt lgkmcnt(0)" ::: "memory");
    __builtin_amdgcn_sched_barrier(0);
    #pragma unroll
    for (int kc = 0; kc < 2; kc++) {
      bf16x8 ap = *(const bf16x8*)&Ps[wave * 16 + mi][kc * 32 + q * 8];
      bf16x8 v0 = *(const bf16x8*)&Vs[mi][kc * 32 + q * 8];
      bf16x8 v1 = *(const bf16x8*)&Vs[16 + mi][kc * 32 + q * 8];
      bf16x8 v2 = *(const bf16x8*)&Vs[32 + mi][kc * 32 + q * 8];
      bf16x8 v3 = *(const bf16x8*)&Vs[48 + mi][kc * 32 + q * 8];
      MF(ap, v0, o0); MF(ap, v1, o1); MF(ap, v2, o2); MF(ap, v3, o3);
    }
  }
  int rr = r0 + wave * 16 + q * 4;
  size_t base = ((size_t)b * N + rr) * C + h * 64 + mi;
  ao[base]              = f2b(o0.x * delta); ao[base + C]          = f2b(o0.y * delta);
  ao[base + 2 * C]      = f2b(o0.z * delta); ao[base + 3 * C]      = f2b(o0.w * delta);
  ao[base + 16]         = f2b(o1.x * delta); ao[base + C + 16]     = f2b(o1.y * delta);
  ao[base + 2 * C + 16] = f2b(o1.z * delta); ao[base + 3 * C + 16] = f2b(o1.w * delta);
  ao[base + 32]         = f2b(o2.x * delta); ao[base + C + 32]     = f2b(o2.y * delta);
  ao[base + 2 * C + 32] = f2b(o2.z * delta); ao[base + 3 * C + 32] = f2b(o2.w * delta);
  ao[base + 48]         = f2b(o3.x * delta); ao[base + C + 48]     = f2b(o3.y * delta);
  ao[base + 2 * C + 48] = f2b(o3.z * delta); ao[base + 3 * C + 48] = f2b(o3.w * delta);
}

// =====================================================================
// shared pipeline macros (T2 xor-swizzle + counted vmcnt + setprio)
// =====================================================================
#define BAR __builtin_amdgcn_s_barrier()
#define LGKM0 do { asm volatile("s_waitcnt lgkmcnt(0)" ::: "memory"); \
                   __builtin_amdgcn_sched_barrier(0); } while (0)
#define VM6 asm volatile("s_waitcnt vmcnt(6)" ::: "memory")
#define VM0 asm volatile("s_waitcnt vmcnt(0)" ::: "memory")
#define PRIO1 __builtin_amdgcn_s_setprio(1)
#define PRIO0 __builtin_amdgcn_s_setprio(0)

#define RDA01(P) do { \
  fa00 = *(const bf16x8*)&(P)[c0];        fa01 = *(const bf16x8*)&(P)[c1]; \
  fa10 = *(const bf16x8*)&(P)[1024 + c0]; fa11 = *(const bf16x8*)&(P)[1024 + c1]; } while (0)
#define RDA23(P) do { \
  fa20 = *(const bf16x8*)&(P)[2048 + c0]; fa21 = *(const bf16x8*)&(P)[2048 + c1]; \
  fa30 = *(const bf16x8*)&(P)[3072 + c0]; fa31 = *(const bf16x8*)&(P)[3072 + c1]; } while (0)
#define RDB(P, H) do { \
  b00 = *(const bf16x8*)&(P)[(H) + c0];        b01 = *(const bf16x8*)&(P)[(H) + c1]; \
  b10 = *(const bf16x8*)&(P)[(H) + 1024 + c0]; b11 = *(const bf16x8*)&(P)[(H) + 1024 + c1]; \
  b20 = *(const bf16x8*)&(P)[(H) + 2048 + c0]; b21 = *(const bf16x8*)&(P)[(H) + 2048 + c1]; \
  b30 = *(const bf16x8*)&(P)[(H) + 3072 + c0]; b31 = *(const bf16x8*)&(P)[(H) + 3072 + c1]; } while (0)
#define RDB8(P) RDB(P, 0)

#define MM8(AX0, AX1, AY0, AY1, C0, C1, C2, C3, D0, D1, D2, D3) \
  MF(AX0, b00, C0); MF(AX1, b01, C0); MF(AX0, b10, C1); MF(AX1, b11, C1); \
  MF(AX0, b20, C2); MF(AX1, b21, C2); MF(AX0, b30, C3); MF(AX1, b31, C3); \
  MF(AY0, b00, D0); MF(AY1, b01, D0); MF(AY0, b10, D1); MF(AY1, b11, D1); \
  MF(AY0, b20, D2); MF(AY1, b21, D2); MF(AY0, b30, D3); MF(AY1, b31, D3)

// =====================================================================
// k_gemm8: 8-wave 256x128-tile NT GEMM, BK=64, TRIPLE-buffered LDS (144 KiB),
// 2 phases/K-tile of 16 MFMA, counted vmcnt(6) (never 0 in main loop).
// Requires M%256==0, N%128==0, K%64==0, K/64>=5, (K/64-2)%3==0, blocks%8==0.
// =====================================================================
#define GB8(AP, BP, DB, KT) \
  RDA01(AP); RDB8(BP); \
  stB(DB, KT, 0); stB(DB, KT, 1); stA(DB, KT, 0); \
  BAR; LGKM0; \
  PRIO1; MM8(fa00, fa01, fa10, fa11, c00, c01, c02, c03, c10, c11, c12, c13); PRIO0; \
  BAR; \
  RDA23(AP); \
  stA(DB, KT, 1); stA(DB, KT, 2); stA(DB, KT, 3); \
  BAR; LGKM0; \
  PRIO1; MM8(fa20, fa21, fa30, fa31, c20, c21, c22, c23, c30, c31, c32, c33); PRIO0; \
  VM6; BAR;

#define GT8(AP, BP) \
  RDA01(AP); RDB8(BP); \
  BAR; LGKM0; \
  PRIO1; MM8(fa00, fa01, fa10, fa11, c00, c01, c02, c03, c10, c11, c12, c13); PRIO0; \
  BAR; \
  RDA23(AP); \
  BAR; LGKM0; \
  PRIO1; MM8(fa20, fa21, fa30, fa31, c20, c21, c22, c23, c30, c31, c32, c33); PRIO0;

__global__ __launch_bounds__(512) void k_gemm8(
    const ushort* __restrict__ A, int lda,
    const ushort* __restrict__ BT, int ldb,
    float* __restrict__ Cf, ushort* __restrict__ Cb, int ldc,
    const float* __restrict__ bias, const float* __restrict__ resid,
    unsigned* am_slot, int M, int N, int K) {
  // per buf (24576 ushorts): A[256][64] @0, B[128][64] @16384. Swizzle: col ^= (row&7)*8.
  __shared__ __align__(16) ushort SAB[73728];  // 144 KiB, 3 bufs
  int tid = threadIdx.x;
  int wave = tid >> 6, lane = tid & 63;
  int q = lane >> 4, mi = lane & 15;
  int wm = wave >> 1, wn = wave & 1;
  int lr = lane >> 3;
  int lc = ((lane & 7) ^ lr) * 8;   // inverse-swizzled source col (elems)

  int NBN = N >> 7;
  int nblk = (M >> 8) * NBN;
  int cpx = nblk >> 3;
  int wg = blockIdx.x;
  int swz = (wg & 7) * cpx + (wg >> 3);   // bijective: nblk % 8 == 0
  int bm0 = (swz / NBN) << 8, bn0 = (swz % NBN) << 7;

  const int swzr = (mi & 7) * 8;
  int c0 = (q * 8) ^ swzr, c1 = (32 + q * 8) ^ swzr;
  const ushort* A0p = &SAB[(wm * 64 + mi) * 64];
  const ushort* B0p = &SAB[16384 + (wn * 64 + mi) * 64];
  const ushort* A1p = A0p + 24576; const ushort* B1p = B0p + 24576;
  const ushort* A2p = A0p + 49152; const ushort* B2p = B0p + 49152;

  const ushort* gA = A  + (size_t)(bm0 + wave * 8 + lr) * lda + lc;
  const ushort* gB = BT + (size_t)(bn0 + wave * 8 + lr) * ldb + lc;
  ushort* lA = &SAB[wave * 512];
  ushort* lB = &SAB[16384 + wave * 512];

  auto stA = [&](int bb, int kt, int call) {   // A: 4 calls x 64 rows
    gl_lds16(lA + bb * 24576 + call * 4096,
             gA + (size_t)call * 64 * lda + (size_t)kt * 64);
  };
  auto stB = [&](int bb, int kt, int call) {   // B: 2 calls x 64 rows
    gl_lds16(lB + bb * 24576 + call * 4096,
             gB + (size_t)call * 64 * ldb + (size_t)kt * 64);
  };

  f32x4 c00 = {}, c01 = {}, c02 = {}, c03 = {};
  f32x4 c10 = {}, c11 = {}, c12 = {}, c13 = {};
  f32x4 c20 = {}, c21 = {}, c22 = {}, c23 = {};
  f32x4 c30 = {}, c31 = {}, c32 = {}, c33 = {};
  bf16x8 fa00, fa01, fa10, fa11, fa20, fa21, fa30, fa31;
  bf16x8 b00, b01, b10, b11, b20, b21, b30, b31;

  // prologue: tile0 -> buf0, tile1 -> buf1 (6 calls each)
  stB(0, 0, 0); stB(0, 0, 1);
  stA(0, 0, 0); stA(0, 0, 1); stA(0, 0, 2); stA(0, 0, 3);
  stB(1, 1, 0); stB(1, 1, 1);
  stA(1, 1, 0); stA(1, 1, 1); stA(1, 1, 2); stA(1, 1, 3);
  VM6; BAR;

  int NT = K >> 6, NTm = NT - 2;  // NTm % 3 == 0 by contract
  for (int t = 0; t < NTm; t += 3) {
    GB8(A0p, B0p, 2, t + 2);
    GB8(A1p, B1p, 0, t + 3);
    GB8(A2p, B2p, 1, t + 4);
  }
  // tail: tile NT-2 (buf0), then tile NT-1 (buf1)
  GT8(A0p, B0p);
  VM0; BAR;
  GT8(A1p, B1p);

  int rb = bm0 + wm * 64 + q * 4, cb = bn0 + wn * 64 + mi;
  float am = 0.f;
  am = fmaxf(am, epi4(c00, rb +  0, cb +  0, M, N, ldc, bias, resid, Cf, Cb));
  am = fmaxf(am, epi4(c01, rb +  0, cb + 16, M, N, ldc, bias, resid, Cf, Cb));
  am = fmaxf(am, epi4(c02, rb +  0, cb + 32, M, N, ldc, bias, resid, Cf, Cb));
  am = fmaxf(am, epi4(c03, rb +  0, cb + 48, M, N, ldc, bias, resid, Cf, Cb));
  am = fmaxf(am, epi4(c10, rb + 16, cb +  0, M, N, ldc, bias, resid, Cf, Cb));
  am = fmaxf(am, epi4(c11, rb + 16, cb + 16, M, N, ldc, bias, resid, Cf, Cb));
  am = fmaxf(am, epi4(c12, rb + 16, cb + 32, M, N, ldc, bias, resid, Cf, Cb));
  am = fmaxf(am, epi4(c13, rb + 16, cb + 48, M, N, ldc, bias, resid, Cf, Cb));
  am = fmaxf(am, epi4(c20, rb + 32, cb +  0, M, N, ldc, bias, resid, Cf, Cb));
  am = fmaxf(am, epi4(c21, rb + 32, cb + 16, M, N, ldc, bias, resid, Cf, Cb));
  am = fmaxf(am, epi4(c22, rb + 32, cb + 32, M, N, ldc, bias, resid, Cf, Cb));
  am = fmaxf(am, epi4(c23, rb + 32, cb + 48, M, N, ldc, bias, resid, Cf, Cb));
  am = fmaxf(am, epi4(c30, rb + 48, cb +  0, M, N, ldc, bias, resid, Cf, Cb));
  am = fmaxf(am, epi4(c31, rb + 48, cb + 16, M, N, ldc, bias, resid, Cf, Cb));
  am = fmaxf(am, epi4(c32, rb + 48, cb + 32, M, N, ldc, bias, resid, Cf, Cb));
  am = fmaxf(am, epi4(c33, rb + 48, cb + 48, M, N, ldc, bias, resid, Cf, Cb));
  if (am_slot) {
    #pragma unroll
    for (int off = 32; off; off >>= 1) am = fmaxf(am, __shfl_down(am, off));
    if (lane == 0) atomicMax(am_slot, __float_as_uint(am));
  }
}

// =====================================================================
// fused FF1 + GEGLU, 256x128(GG) tile, BK=64, 8 waves, 8-phase schedule
// =====================================================================
// gelu-tanh via sigmoid identity: 0.5*(1+tanh(x)) == sigmoid(2x)
DEV ushort ggel(float a, float g) {
  float u = 1.5957691216057308f * g * (1.f + 0.044715f * g * g);
  float s = 1.f / (1.f + __expf(-u));
  return f2b(a * g * s);
}
DEV void epi4g(f32x4 va, f32x4 vg, size_t base, float ba, float bg,
               ushort* __restrict__ GG) {
  GG[base]         = ggel(va.x + ba, vg.x + bg);
  GG[base + 5120]  = ggel(va.y + ba, vg.y + bg);
  GG[base + 10240] = ggel(va.z + ba, vg.z + bg);
  GG[base + 15360] = ggel(va.w + ba, vg.w + bg);
}
#define EPIN(nn, P0, Q0, P1, Q1, P2, Q2, P3, Q3) do { \
  int cg = colBase + nn * 16 + mi; \
  float ba = bias[cg], bg = bias[5120 + cg]; \
  size_t b0_ = (size_t)rowBase * 5120 + cg; \
  epi4g(P0, Q0, b0_,             ba, bg, GG); \
  epi4g(P1, Q1, b0_ + 16 * 5120, ba, bg, GG); \
  epi4g(P2, Q2, b0_ + 32 * 5120, ba, bg, GG); \
  epi4g(P3, Q3, b0_ + 48 * 5120, ba, bg, GG); \
} while (0)

__global__ __launch_bounds__(512) void k_ff1_8p(
    const ushort* __restrict__ A,    // LN [8192][1280]
    const ushort* __restrict__ BT,   // WF1T [10240][1280]
    const float* __restrict__ bias,  // bff1 [10240]
    ushort* __restrict__ GG) {       // [8192][5120]
  __shared__ __align__(16) ushort SAB[65536];  // 128 KiB
  int tid = threadIdx.x;
  int wave = tid >> 6, lane = tid & 63;
  int q = lane >> 4, mi = lane & 15;
  int wm = wave >> 1, wn = wave & 1;
  int lr = lane >> 3;
  int lc = ((lane & 7) ^ lr) * 8;  // inverse-swizzled source col (elems)

  int wg = blockIdx.x;
  int swz = (wg & 7) * 160 + (wg >> 3);
  int bm0 = (swz & 31) * 256, bn0 = (swz >> 5) * 128;

  const int swzr = (mi & 7) * 8;
  int c0 = (q * 8) ^ swzr, c1 = (32 + q * 8) ^ swzr;
  const ushort* A0p = &SAB[(wm * 64 + mi) * 64];
  const ushort* B0p = &SAB[16384 + (wn * 64 + mi) * 64];
  const ushort* A1p = A0p + 32768;
  const ushort* B1p = B0p + 32768;

  const ushort* gA  = A  + (size_t)(bm0 + wave * 8 + lr) * 1280 + lc;
  const ushort* gBa = BT + (size_t)(bn0 + wave * 8 + lr) * 1280 + lc;
  const ushort* gBg = BT + (size_t)(5120 + bn0 + wave * 8 + lr) * 1280 + lc;
  ushort* lA = &SAB[wave * 512];
  ushort* lB = &SAB[16384 + wave * 512];

  auto stA = [&](int bb, int kt, int call) {
    gl_lds16(lA + bb * 32768 + call * 4096,
             gA + (size_t)call * 81920 + (size_t)kt * 64);
  };
  auto stBa = [&](int bb, int kt, int call) {
    gl_lds16(lB + bb * 32768 + call * 4096,
             gBa + (size_t)call * 81920 + (size_t)kt * 64);
  };
  auto stBg = [&](int bb, int kt, int call) {
    gl_lds16(lB + bb * 32768 + (call + 2) * 4096,
             gBg + (size_t)call * 81920 + (size_t)kt * 64);
  };

  f32x4 cA00 = {}, cA01 = {}, cA02 = {}, cA03 = {};
  f32x4 cA10 = {}, cA11 = {}, cA12 = {}, cA13 = {};
  f32x4 cA20 = {}, cA21 = {}, cA22 = {}, cA23 = {};
  f32x4 cA30 = {}, cA31 = {}, cA32 = {}, cA33 = {};
  f32x4 cG00 = {}, cG01 = {}, cG02 = {}, cG03 = {};
  f32x4 cG10 = {}, cG11 = {}, cG12 = {}, cG13 = {};
  f32x4 cG20 = {}, cG21 = {}, cG22 = {}, cG23 = {};
  f32x4 cG30 = {}, cG31 = {}, cG32 = {}, cG33 = {};
  bf16x8 fa00, fa01, fa10, fa11, fa20, fa21, fa30, fa31;
  bf16x8 b00, b01, b10, b11, b20, b21, b30, b31;

  stBa(0, 0, 0); stBa(0, 0, 1); stBg(0, 0, 0); stBg(0, 0, 1);
  stA(0, 0, 0); stA(0, 0, 1); stA(0, 0, 2); stA(0, 0, 3);
  stBa(1, 1, 0); stBa(1, 1, 1);
  stA(1, 1, 0); stA(1, 1, 1); stA(1, 1, 2); stA(1, 1, 3);
  VM6; BAR;

  for (int it = 0; it < 10; ++it) {
    int t1 = 2 * it + 1;
    int s0 = t1 + 1; if (s0 > 19) s0 = 19;
    int s1 = t1 + 2; if (s1 > 19) s1 = 19;
    // ---- P1: buf0 m01 x Ba ----
    RDA01(A0p); RDB(B0p, 0);
    stBg(1, t1, 0); stBg(1, t1, 1);
    BAR; LGKM0;
    PRIO1; MM8(fa00, fa01, fa10, fa11, cA00, cA01, cA02, cA03,
               cA10, cA11, cA12, cA13); PRIO0;
    BAR;
    // ---- P2: buf0 m23 x Ba ----
    RDA23(A0p);
    stBa(0, s0, 0); stBa(0, s0, 1);
    BAR; LGKM0;
    PRIO1; MM8(fa20, fa21, fa30, fa31, cA20, cA21, cA22, cA23,
               cA30, cA31, cA32, cA33); PRIO0;
    BAR;
    // ---- P3: buf0 m01 x Bg ----
    RDB(B0p, 8192);
    stA(0, s0, 0); stA(0, s0, 1);
    BAR; LGKM0;
    PRIO1; MM8(fa00, fa01, fa10, fa11, cG00, cG01, cG02, cG03,
               cG10, cG11, cG12, cG13); PRIO0;
    BAR;
    // ---- P4: buf0 m23 x Bg ----
    stA(0, s0, 2); stA(0, s0, 3);
    BAR;
    PRIO1; MM8(fa20, fa21, fa30, fa31, cG20, cG21, cG22, cG23,
               cG30, cG31, cG32, cG33); PRIO0;
    VM6; BAR;
    // ---- P5: buf1 m01 x Ba ----
    RDA01(A1p); RDB(B1p, 0);
    stBg(0, s0, 0); stBg(0, s0, 1);
    BAR; LGKM0;
    PRIO1; MM8(fa00, fa01, fa10, fa11, cA00, cA01, cA02, cA03,
               cA10, cA11, cA12, cA13); PRIO0;
    BAR;
    // ---- P6: buf1 m23 x Ba ----
    RDA23(A1p);
    stBa(1, s1, 0); stBa(1, s1, 1);
    BAR; LGKM0;
    PRIO1; MM8(fa20, fa21, fa30, fa31, cA20, cA21, cA22, cA23,
               cA30, cA31, cA32, cA33); PRIO0;
    BAR;
    // ---- P7: buf1 m01 x Bg ----
    RDB(B1p, 8192);
    stA(1, s1, 0); stA(1, s1, 1);
    BAR; LGKM0;
    PRIO1; MM8(fa00, fa01, fa10, fa11, cG00, cG01, cG02, cG03,
               cG10, cG11, cG12, cG13); PRIO0;
    BAR;
    // ---- P8: buf1 m23 x Bg ----
    stA(1, s1, 2); stA(1, s1, 3);
    BAR;
    PRIO1; MM8(fa20, fa21, fa30, fa31, cG20, cG21, cG22, cG23,
               cG30, cG31, cG32, cG33); PRIO0;
    VM6; BAR;
  }

  int colBase = bn0 + wn * 64;
  int rowBase = bm0 + wm * 64 + q * 4;
  EPIN(0, cA00, cG00, cA10, cG10, cA20, cG20, cA30, cG30);
  EPIN(1, cA01, cG01, cA11, cG11, cA21, cG21, cA31, cG31);
  EPIN(2, cA02, cG02, cA12, cG12, cA22, cG22, cA32, cG32);
  EPIN(3, cA03, cG03, cA13, cG13, cA23, cG23, cA33, cG33);
}

extern "C" void kernel_launch(void* const* d_in, const int* in_sizes, int n_in,
                              void* d_out, int out_size, void* d_ws, size_t ws_size,
                              hipStream_t stream) {
  const float* x_in = (const float*)d_in[0];
  const float* ctx  = (const float*)d_in[1];
  const float* ln1g = (const float*)d_in[2];
  const float* ln1b = (const float*)d_in[3];
  const float* ln2g = (const float*)d_in[4];
  const float* ln2b = (const float*)d_in[5];
  const float* ln3g = (const float*)d_in[6];
  const float* ln3b = (const float*)d_in[7];
  const float* Wq1  = (const float*)d_in[8];
  const float* Wk1  = (const float*)d_in[9];
  const float* Wv1  = (const float*)d_in[10];
  const float* Wo1  = (const float*)d_in[11];
  const float* bo1  = (const float*)d_in[12];
  const float* Wq2  = (const float*)d_in[13];
  const float* Wk2  = (const float*)d_in[14];
  const float* Wv2  = (const float*)d_in[15];
  const float* Wo2  = (const float*)d_in[16];
  const float* bo2  = (const float*)d_in[17];
  const float* Wff1 = (const float*)d_in[18];
  const float* bff1 = (const float*)d_in[19];
  const float* Wff2 = (const float*)d_in[20];
  const float* bff2 = (const float*)d_in[21];
  float* out = (float*)d_out;   // also doubles as the fp32 residual stream "xcur"

  const int NR = 8192;   // B*N
  const int C = 1280, H = 20, Nseq = 1024, CC = 768;
  const int MR2 = 616;   // B*M (cross rows)
  const float CS = 0.18033688011112042f;  // 0.125 * log2(e)

  char* ws = (char*)d_ws;
  size_t off = 0;
  auto alloc = [&](size_t bytes) -> void* {
    void* p = ws + off;
    off += (bytes + 255) & ~(size_t)255;
    return p;
  };
  unsigned* scal = (unsigned*)alloc(64);
  ushort* Wq1T  = (ushort*)alloc((size_t)C * C * 2);
  ushort* Wk1T  = (ushort*)alloc((size_t)C * C * 2);
  ushort* Wv1T  = (ushort*)alloc((size_t)C * C * 2);
  ushort* Wo1T  = (ushort*)alloc((size_t)C * C * 2);
  ushort* Wq2T  = (ushort*)alloc((size_t)C * C * 2);
  ushort* Wk2T  = (ushort*)alloc((size_t)C * CC * 2);
  ushort* Wv2T  = (ushort*)alloc((size_t)C * CC * 2);
  ushort* Wo2T  = (ushort*)alloc((size_t)C * C * 2);
  ushort* WF1T  = (ushort*)alloc((size_t)10240 * C * 2);
  ushort* WF2T  = (ushort*)alloc((size_t)C * 5120 * 2);
  ushort* LN    = (ushort*)alloc((size_t)NR * C * 2);
  size_t regionR = off;  // attention region; stage-3 GG overlays it
  ushort* QQ    = (ushort*)alloc((size_t)NR * C * 2);
  ushort* KQ    = (ushort*)alloc((size_t)NR * C * 2);
  ushort* VQ    = (ushort*)alloc((size_t)NR * C * 2);  // also AO after k_vt
  ushort* VT    = (ushort*)alloc((size_t)160 * 64 * 1024 * 2);
  float2* RS    = (float2*)alloc((size_t)160 * 1024 * 8);
  ushort* CTXB  = (ushort*)alloc((size_t)MR2 * CC * 2);
  size_t need = off;
  ushort* AO = VQ;                       // alias: VQ dead once VT is built
  ushort* GG = (ushort*)(ws + regionR);  // 84 MB, overlays QQ..VT in stage 3
  if (ws_size < need) return;  // diagnostic: absmax==poison => ws too small

  // --- init & weight prep ---
  k_zero<<<1, 64, 0, stream>>>(scal, 8);
  k_wt<<<dim3(40, 40), 256, 0, stream>>>(Wq1, Wq1T, C, C);
  k_wt<<<dim3(40, 40), 256, 0, stream>>>(Wk1, Wk1T, C, C);
  k_wt<<<dim3(40, 40), 256, 0, stream>>>(Wv1, Wv1T, C, C);
  k_wt<<<dim3(40, 40), 256, 0, stream>>>(Wo1, Wo1T, C, C);
  k_wt<<<dim3(40, 40), 256, 0, stream>>>(Wq2, Wq2T, C, C);
  k_wt<<<dim3(40, 24), 256, 0, stream>>>(Wk2, Wk2T, CC, C);
  k_wt<<<dim3(40, 24), 256, 0, stream>>>(Wv2, Wv2T, CC, C);
  k_wt<<<dim3(40, 40), 256, 0, stream>>>(Wo2, Wo2T, C, C);
  k_wt<<<dim3(320, 40), 256, 0, stream>>>(Wff1, WF1T, C, 10240);
  k_wt<<<dim3(40, 160), 256, 0, stream>>>(Wff2, WF2T, 5120, C);

  // ================= stage 1: self-attention =================
  k_ln<<<NR, 256, 0, stream>>>(x_in, ln1g, ln1b, LN);
  k_gemm8<<<dim3(320), 512, 0, stream>>>(LN, C, Wq1T, C, nullptr, QQ, C,
                                         nullptr, nullptr, scal + 0, NR, C, C);
  k_quant<<<(NR * C + 255) / 256, 256, 0, stream>>>(QQ, QQ, scal + 0, NR * C);
  k_gemm8<<<dim3(320), 512, 0, stream>>>(LN, C, Wk1T, C, nullptr, KQ, C,
                                         nullptr, nullptr, scal + 1, NR, C, C);
  k_quant<<<(NR * C + 255) / 256, 256, 0, stream>>>(KQ, KQ, scal + 1, NR * C);
  k_gemm8<<<dim3(320), 512, 0, stream>>>(LN, C, Wv1T, C, nullptr, VQ, C,
                                         nullptr, nullptr, scal + 2, NR, C, C);
  k_quant<<<(NR * C + 255) / 256, 256, 0, stream>>>(VQ, VQ, scal + 2, NR * C);
  k_vt<<<dim3(16, 160), 256, 0, stream>>>(VQ, VT, H, 1024, 1024);
  k_attn1<<<dim3(16, 160), 256, 0, stream>>>(QQ, KQ, RS, scal + 3, H, Nseq, 1024, CS);
  k_attn2<<<dim3(16, 160), 256, 0, stream>>>(QQ, KQ, VT, RS, scal + 3, AO,
                                             H, Nseq, 1024, 1024, CS);
  k_gemm8<<<dim3(320), 512, 0, stream>>>(AO, C, Wo1T, C, out, nullptr, C,
                                         bo1, x_in, nullptr, NR, C, C);

  // ================= stage 2: cross-attention =================
  k_ln<<<NR, 256, 0, stream>>>(out, ln2g, ln2b, LN);
  k_gemm8<<<dim3(320), 512, 0, stream>>>(LN, C, Wq2T, C, nullptr, QQ, C,
                                         nullptr, nullptr, scal + 4, NR, C, C);
  k_quant<<<(NR * C + 255) / 256, 256, 0, stream>>>(QQ, QQ, scal + 4, NR * C);
  k_cvt<<<(MR2 * CC + 255) / 256, 256, 0, stream>>>(ctx, CTXB, MR2 * CC);
  k_gemm<<<dim3(10, 5), 256, 0, stream>>>(CTXB, CC, Wk2T, CC, nullptr, KQ, C,
                                          nullptr, nullptr, scal + 5, MR2, C, CC);
  k_quant<<<(MR2 * C + 255) / 256, 256, 0, stream>>>(KQ, KQ, scal + 5, MR2 * C);
  k_gemm<<<dim3(10, 5), 256, 0, stream>>>(CTXB, CC, Wv2T, CC, nullptr, VQ, C,
                                          nullptr, nullptr, scal + 6, MR2, C, CC);
  k_quant<<<(MR2 * C + 255) / 256, 256, 0, stream>>>(VQ, VQ, scal + 6, MR2 * C);
  k_vt<<<dim3(2, 160), 256, 0, stream>>>(VQ, VT, H, 77, 128);
  k_attn1<<<dim3(16, 160), 256, 0, stream>>>(QQ, KQ, RS, scal + 7, H, Nseq, 77, CS);
  k_attn2<<<dim3(16, 160), 256, 0, stream>>>(QQ, KQ, VT, RS, scal + 7, AO,
                                             H, Nseq, 77, 128, CS);
  k_gemm8<<<dim3(320), 512, 0, stream>>>(AO, C, Wo2T, C, out, nullptr, C,
                                         bo2, out, nullptr, NR, C, C);

  // ================= stage 3: GEGLU FF (fused, 8-phase) =================
  k_ln<<<NR, 256, 0, stream>>>(out, ln3g, ln3b, LN);
  k_ff1_8p<<<dim3(1280), 512, 0, stream>>>(LN, WF1T, bff1, GG);
  k_gemm8<<<dim3(320), 512, 0, stream>>>(GG, 5120, WF2T, 5120, out, nullptr, C,
                                         bff2, out, nullptr, NR, C, 5120);
}

// Round 5
// 1685.569 us; speedup vs baseline: 1.1467x; 1.0336x over previous
//
#include <hip/hip_runtime.h>

typedef __attribute__((ext_vector_type(8))) short bf16x8;
typedef __attribute__((ext_vector_type(4))) float f32x4;

#define DEV __device__ __forceinline__
#define MF(A, B, CACC) CACC = __builtin_amdgcn_mfma_f32_16x16x32_bf16(A, B, CACC, 0, 0, 0)

DEV ushort f2b(float f) {
  unsigned u = __float_as_uint(f);
  u += 0x7fffu + ((u >> 16) & 1u);   // RNE to bf16
  return (ushort)(u >> 16);
}
DEV float b2f(ushort u) { return __uint_as_float(((unsigned)u) << 16); }

// async global->LDS, 16B per lane; lds base must be wave-uniform (HW adds lane*16)
DEV void gl_lds16(ushort* lds_base, const ushort* gp) {
  __builtin_amdgcn_global_load_lds(
      (__attribute__((address_space(1))) const void*)gp,
      (__attribute__((address_space(3))) void*)lds_base, 16, 0, 0);
}

// ---------------- zero scalar slots ----------------
__global__ void k_zero(unsigned* p, int n) {
  int i = blockIdx.x * blockDim.x + threadIdx.x;
  if (i < n) p[i] = 0u;
}

// ------------- weight transpose fp32 W[K][N] -> bf16 WT[N][K] -------------
__global__ __launch_bounds__(256) void k_wt(const float* __restrict__ W,
                                            ushort* __restrict__ WT, int K, int N) {
  __shared__ float T[32][33];
  int k0 = blockIdx.y * 32, n0 = blockIdx.x * 32;
  int tx = threadIdx.x & 31, ty = threadIdx.x >> 5;
  #pragma unroll
  for (int r = ty; r < 32; r += 8) {
    int k = k0 + r, n = n0 + tx;
    T[r][tx] = (k < K && n < N) ? W[(size_t)k * N + n] : 0.f;
  }
  __syncthreads();
  #pragma unroll
  for (int r = ty; r < 32; r += 8) {
    int n = n0 + r, k = k0 + tx;
    if (n < N && k < K) WT[(size_t)n * K + k] = f2b(T[tx][r]);
  }
}

// ---------------- f32 -> bf16 elementwise ----------------
__global__ void k_cvt(const float* __restrict__ in, ushort* __restrict__ out, int n) {
  int i = blockIdx.x * 256 + threadIdx.x;
  if (i < n) out[i] = f2b(in[i]);
}

// ---------------- layernorm (C==1280), out bf16 ----------------
__global__ __launch_bounds__(256) void k_ln(const float* __restrict__ x,
    const float* __restrict__ g, const float* __restrict__ b,
    ushort* __restrict__ out) {
  const int C = 1280;
  int row = blockIdx.x, tid = threadIdx.x;
  const float* xr = x + (size_t)row * C;
  float v0 = xr[tid], v1 = xr[tid + 256], v2 = xr[tid + 512],
        v3 = xr[tid + 768], v4 = xr[tid + 1024];
  float s = v0 + v1 + v2 + v3 + v4;
  float ss = v0 * v0 + v1 * v1 + v2 * v2 + v3 * v3 + v4 * v4;
  #pragma unroll
  for (int off = 32; off; off >>= 1) {
    s += __shfl_down(s, off);
    ss += __shfl_down(ss, off);
  }
  __shared__ float red[8];
  __shared__ float mu_s, rstd_s;
  int wave = tid >> 6, lane = tid & 63;
  if (lane == 0) { red[wave] = s; red[4 + wave] = ss; }
  __syncthreads();
  if (tid == 0) {
    float S = red[0] + red[1] + red[2] + red[3];
    float SS = red[4] + red[5] + red[6] + red[7];
    float mu = S / C;
    float var = SS / C - mu * mu;
    mu_s = mu;
    rstd_s = rsqrtf(var + 1e-5f);
  }
  __syncthreads();
  float mu = mu_s, rstd = rstd_s;
  size_t o = (size_t)row * C + tid;
  out[o]        = f2b((v0 - mu) * rstd * g[tid]        + b[tid]);
  out[o + 256]  = f2b((v1 - mu) * rstd * g[tid + 256]  + b[tid + 256]);
  out[o + 512]  = f2b((v2 - mu) * rstd * g[tid + 512]  + b[tid + 512]);
  out[o + 768]  = f2b((v3 - mu) * rstd * g[tid + 768]  + b[tid + 768]);
  out[o + 1024] = f2b((v4 - mu) * rstd * g[tid + 1024] + b[tid + 1024]);
}

// ---- GEMM epilogue helpers (by-value f32x4, constant swizzles: SROA-proof) ----
DEV void st1(float v, int r_, int c_, int ldc, const float* resid,
             float* Cf, ushort* Cb) {
  size_t o = (size_t)r_ * ldc + c_;
  if (resid) v += resid[o];
  if (Cf) Cf[o] = v;
  if (Cb) Cb[o] = f2b(v);
}
DEV float epi4(f32x4 v, int rbase, int c_, int M, int N, int ldc,
               const float* bias, const float* resid, float* Cf, ushort* Cb) {
  float v0 = v.x, v1 = v.y, v2 = v.z, v3 = v.w;
  float am = fmaxf(fmaxf(fabsf(v0), fabsf(v1)), fmaxf(fabsf(v2), fabsf(v3)));
  if (c_ < N) {
    float bb = bias ? bias[c_] : 0.f;
    v0 += bb; v1 += bb; v2 += bb; v3 += bb;
    if (rbase + 0 < M) st1(v0, rbase + 0, c_, ldc, resid, Cf, Cb);
    if (rbase + 1 < M) st1(v1, rbase + 1, c_, ldc, resid, Cf, Cb);
    if (rbase + 2 < M) st1(v2, rbase + 2, c_, ldc, resid, Cf, Cb);
    if (rbase + 3 < M) st1(v3, rbase + 3, c_, ldc, resid, Cf, Cb);
  }
  return am;
}

// ---------------- bf16 NT GEMM: C[M,N] = A[M,K] @ BT[N,K]^T ----------------
// 128x128 tile, 4 waves (2x2 of 64x64), 16x16x32 MFMA, BK=32,
// global_load_lds width=16 staging. Used for odd-shaped (M=616) GEMMs.
__global__ __launch_bounds__(256) void k_gemm(
    const ushort* __restrict__ A, int lda,
    const ushort* __restrict__ BT, int ldb,
    float* __restrict__ Cf, ushort* __restrict__ Cb, int ldc,
    const float* __restrict__ bias, const float* __restrict__ resid,
    unsigned* am_slot, int M, int N, int K, int slcN) {
  __shared__ __align__(16) ushort SAB[8192];  // A[128][32] @0, B[128][32] @4096
  int tid = threadIdx.x;
  int wave = tid >> 6, lane = tid & 63;
  int q = lane >> 4, mi = lane & 15;
  int wr = (wave >> 1) * 64, wc = (wave & 1) * 64;
  int bm0 = blockIdx.y * 128, bn0 = blockIdx.x * 128;
  f32x4 c00 = {}, c01 = {}, c02 = {}, c03 = {};
  f32x4 c10 = {}, c11 = {}, c12 = {}, c13 = {};
  f32x4 c20 = {}, c21 = {}, c22 = {}, c23 = {};
  f32x4 c30 = {}, c31 = {}, c32 = {}, c33 = {};
  for (int k0 = 0; k0 < K; k0 += 32) {
    __syncthreads();
    #pragma unroll
    for (int t = 0; t < 4; t++) {
      int c = wave * 256 + t * 64 + lane;
      const ushort* gp;
      if (c < 512) {
        int r = c >> 2, kc = (c & 3) << 3;
        int gr = bm0 + r; if (gr >= M) gr = M - 1;
        gp = A + (size_t)gr * lda + k0 + kc;
      } else {
        int c2 = c - 512;
        int r = c2 >> 2, kc = (c2 & 3) << 3;
        int gn = bn0 + r; if (gn >= N) gn = N - 1;
        gp = BT + (size_t)gn * ldb + k0 + kc;
      }
      gl_lds16(&SAB[(wave * 256 + t * 64) * 8], gp);
    }
    __syncthreads();
    const ushort* Ab = &SAB[(wr + mi) * 32 + q * 8];
    const ushort* Bb = &SAB[4096 + (wc + mi) * 32 + q * 8];
    bf16x8 a0 = *(const bf16x8*)(Ab);
    bf16x8 a1 = *(const bf16x8*)(Ab + 512);
    bf16x8 a2 = *(const bf16x8*)(Ab + 1024);
    bf16x8 a3 = *(const bf16x8*)(Ab + 1536);
    bf16x8 b0 = *(const bf16x8*)(Bb);
    bf16x8 b1 = *(const bf16x8*)(Bb + 512);
    bf16x8 b2 = *(const bf16x8*)(Bb + 1024);
    bf16x8 b3 = *(const bf16x8*)(Bb + 1536);
    MF(a0, b0, c00); MF(a0, b1, c01); MF(a0, b2, c02); MF(a0, b3, c03);
    MF(a1, b0, c10); MF(a1, b1, c11); MF(a1, b2, c12); MF(a1, b3, c13);
    MF(a2, b0, c20); MF(a2, b1, c21); MF(a2, b2, c22); MF(a2, b3, c23);
    MF(a3, b0, c30); MF(a3, b1, c31); MF(a3, b2, c32); MF(a3, b3, c33);
  }
  int rb = bm0 + wr + q * 4, cb = bn0 + wc + mi;
  float am = 0.f;
  am = fmaxf(am, epi4(c00, rb +  0, cb +  0, M, N, ldc, bias, resid, Cf, Cb));
  am = fmaxf(am, epi4(c01, rb +  0, cb + 16, M, N, ldc, bias, resid, Cf, Cb));
  am = fmaxf(am, epi4(c02, rb +  0, cb + 32, M, N, ldc, bias, resid, Cf, Cb));
  am = fmaxf(am, epi4(c03, rb +  0, cb + 48, M, N, ldc, bias, resid, Cf, Cb));
  am = fmaxf(am, epi4(c10, rb + 16, cb +  0, M, N, ldc, bias, resid, Cf, Cb));
  am = fmaxf(am, epi4(c11, rb + 16, cb + 16, M, N, ldc, bias, resid, Cf, Cb));
  am = fmaxf(am, epi4(c12, rb + 16, cb + 32, M, N, ldc, bias, resid, Cf, Cb));
  am = fmaxf(am, epi4(c13, rb + 16, cb + 48, M, N, ldc, bias, resid, Cf, Cb));
  am = fmaxf(am, epi4(c20, rb + 32, cb +  0, M, N, ldc, bias, resid, Cf, Cb));
  am = fmaxf(am, epi4(c21, rb + 32, cb + 16, M, N, ldc, bias, resid, Cf, Cb));
  am = fmaxf(am, epi4(c22, rb + 32, cb + 32, M, N, ldc, bias, resid, Cf, Cb));
  am = fmaxf(am, epi4(c23, rb + 32, cb + 48, M, N, ldc, bias, resid, Cf, Cb));
  am = fmaxf(am, epi4(c30, rb + 48, cb +  0, M, N, ldc, bias, resid, Cf, Cb));
  am = fmaxf(am, epi4(c31, rb + 48, cb + 16, M, N, ldc, bias, resid, Cf, Cb));
  am = fmaxf(am, epi4(c32, rb + 48, cb + 32, M, N, ldc, bias, resid, Cf, Cb));
  am = fmaxf(am, epi4(c33, rb + 48, cb + 48, M, N, ldc, bias, resid, Cf, Cb));
  if (am_slot) {
    #pragma unroll
    for (int off = 32; off; off >>= 1) am = fmaxf(am, __shfl_down(am, off));
    if (lane == 0) atomicMax(am_slot + bn0 / slcN, __float_as_uint(am));
  }
}

// ------- strided multi-slice fake-quant: addr=(i/colw)*ld+i%colw, slot by col -------
__global__ void k_quant3(const ushort* __restrict__ in, ushort* __restrict__ out,
                         const unsigned* __restrict__ slotb, int n,
                         int colw, int ld, int slcw) {
  int i = blockIdx.x * 256 + threadIdx.x;
  if (i >= n) return;
  int row = i / colw, col = i - row * colw;
  size_t a = (size_t)row * ld + col;
  float delta = fmaxf(__uint_as_float(slotb[col / slcw]), 1e-8f) * (1.f / 127.f);
  float x = b2f(in[a]);
  float y = fminf(fmaxf(rintf(x / delta), -128.f), 127.f) * delta;
  out[a] = f2b(y);
}

// ------- V transpose per head: vq[(b*Mr+m)*ldv + h*64+d] -> vT[bh][d][m] (zero-pad) -------
__global__ __launch_bounds__(256) void k_vt(const ushort* __restrict__ vq,
    ushort* __restrict__ vT, int H, int Mr, int Mpad, int ldv) {
  __shared__ __align__(16) ushort T[64][72];
  int bh = blockIdx.y, b = bh / H, h = bh % H;
  int m0 = blockIdx.x * 64;
  int tid = threadIdx.x;
  #pragma unroll
  for (int c = tid; c < 512; c += 256) {
    int mm = c >> 3, dc = (c & 7) << 3;
    int m = m0 + mm;
    int4 val = make_int4(0, 0, 0, 0);
    if (m < Mr) val = *(const int4*)(vq + ((size_t)b * Mr + m) * ldv + h * 64 + dc);
    *(int4*)&T[mm][dc] = val;
  }
  __syncthreads();
  #pragma unroll
  for (int c = tid; c < 512; c += 256) {
    int dd = c >> 3, mc = (c & 7) << 3;
    unsigned w0 = (unsigned)T[mc + 0][dd] | ((unsigned)T[mc + 1][dd] << 16);
    unsigned w1 = (unsigned)T[mc + 2][dd] | ((unsigned)T[mc + 3][dd] << 16);
    unsigned w2 = (unsigned)T[mc + 4][dd] | ((unsigned)T[mc + 5][dd] << 16);
    unsigned w3 = (unsigned)T[mc + 6][dd] | ((unsigned)T[mc + 7][dd] << 16);
    int4 val = make_int4((int)w0, (int)w1, (int)w2, (int)w3);
    *(int4*)(vT + ((size_t)bh * 64 + dd) * Mpad + m0 + mc) = val;
  }
}

// ------- attention phase 1: per-row smax & Z (log2 domain), max(1/Z) -> pmax -------
__global__ __launch_bounds__(256) void k_attn1(
    const ushort* __restrict__ qq, const ushort* __restrict__ kq,
    float2* __restrict__ rs, unsigned* __restrict__ pmax,
    int H, int N, int Mr, int ldq, int ldk, float cs) {   // cs = scale * log2(e)
  __shared__ __align__(16) ushort Qs[64][72];
  __shared__ __align__(16) ushort Ks[64][72];
  int tid = threadIdx.x;
  int wave = tid >> 6, lane = tid & 63;
  int q = lane >> 4, mi = lane & 15;
  int bh = blockIdx.y, b = bh / H, h = bh % H;
  int r0 = blockIdx.x * 64;
  #pragma unroll
  for (int c = tid; c < 512; c += 256) {
    int r = c >> 3, dc = (c & 7) << 3;
    *(int4*)&Qs[r][dc] = *(const int4*)(qq + ((size_t)b * N + r0 + r) * ldq + h * 64 + dc);
  }
  float m_run = -3.0e38f, z_run = 0.f;
  int nt = (Mr + 63) >> 6;
  for (int mt = 0; mt < nt; mt++) {
    __syncthreads();
    #pragma unroll
    for (int c = tid; c < 512; c += 256) {
      int mm = c >> 3, dc = (c & 7) << 3;
      int m = mt * 64 + mm;
      int4 val = make_int4(0, 0, 0, 0);
      if (m < Mr) val = *(const int4*)(kq + ((size_t)b * Mr + m) * ldk + h * 64 + dc);
      *(int4*)&Ks[mm][dc] = val;
    }
    __syncthreads();
    f32x4 s0 = {}, s1 = {}, s2 = {}, s3 = {};
    #pragma unroll
    for (int kc = 0; kc < 2; kc++) {
      bf16x8 qv  = *(const bf16x8*)&Qs[wave * 16 + mi][kc * 32 + q * 8];
      bf16x8 k0v = *(const bf16x8*)&Ks[mi][kc * 32 + q * 8];
      bf16x8 k1v = *(const bf16x8*)&Ks[16 + mi][kc * 32 + q * 8];
      bf16x8 k2v = *(const bf16x8*)&Ks[32 + mi][kc * 32 + q * 8];
      bf16x8 k3v = *(const bf16x8*)&Ks[48 + mi][kc * 32 + q * 8];
      MF(k0v, qv, s0); MF(k1v, qv, s1); MF(k2v, qv, s2); MF(k3v, qv, s3);
    }
    int kb = mt * 64 + q * 4;
    float e0  = (kb + 0  < Mr) ? s0.x * cs : -3.0e38f;
    float e1  = (kb + 1  < Mr) ? s0.y * cs : -3.0e38f;
    float e2  = (kb + 2  < Mr) ? s0.z * cs : -3.0e38f;
    float e3  = (kb + 3  < Mr) ? s0.w * cs : -3.0e38f;
    float e4  = (kb + 16 < Mr) ? s1.x * cs : -3.0e38f;
    float e5  = (kb + 17 < Mr) ? s1.y * cs : -3.0e38f;
    float e6  = (kb + 18 < Mr) ? s1.z * cs : -3.0e38f;
    float e7  = (kb + 19 < Mr) ? s1.w * cs : -3.0e38f;
    float e8  = (kb + 32 < Mr) ? s2.x * cs : -3.0e38f;
    float e9  = (kb + 33 < Mr) ? s2.y * cs : -3.0e38f;
    float e10 = (kb + 34 < Mr) ? s2.z * cs : -3.0e38f;
    float e11 = (kb + 35 < Mr) ? s2.w * cs : -3.0e38f;
    float e12 = (kb + 48 < Mr) ? s3.x * cs : -3.0e38f;
    float e13 = (kb + 49 < Mr) ? s3.y * cs : -3.0e38f;
    float e14 = (kb + 50 < Mr) ? s3.z * cs : -3.0e38f;
    float e15 = (kb + 51 < Mr) ? s3.w * cs : -3.0e38f;
    float tm = fmaxf(fmaxf(fmaxf(fmaxf(e0, e1), fmaxf(e2, e3)),
                           fmaxf(fmaxf(e4, e5), fmaxf(e6, e7))),
                     fmaxf(fmaxf(fmaxf(e8, e9), fmaxf(e10, e11)),
                           fmaxf(fmaxf(e12, e13), fmaxf(e14, e15))));
    float mn = fmaxf(m_run, tm);
    float zs = exp2f(e0 - mn)  + exp2f(e1 - mn)  + exp2f(e2 - mn)  + exp2f(e3 - mn)
             + exp2f(e4 - mn)  + exp2f(e5 - mn)  + exp2f(e6 - mn)  + exp2f(e7 - mn)
             + exp2f(e8 - mn)  + exp2f(e9 - mn)  + exp2f(e10 - mn) + exp2f(e11 - mn)
             + exp2f(e12 - mn) + exp2f(e13 - mn) + exp2f(e14 - mn) + exp2f(e15 - mn);
    z_run = z_run * exp2f(m_run - mn) + zs;
    m_run = mn;
  }
  // cross-q combine (4 lanes share a q-row: lane, lane^16, lane^32, lane^48)
  float mo = fmaxf(m_run, __shfl_xor(m_run, 16));
  mo = fmaxf(mo, __shfl_xor(mo, 32));
  float zz = z_run * exp2f(m_run - mo);
  zz += __shfl_xor(zz, 16);
  zz += __shfl_xor(zz, 32);
  if (q == 0) {
    float2 st; st.x = mo; st.y = zz;
    rs[(size_t)bh * N + r0 + wave * 16 + mi] = st;
  }
  float pm = 1.f / zz;
  #pragma unroll
  for (int off = 32; off; off >>= 1) pm = fmaxf(pm, __shfl_down(pm, off));
  if (lane == 0) atomicMax(pmax, __float_as_uint(pm));
}

// quantized-prob level: q8 = min(rint(2^(s*cs - mc)), 255), exact in bf16 via shift
DEV ushort q8lvl(float s, float cs, float mc) {
  float p = fminf(rintf(exp2f(fmaf(s, cs, -mc))), 255.f);
  return (ushort)(__float_as_uint(p) >> 16);
}

// ------- attention phase 2: recompute S, quantize probs IN REGISTER, P@V -------
__global__ __launch_bounds__(256) void k_attn2(
    const ushort* __restrict__ qq, const ushort* __restrict__ kq,
    const ushort* __restrict__ vT, const float2* __restrict__ rs,
    const unsigned* __restrict__ pmax, ushort* __restrict__ ao,
    int H, int N, int Mr, int Mpad, int ldq, int ldk, float cs) {
  const int C = 1280;
  __shared__ __align__(16) ushort Qs[64][72];
  __shared__ __align__(16) ushort Ks[64][72];
  __shared__ __align__(16) ushort Vs[64][72];
  __shared__ __align__(16) ushort Ps[64][72];
  int tid = threadIdx.x;
  int wave = tid >> 6, lane = tid & 63;
  int q = lane >> 4, mi = lane & 15;
  int bh = blockIdx.y, b = bh / H, h = bh % H;
  int r0 = blockIdx.x * 64;
  #pragma unroll
  for (int c = tid; c < 512; c += 256) {
    int r = c >> 3, dc = (c & 7) << 3;
    *(int4*)&Qs[r][dc] = *(const int4*)(qq + ((size_t)b * N + r0 + r) * ldq + h * 64 + dc);
  }
  int rbase = wave * 16 + q * 4;   // local q-row base of this lane's C-tile rows
  float delta = fmaxf(__uint_as_float(*pmax), 1e-8f) * (1.f / 255.f);
  float ld = __log2f(delta);
  float2 st0 = rs[(size_t)bh * N + r0 + rbase + 0];
  float2 st1 = rs[(size_t)bh * N + r0 + rbase + 1];
  float2 st2 = rs[(size_t)bh * N + r0 + rbase + 2];
  float2 st3 = rs[(size_t)bh * N + r0 + rbase + 3];
  float mc0 = st0.x + __log2f(st0.y) + ld;
  float mc1 = st1.x + __log2f(st1.y) + ld;
  float mc2 = st2.x + __log2f(st2.y) + ld;
  float mc3 = st3.x + __log2f(st3.y) + ld;
  f32x4 o0 = {}, o1 = {}, o2 = {}, o3 = {};
  int nt = (Mr + 63) >> 6;
  for (int mt = 0; mt < nt; mt++) {
    __syncthreads();
    #pragma unroll
    for (int c = tid; c < 512; c += 256) {
      int mm = c >> 3, dc = (c & 7) << 3;
      int m = mt * 64 + mm;
      int4 val = make_int4(0, 0, 0, 0);
      if (m < Mr) val = *(const int4*)(kq + ((size_t)b * Mr + m) * ldk + h * 64 + dc);
      *(int4*)&Ks[mm][dc] = val;
      *(int4*)&Vs[mm][dc] = *(const int4*)(vT + ((size_t)bh * 64 + mm) * Mpad + mt * 64 + dc);
    }
    __syncthreads();
    f32x4 s0 = {}, s1 = {}, s2 = {}, s3 = {};
    #pragma unroll
    for (int kc = 0; kc < 2; kc++) {
      bf16x8 aq  = *(const bf16x8*)&Qs[wave * 16 + mi][kc * 32 + q * 8];
      bf16x8 k0v = *(const bf16x8*)&Ks[mi][kc * 32 + q * 8];
      bf16x8 k1v = *(const bf16x8*)&Ks[16 + mi][kc * 32 + q * 8];
      bf16x8 k2v = *(const bf16x8*)&Ks[32 + mi][kc * 32 + q * 8];
      bf16x8 k3v = *(const bf16x8*)&Ks[48 + mi][kc * 32 + q * 8];
      MF(aq, k0v, s0); MF(aq, k1v, s1); MF(aq, k2v, s2); MF(aq, k3v, s3);
    }
    // in-register quantize: s_t[reg] = S[rbase+reg][16t+mi]
    int mlim = Mr - mt * 64;
    bool ok0 = (mi      < mlim);
    bool ok1 = (16 + mi < mlim);
    bool ok2 = (32 + mi < mlim);
    bool ok3 = (48 + mi < mlim);
    Ps[rbase + 0][mi]      = ok0 ? q8lvl(s0.x, cs, mc0) : (ushort)0;
    Ps[rbase + 1][mi]      = ok0 ? q8lvl(s0.y, cs, mc1) : (ushort)0;
    Ps[rbase + 2][mi]      = ok0 ? q8lvl(s0.z, cs, mc2) : (ushort)0;
    Ps[rbase + 3][mi]      = ok0 ? q8lvl(s0.w, cs, mc3) : (ushort)0;
    Ps[rbase + 0][16 + mi] = ok1 ? q8lvl(s1.x, cs, mc0) : (ushort)0;
    Ps[rbase + 1][16 + mi] = ok1 ? q8lvl(s1.y, cs, mc1) : (ushort)0;
    Ps[rbase + 2][16 + mi] = ok1 ? q8lvl(s1.z, cs, mc2) : (ushort)0;
    Ps[rbase + 3][16 + mi] = ok1 ? q8lvl(s1.w, cs, mc3) : (ushort)0;
    Ps[rbase + 0][32 + mi] = ok2 ? q8lvl(s2.x, cs, mc0) : (ushort)0;
    Ps[rbase + 1][32 + mi] = ok2 ? q8lvl(s2.y, cs, mc1) : (ushort)0;
    Ps[rbase + 2][32 + mi] = ok2 ? q8lvl(s2.z, cs, mc2) : (ushort)0;
    Ps[rbase + 3][32 + mi] = ok2 ? q8lvl(s2.w, cs, mc3) : (ushort)0;
    Ps[rbase + 0][48 + mi] = ok3 ? q8lvl(s3.x, cs, mc0) : (ushort)0;
    Ps[rbase + 1][48 + mi] = ok3 ? q8lvl(s3.y, cs, mc1) : (ushort)0;
    Ps[rbase + 2][48 + mi] = ok3 ? q8lvl(s3.z, cs, mc2) : (ushort)0;
    Ps[rbase + 3][48 + mi] = ok3 ? q8lvl(s3.w, cs, mc3) : (ushort)0;
    // wave-local RAW through LDS: rows 16w..16w+15 written & read by wave w only.
    asm volatile("s_waitcnt lgkmcnt(0)" ::: "memory");
    __builtin_amdgcn_sched_barrier(0);
    #pragma unroll
    for (int kc = 0; kc < 2; kc++) {
      bf16x8 ap = *(const bf16x8*)&Ps[wave * 16 + mi][kc * 32 + q * 8];
      bf16x8 v0 = *(const bf16x8*)&Vs[mi][kc * 32 + q * 8];
      bf16x8 v1 = *(const bf16x8*)&Vs[16 + mi][kc * 32 + q * 8];
      bf16x8 v2 = *(const bf16x8*)&Vs[32 + mi][kc * 32 + q * 8];
      bf16x8 v3 = *(const bf16x8*)&Vs[48 + mi][kc * 32 + q * 8];
      MF(ap, v0, o0); MF(ap, v1, o1); MF(ap, v2, o2); MF(ap, v3, o3);
    }
  }
  int rr = r0 + wave * 16 + q * 4;
  size_t base = ((size_t)b * N + rr) * C + h * 64 + mi;
  ao[base]              = f2b(o0.x * delta); ao[base + C]          = f2b(o0.y * delta);
  ao[base + 2 * C]      = f2b(o0.z * delta); ao[base + 3 * C]      = f2b(o0.w * delta);
  ao[base + 16]         = f2b(o1.x * delta); ao[base + C + 16]     = f2b(o1.y * delta);
  ao[base + 2 * C + 16] = f2b(o1.z * delta); ao[base + 3 * C + 16] = f2b(o1.w * delta);
  ao[base + 32]         = f2b(o2.x * delta); ao[base + C + 32]     = f2b(o2.y * delta);
  ao[base + 2 * C + 32] = f2b(o2.z * delta); ao[base + 3 * C + 32] = f2b(o2.w * delta);
  ao[base + 48]         = f2b(o3.x * delta); ao[base + C + 48]     = f2b(o3.y * delta);
  ao[base + 2 * C + 48] = f2b(o3.z * delta); ao[base + 3 * C + 48] = f2b(o3.w * delta);
}

// =====================================================================
// shared pipeline macros (T2 xor-swizzle + counted vmcnt + setprio)
// =====================================================================
#define BAR __builtin_amdgcn_s_barrier()
#define LGKM0 do { asm volatile("s_waitcnt lgkmcnt(0)" ::: "memory"); \
                   __builtin_amdgcn_sched_barrier(0); } while (0)
#define VM6 asm volatile("s_waitcnt vmcnt(6)" ::: "memory")
#define VM0 asm volatile("s_waitcnt vmcnt(0)" ::: "memory")
#define PRIO1 __builtin_amdgcn_s_setprio(1)
#define PRIO0 __builtin_amdgcn_s_setprio(0)

#define RDA01(P) do { \
  fa00 = *(const bf16x8*)&(P)[c0];        fa01 = *(const bf16x8*)&(P)[c1]; \
  fa10 = *(const bf16x8*)&(P)[1024 + c0]; fa11 = *(const bf16x8*)&(P)[1024 + c1]; } while (0)
#define RDA23(P) do { \
  fa20 = *(const bf16x8*)&(P)[2048 + c0]; fa21 = *(const bf16x8*)&(P)[2048 + c1]; \
  fa30 = *(const bf16x8*)&(P)[3072 + c0]; fa31 = *(const bf16x8*)&(P)[3072 + c1]; } while (0)
#define RDB(P, H) do { \
  b00 = *(const bf16x8*)&(P)[(H) + c0];        b01 = *(const bf16x8*)&(P)[(H) + c1]; \
  b10 = *(const bf16x8*)&(P)[(H) + 1024 + c0]; b11 = *(const bf16x8*)&(P)[(H) + 1024 + c1]; \
  b20 = *(const bf16x8*)&(P)[(H) + 2048 + c0]; b21 = *(const bf16x8*)&(P)[(H) + 2048 + c1]; \
  b30 = *(const bf16x8*)&(P)[(H) + 3072 + c0]; b31 = *(const bf16x8*)&(P)[(H) + 3072 + c1]; } while (0)
#define RDB8(P) RDB(P, 0)

#define MM8(AX0, AX1, AY0, AY1, C0, C1, C2, C3, D0, D1, D2, D3) \
  MF(AX0, b00, C0); MF(AX1, b01, C0); MF(AX0, b10, C1); MF(AX1, b11, C1); \
  MF(AX0, b20, C2); MF(AX1, b21, C2); MF(AX0, b30, C3); MF(AX1, b31, C3); \
  MF(AY0, b00, D0); MF(AY1, b01, D0); MF(AY0, b10, D1); MF(AY1, b11, D1); \
  MF(AY0, b20, D2); MF(AY1, b21, D2); MF(AY0, b30, D3); MF(AY1, b31, D3)

// =====================================================================
// k_gemm8: 8-wave 256x128-tile NT GEMM, BK=64, TRIPLE-buffered LDS (144 KiB),
// 2 phases/K-tile of 16 MFMA, counted vmcnt(6) (never 0 in main loop).
// Requires M%256==0, N%128==0, K%64==0, K/64>=5, (K/64-2)%3==0, blocks%8==0.
// =====================================================================
#define GB8(AP, BP, DB, KT) \
  RDA01(AP); RDB8(BP); \
  stB(DB, KT, 0); stB(DB, KT, 1); stA(DB, KT, 0); \
  BAR; LGKM0; \
  PRIO1; MM8(fa00, fa01, fa10, fa11, c00, c01, c02, c03, c10, c11, c12, c13); PRIO0; \
  BAR; \
  RDA23(AP); \
  stA(DB, KT, 1); stA(DB, KT, 2); stA(DB, KT, 3); \
  BAR; LGKM0; \
  PRIO1; MM8(fa20, fa21, fa30, fa31, c20, c21, c22, c23, c30, c31, c32, c33); PRIO0; \
  VM6; BAR;

#define GT8(AP, BP) \
  RDA01(AP); RDB8(BP); \
  BAR; LGKM0; \
  PRIO1; MM8(fa00, fa01, fa10, fa11, c00, c01, c02, c03, c10, c11, c12, c13); PRIO0; \
  BAR; \
  RDA23(AP); \
  BAR; LGKM0; \
  PRIO1; MM8(fa20, fa21, fa30, fa31, c20, c21, c22, c23, c30, c31, c32, c33); PRIO0;

__global__ __launch_bounds__(512) void k_gemm8(
    const ushort* __restrict__ A, int lda,
    const ushort* __restrict__ BT, int ldb,
    float* __restrict__ Cf, ushort* __restrict__ Cb, int ldc,
    const float* __restrict__ bias, const float* __restrict__ resid,
    unsigned* am_slot, int M, int N, int K, int slcN) {
  // per buf (24576 ushorts): A[256][64] @0, B[128][64] @16384. Swizzle: col ^= (row&7)*8.
  __shared__ __align__(16) ushort SAB[73728];  // 144 KiB, 3 bufs
  int tid = threadIdx.x;
  int wave = tid >> 6, lane = tid & 63;
  int q = lane >> 4, mi = lane & 15;
  int wm = wave >> 1, wn = wave & 1;
  int lr = lane >> 3;
  int lc = ((lane & 7) ^ lr) * 8;   // inverse-swizzled source col (elems)

  int NBN = N >> 7;
  int nblk = (M >> 8) * NBN;
  int cpx = nblk >> 3;
  int wg = blockIdx.x;
  int swz = (wg & 7) * cpx + (wg >> 3);   // bijective: nblk % 8 == 0
  int bm0 = (swz / NBN) << 8, bn0 = (swz % NBN) << 7;

  const int swzr = (mi & 7) * 8;
  int c0 = (q * 8) ^ swzr, c1 = (32 + q * 8) ^ swzr;
  const ushort* A0p = &SAB[(wm * 64 + mi) * 64];
  const ushort* B0p = &SAB[16384 + (wn * 64 + mi) * 64];
  const ushort* A1p = A0p + 24576; const ushort* B1p = B0p + 24576;
  const ushort* A2p = A0p + 49152; const ushort* B2p = B0p + 49152;

  const ushort* gA = A  + (size_t)(bm0 + wave * 8 + lr) * lda + lc;
  const ushort* gB = BT + (size_t)(bn0 + wave * 8 + lr) * ldb + lc;
  ushort* lA = &SAB[wave * 512];
  ushort* lB = &SAB[16384 + wave * 512];

  auto stA = [&](int bb, int kt, int call) {   // A: 4 calls x 64 rows
    gl_lds16(lA + bb * 24576 + call * 4096,
             gA + (size_t)call * 64 * lda + (size_t)kt * 64);
  };
  auto stB = [&](int bb, int kt, int call) {   // B: 2 calls x 64 rows
    gl_lds16(lB + bb * 24576 + call * 4096,
             gB + (size_t)call * 64 * ldb + (size_t)kt * 64);
  };

  f32x4 c00 = {}, c01 = {}, c02 = {}, c03 = {};
  f32x4 c10 = {}, c11 = {}, c12 = {}, c13 = {};
  f32x4 c20 = {}, c21 = {}, c22 = {}, c23 = {};
  f32x4 c30 = {}, c31 = {}, c32 = {}, c33 = {};
  bf16x8 fa00, fa01, fa10, fa11, fa20, fa21, fa30, fa31;
  bf16x8 b00, b01, b10, b11, b20, b21, b30, b31;

  // prologue: tile0 -> buf0, tile1 -> buf1 (6 calls each)
  stB(0, 0, 0); stB(0, 0, 1);
  stA(0, 0, 0); stA(0, 0, 1); stA(0, 0, 2); stA(0, 0, 3);
  stB(1, 1, 0); stB(1, 1, 1);
  stA(1, 1, 0); stA(1, 1, 1); stA(1, 1, 2); stA(1, 1, 3);
  VM6; BAR;

  int NT = K >> 6, NTm = NT - 2;  // NTm % 3 == 0 by contract
  for (int t = 0; t < NTm; t += 3) {
    GB8(A0p, B0p, 2, t + 2);
    GB8(A1p, B1p, 0, t + 3);
    GB8(A2p, B2p, 1, t + 4);
  }
  // tail: tile NT-2 (buf0), then tile NT-1 (buf1)
  GT8(A0p, B0p);
  VM0; BAR;
  GT8(A1p, B1p);

  int rb = bm0 + wm * 64 + q * 4, cb = bn0 + wn * 64 + mi;
  float am = 0.f;
  am = fmaxf(am, epi4(c00, rb +  0, cb +  0, M, N, ldc, bias, resid, Cf, Cb));
  am = fmaxf(am, epi4(c01, rb +  0, cb + 16, M, N, ldc, bias, resid, Cf, Cb));
  am = fmaxf(am, epi4(c02, rb +  0, cb + 32, M, N, ldc, bias, resid, Cf, Cb));
  am = fmaxf(am, epi4(c03, rb +  0, cb + 48, M, N, ldc, bias, resid, Cf, Cb));
  am = fmaxf(am, epi4(c10, rb + 16, cb +  0, M, N, ldc, bias, resid, Cf, Cb));
  am = fmaxf(am, epi4(c11, rb + 16, cb + 16, M, N, ldc, bias, resid, Cf, Cb));
  am = fmaxf(am, epi4(c12, rb + 16, cb + 32, M, N, ldc, bias, resid, Cf, Cb));
  am = fmaxf(am, epi4(c13, rb + 16, cb + 48, M, N, ldc, bias, resid, Cf, Cb));
  am = fmaxf(am, epi4(c20, rb + 32, cb +  0, M, N, ldc, bias, resid, Cf, Cb));
  am = fmaxf(am, epi4(c21, rb + 32, cb + 16, M, N, ldc, bias, resid, Cf, Cb));
  am = fmaxf(am, epi4(c22, rb + 32, cb + 32, M, N, ldc, bias, resid, Cf, Cb));
  am = fmaxf(am, epi4(c23, rb + 32, cb + 48, M, N, ldc, bias, resid, Cf, Cb));
  am = fmaxf(am, epi4(c30, rb + 48, cb +  0, M, N, ldc, bias, resid, Cf, Cb));
  am = fmaxf(am, epi4(c31, rb + 48, cb + 16, M, N, ldc, bias, resid, Cf, Cb));
  am = fmaxf(am, epi4(c32, rb + 48, cb + 32, M, N, ldc, bias, resid, Cf, Cb));
  am = fmaxf(am, epi4(c33, rb + 48, cb + 48, M, N, ldc, bias, resid, Cf, Cb));
  if (am_slot) {
    #pragma unroll
    for (int off = 32; off; off >>= 1) am = fmaxf(am, __shfl_down(am, off));
    if (lane == 0) atomicMax(am_slot + bn0 / slcN, __float_as_uint(am));
  }
}

// =====================================================================
// fused FF1 + GEGLU, 256x128(GG) tile, BK=64, 8 waves, 8-phase schedule
// =====================================================================
// gelu-tanh via sigmoid identity: 0.5*(1+tanh(x)) == sigmoid(2x)
DEV ushort ggel(float a, float g) {
  float u = 1.5957691216057308f * g * (1.f + 0.044715f * g * g);
  float s = 1.f / (1.f + __expf(-u));
  return f2b(a * g * s);
}
DEV void epi4g(f32x4 va, f32x4 vg, size_t base, float ba, float bg,
               ushort* __restrict__ GG) {
  GG[base]         = ggel(va.x + ba, vg.x + bg);
  GG[base + 5120]  = ggel(va.y + ba, vg.y + bg);
  GG[base + 10240] = ggel(va.z + ba, vg.z + bg);
  GG[base + 15360] = ggel(va.w + ba, vg.w + bg);
}
#define EPIN(nn, P0, Q0, P1, Q1, P2, Q2, P3, Q3) do { \
  int cg = colBase + nn * 16 + mi; \
  float ba = bias[cg], bg = bias[5120 + cg]; \
  size_t b0_ = (size_t)rowBase * 5120 + cg; \
  epi4g(P0, Q0, b0_,             ba, bg, GG); \
  epi4g(P1, Q1, b0_ + 16 * 5120, ba, bg, GG); \
  epi4g(P2, Q2, b0_ + 32 * 5120, ba, bg, GG); \
  epi4g(P3, Q3, b0_ + 48 * 5120, ba, bg, GG); \
} while (0)

__global__ __launch_bounds__(512) void k_ff1_8p(
    const ushort* __restrict__ A,    // LN [8192][1280]
    const ushort* __restrict__ BT,   // WF1T [10240][1280]
    const float* __restrict__ bias,  // bff1 [10240]
    ushort* __restrict__ GG) {       // [8192][5120]
  __shared__ __align__(16) ushort SAB[65536];  // 128 KiB
  int tid = threadIdx.x;
  int wave = tid >> 6, lane = tid & 63;
  int q = lane >> 4, mi = lane & 15;
  int wm = wave >> 1, wn = wave & 1;
  int lr = lane >> 3;
  int lc = ((lane & 7) ^ lr) * 8;  // inverse-swizzled source col (elems)

  int wg = blockIdx.x;
  int swz = (wg & 7) * 160 + (wg >> 3);
  int bm0 = (swz & 31) * 256, bn0 = (swz >> 5) * 128;

  const int swzr = (mi & 7) * 8;
  int c0 = (q * 8) ^ swzr, c1 = (32 + q * 8) ^ swzr;
  const ushort* A0p = &SAB[(wm * 64 + mi) * 64];
  const ushort* B0p = &SAB[16384 + (wn * 64 + mi) * 64];
  const ushort* A1p = A0p + 32768;
  const ushort* B1p = B0p + 32768;

  const ushort* gA  = A  + (size_t)(bm0 + wave * 8 + lr) * 1280 + lc;
  const ushort* gBa = BT + (size_t)(bn0 + wave * 8 + lr) * 1280 + lc;
  const ushort* gBg = BT + (size_t)(5120 + bn0 + wave * 8 + lr) * 1280 + lc;
  ushort* lA = &SAB[wave * 512];
  ushort* lB = &SAB[16384 + wave * 512];

  auto stA = [&](int bb, int kt, int call) {
    gl_lds16(lA + bb * 32768 + call * 4096,
             gA + (size_t)call * 81920 + (size_t)kt * 64);
  };
  auto stBa = [&](int bb, int kt, int call) {
    gl_lds16(lB + bb * 32768 + call * 4096,
             gBa + (size_t)call * 81920 + (size_t)kt * 64);
  };
  auto stBg = [&](int bb, int kt, int call) {
    gl_lds16(lB + bb * 32768 + (call + 2) * 4096,
             gBg + (size_t)call * 81920 + (size_t)kt * 64);
  };

  f32x4 cA00 = {}, cA01 = {}, cA02 = {}, cA03 = {};
  f32x4 cA10 = {}, cA11 = {}, cA12 = {}, cA13 = {};
  f32x4 cA20 = {}, cA21 = {}, cA22 = {}, cA23 = {};
  f32x4 cA30 = {}, cA31 = {}, cA32 = {}, cA33 = {};
  f32x4 cG00 = {}, cG01 = {}, cG02 = {}, cG03 = {};
  f32x4 cG10 = {}, cG11 = {}, cG12 = {}, cG13 = {};
  f32x4 cG20 = {}, cG21 = {}, cG22 = {}, cG23 = {};
  f32x4 cG30 = {}, cG31 = {}, cG32 = {}, cG33 = {};
  bf16x8 fa00, fa01, fa10, fa11, fa20, fa21, fa30, fa31;
  bf16x8 b00, b01, b10, b11, b20, b21, b30, b31;

  stBa(0, 0, 0); stBa(0, 0, 1); stBg(0, 0, 0); stBg(0, 0, 1);
  stA(0, 0, 0); stA(0, 0, 1); stA(0, 0, 2); stA(0, 0, 3);
  stBa(1, 1, 0); stBa(1, 1, 1);
  stA(1, 1, 0); stA(1, 1, 1); stA(1, 1, 2); stA(1, 1, 3);
  VM6; BAR;

  for (int it = 0; it < 10; ++it) {
    int t1 = 2 * it + 1;
    int s0 = t1 + 1; if (s0 > 19) s0 = 19;
    int s1 = t1 + 2; if (s1 > 19) s1 = 19;
    // ---- P1: buf0 m01 x Ba ----
    RDA01(A0p); RDB(B0p, 0);
    stBg(1, t1, 0); stBg(1, t1, 1);
    BAR; LGKM0;
    PRIO1; MM8(fa00, fa01, fa10, fa11, cA00, cA01, cA02, cA03,
               cA10, cA11, cA12, cA13); PRIO0;
    BAR;
    // ---- P2: buf0 m23 x Ba ----
    RDA23(A0p);
    stBa(0, s0, 0); stBa(0, s0, 1);
    BAR; LGKM0;
    PRIO1; MM8(fa20, fa21, fa30, fa31, cA20, cA21, cA22, cA23,
               cA30, cA31, cA32, cA33); PRIO0;
    BAR;
    // ---- P3: buf0 m01 x Bg ----
    RDB(B0p, 8192);
    stA(0, s0, 0); stA(0, s0, 1);
    BAR; LGKM0;
    PRIO1; MM8(fa00, fa01, fa10, fa11, cG00, cG01, cG02, cG03,
               cG10, cG11, cG12, cG13); PRIO0;
    BAR;
    // ---- P4: buf0 m23 x Bg ----
    stA(0, s0, 2); stA(0, s0, 3);
    BAR;
    PRIO1; MM8(fa20, fa21, fa30, fa31, cG20, cG21, cG22, cG23,
               cG30, cG31, cG32, cG33); PRIO0;
    VM6; BAR;
    // ---- P5: buf1 m01 x Ba ----
    RDA01(A1p); RDB(B1p, 0);
    stBg(0, s0, 0); stBg(0, s0, 1);
    BAR; LGKM0;
    PRIO1; MM8(fa00, fa01, fa10, fa11, cA00, cA01, cA02, cA03,
               cA10, cA11, cA12, cA13); PRIO0;
    BAR;
    // ---- P6: buf1 m23 x Ba ----
    RDA23(A1p);
    stBa(1, s1, 0); stBa(1, s1, 1);
    BAR; LGKM0;
    PRIO1; MM8(fa20, fa21, fa30, fa31, cA20, cA21, cA22, cA23,
               cA30, cA31, cA32, cA33); PRIO0;
    BAR;
    // ---- P7: buf1 m01 x Bg ----
    RDB(B1p, 8192);
    stA(1, s1, 0); stA(1, s1, 1);
    BAR; LGKM0;
    PRIO1; MM8(fa00, fa01, fa10, fa11, cG00, cG01, cG02, cG03,
               cG10, cG11, cG12, cG13); PRIO0;
    BAR;
    // ---- P8: buf1 m23 x Bg ----
    stA(1, s1, 2); stA(1, s1, 3);
    BAR;
    PRIO1; MM8(fa20, fa21, fa30, fa31, cG20, cG21, cG22, cG23,
               cG30, cG31, cG32, cG33); PRIO0;
    VM6; BAR;
  }

  int colBase = bn0 + wn * 64;
  int rowBase = bm0 + wm * 64 + q * 4;
  EPIN(0, cA00, cG00, cA10, cG10, cA20, cG20, cA30, cG30);
  EPIN(1, cA01, cG01, cA11, cG11, cA21, cG21, cA31, cG31);
  EPIN(2, cA02, cG02, cA12, cG12, cA22, cG22, cA32, cG32);
  EPIN(3, cA03, cG03, cA13, cG13, cA23, cG23, cA33, cG33);
}

extern "C" void kernel_launch(void* const* d_in, const int* in_sizes, int n_in,
                              void* d_out, int out_size, void* d_ws, size_t ws_size,
                              hipStream_t stream) {
  const float* x_in = (const float*)d_in[0];
  const float* ctx  = (const float*)d_in[1];
  const float* ln1g = (const float*)d_in[2];
  const float* ln1b = (const float*)d_in[3];
  const float* ln2g = (const float*)d_in[4];
  const float* ln2b = (const float*)d_in[5];
  const float* ln3g = (const float*)d_in[6];
  const float* ln3b = (const float*)d_in[7];
  const float* Wq1  = (const float*)d_in[8];
  const float* Wk1  = (const float*)d_in[9];
  const float* Wv1  = (const float*)d_in[10];
  const float* Wo1  = (const float*)d_in[11];
  const float* bo1  = (const float*)d_in[12];
  const float* Wq2  = (const float*)d_in[13];
  const float* Wk2  = (const float*)d_in[14];
  const float* Wv2  = (const float*)d_in[15];
  const float* Wo2  = (const float*)d_in[16];
  const float* bo2  = (const float*)d_in[17];
  const float* Wff1 = (const float*)d_in[18];
  const float* bff1 = (const float*)d_in[19];
  const float* Wff2 = (const float*)d_in[20];
  const float* bff2 = (const float*)d_in[21];
  float* out = (float*)d_out;   // also doubles as the fp32 residual stream "xcur"

  const int NR = 8192;   // B*N
  const int C = 1280, H = 20, Nseq = 1024, CC = 768;
  const int MR2 = 616;   // B*M (cross rows)
  const float CS = 0.18033688011112042f;  // 0.125 * log2(e)

  char* ws = (char*)d_ws;
  size_t off = 0;
  auto alloc = [&](size_t bytes) -> void* {
    void* p = ws + off;
    off += (bytes + 255) & ~(size_t)255;
    return p;
  };
  unsigned* scal = (unsigned*)alloc(64);
  // NOTE: Wq1T/Wk1T/Wv1T contiguous (each C*C*2 = 3,276,800, 256-mult) -> WQKV1T [3840][1280]
  ushort* Wq1T  = (ushort*)alloc((size_t)C * C * 2);
  ushort* Wk1T  = (ushort*)alloc((size_t)C * C * 2);
  ushort* Wv1T  = (ushort*)alloc((size_t)C * C * 2);
  ushort* Wo1T  = (ushort*)alloc((size_t)C * C * 2);
  ushort* Wq2T  = (ushort*)alloc((size_t)C * C * 2);
  // Wk2T/Wv2T contiguous (each C*CC*2 = 1,966,080, 256-mult) -> WKV2T [2560][768]
  ushort* Wk2T  = (ushort*)alloc((size_t)C * CC * 2);
  ushort* Wv2T  = (ushort*)alloc((size_t)C * CC * 2);
  ushort* Wo2T  = (ushort*)alloc((size_t)C * C * 2);
  ushort* WF1T  = (ushort*)alloc((size_t)10240 * C * 2);
  ushort* WF2T  = (ushort*)alloc((size_t)C * 5120 * 2);
  ushort* LN    = (ushort*)alloc((size_t)NR * C * 2);   // also AO (attn output)
  size_t regionR = off;  // attention region; stage-3 GG overlays it
  ushort* QKV   = (ushort*)alloc((size_t)NR * 3840 * 2);  // packed Q|K|V, ld=3840
  ushort* VT    = (ushort*)alloc((size_t)160 * 64 * 1024 * 2);
  float2* RS    = (float2*)alloc((size_t)160 * 1024 * 8);
  ushort* CTXB  = (ushort*)alloc((size_t)MR2 * CC * 2);
  ushort* KV2   = (ushort*)alloc((size_t)MR2 * 2560 * 2);  // packed K|V cross, ld=2560
  size_t need = off;
  ushort* AO = LN;                       // alias: LN dead once QKV gemm ran
  ushort* GG = (ushort*)(ws + regionR);  // 84 MB, overlays QKV..KV2 in stage 3
  if (ws_size < need) return;  // diagnostic: absmax==poison => ws too small

  // --- init & weight prep ---
  k_zero<<<1, 64, 0, stream>>>(scal, 8);
  k_wt<<<dim3(40, 40), 256, 0, stream>>>(Wq1, Wq1T, C, C);
  k_wt<<<dim3(40, 40), 256, 0, stream>>>(Wk1, Wk1T, C, C);
  k_wt<<<dim3(40, 40), 256, 0, stream>>>(Wv1, Wv1T, C, C);
  k_wt<<<dim3(40, 40), 256, 0, stream>>>(Wo1, Wo1T, C, C);
  k_wt<<<dim3(40, 40), 256, 0, stream>>>(Wq2, Wq2T, C, C);
  k_wt<<<dim3(40, 24), 256, 0, stream>>>(Wk2, Wk2T, CC, C);
  k_wt<<<dim3(40, 24), 256, 0, stream>>>(Wv2, Wv2T, CC, C);
  k_wt<<<dim3(40, 40), 256, 0, stream>>>(Wo2, Wo2T, C, C);
  k_wt<<<dim3(320, 40), 256, 0, stream>>>(Wff1, WF1T, C, 10240);
  k_wt<<<dim3(40, 160), 256, 0, stream>>>(Wff2, WF2T, 5120, C);

  // ================= stage 1: self-attention =================
  k_ln<<<NR, 256, 0, stream>>>(x_in, ln1g, ln1b, LN);
  // fused Q|K|V gemm: N=3840, grid 960 (93.75% CU util vs 62.5% for 3x320)
  k_gemm8<<<dim3(960), 512, 0, stream>>>(LN, C, Wq1T, C, nullptr, QKV, 3840,
                                         nullptr, nullptr, scal + 0, NR, 3840, C, 1280);
  k_quant3<<<(NR * 3840 + 255) / 256, 256, 0, stream>>>(QKV, QKV, scal + 0,
                                                        NR * 3840, 3840, 3840, 1280);
  k_vt<<<dim3(16, 160), 256, 0, stream>>>(QKV + 2560, VT, H, 1024, 1024, 3840);
  k_attn1<<<dim3(16, 160), 256, 0, stream>>>(QKV, QKV + 1280, RS, scal + 3,
                                             H, Nseq, 1024, 3840, 3840, CS);
  k_attn2<<<dim3(16, 160), 256, 0, stream>>>(QKV, QKV + 1280, VT, RS, scal + 3, AO,
                                             H, Nseq, 1024, 1024, 3840, 3840, CS);
  k_gemm8<<<dim3(320), 512, 0, stream>>>(AO, C, Wo1T, C, out, nullptr, C,
                                         bo1, x_in, nullptr, NR, C, C, C);

  // ================= stage 2: cross-attention =================
  k_ln<<<NR, 256, 0, stream>>>(out, ln2g, ln2b, LN);
  k_gemm8<<<dim3(320), 512, 0, stream>>>(LN, C, Wq2T, C, nullptr, QKV, 3840,
                                         nullptr, nullptr, scal + 4, NR, C, C, C);
  k_quant3<<<(NR * C + 255) / 256, 256, 0, stream>>>(QKV, QKV, scal + 4,
                                                     NR * C, 1280, 3840, 1280);
  k_cvt<<<(MR2 * CC + 255) / 256, 256, 0, stream>>>(ctx, CTXB, MR2 * CC);
  // fused K|V cross gemm: N=2560
  k_gemm<<<dim3(20, 5), 256, 0, stream>>>(CTXB, CC, Wk2T, CC, nullptr, KV2, 2560,
                                          nullptr, nullptr, scal + 5, MR2, 2560, CC, 1280);
  k_quant3<<<(MR2 * 2560 + 255) / 256, 256, 0, stream>>>(KV2, KV2, scal + 5,
                                                         MR2 * 2560, 2560, 2560, 1280);
  k_vt<<<dim3(2, 160), 256, 0, stream>>>(KV2 + 1280, VT, H, 77, 128, 2560);
  k_attn1<<<dim3(16, 160), 256, 0, stream>>>(QKV, KV2, RS, scal + 7,
                                             H, Nseq, 77, 3840, 2560, CS);
  k_attn2<<<dim3(16, 160), 256, 0, stream>>>(QKV, KV2, VT, RS, scal + 7, AO,
                                             H, Nseq, 77, 128, 3840, 2560, CS);
  k_gemm8<<<dim3(320), 512, 0, stream>>>(AO, C, Wo2T, C, out, nullptr, C,
                                         bo2, out, nullptr, NR, C, C, C);

  // ================= stage 3: GEGLU FF (fused, 8-phase) =================
  k_ln<<<NR, 256, 0, stream>>>(out, ln3g, ln3b, LN);
  k_ff1_8p<<<dim3(1280), 512, 0, stream>>>(LN, WF1T, bff1, GG);
  k_gemm8<<<dim3(320), 512, 0, stream>>>(GG, 5120, WF2T, 5120, out, nullptr, C,
                                         bff2, out, nullptr, NR, C, 5120, C);
}

// Round 6
// 1551.342 us; speedup vs baseline: 1.2459x; 1.0865x over previous
//
#include <hip/hip_runtime.h>

typedef __attribute__((ext_vector_type(8))) short bf16x8;
typedef __attribute__((ext_vector_type(4))) float f32x4;

#define DEV __device__ __forceinline__
#define MF(A, B, CACC) CACC = __builtin_amdgcn_mfma_f32_16x16x32_bf16(A, B, CACC, 0, 0, 0)

DEV ushort f2b(float f) {
  unsigned u = __float_as_uint(f);
  u += 0x7fffu + ((u >> 16) & 1u);   // RNE to bf16
  return (ushort)(u >> 16);
}
DEV float b2f(ushort u) { return __uint_as_float(((unsigned)u) << 16); }

// async global->LDS, 16B per lane; lds base must be wave-uniform (HW adds lane*16)
DEV void gl_lds16(ushort* lds_base, const ushort* gp) {
  __builtin_amdgcn_global_load_lds(
      (__attribute__((address_space(1))) const void*)gp,
      (__attribute__((address_space(3))) void*)lds_base, 16, 0, 0);
}

// ---------------- zero scalar slots ----------------
__global__ void k_zero(unsigned* p, int n) {
  int i = blockIdx.x * blockDim.x + threadIdx.x;
  if (i < n) p[i] = 0u;
}

// ------------- weight transpose fp32 W[K][N] -> bf16 WT[N][K] -------------
__global__ __launch_bounds__(256) void k_wt(const float* __restrict__ W,
                                            ushort* __restrict__ WT, int K, int N) {
  __shared__ float T[32][33];
  int k0 = blockIdx.y * 32, n0 = blockIdx.x * 32;
  int tx = threadIdx.x & 31, ty = threadIdx.x >> 5;
  #pragma unroll
  for (int r = ty; r < 32; r += 8) {
    int k = k0 + r, n = n0 + tx;
    T[r][tx] = (k < K && n < N) ? W[(size_t)k * N + n] : 0.f;
  }
  __syncthreads();
  #pragma unroll
  for (int r = ty; r < 32; r += 8) {
    int n = n0 + r, k = k0 + tx;
    if (n < N && k < K) WT[(size_t)n * K + k] = f2b(T[tx][r]);
  }
}

// ---------------- f32 -> bf16 elementwise ----------------
__global__ void k_cvt(const float* __restrict__ in, ushort* __restrict__ out, int n) {
  int i = blockIdx.x * 256 + threadIdx.x;
  if (i < n) out[i] = f2b(in[i]);
}

// ---------------- layernorm (C==1280), out bf16 ----------------
__global__ __launch_bounds__(256) void k_ln(const float* __restrict__ x,
    const float* __restrict__ g, const float* __restrict__ b,
    ushort* __restrict__ out) {
  const int C = 1280;
  int row = blockIdx.x, tid = threadIdx.x;
  const float* xr = x + (size_t)row * C;
  float v0 = xr[tid], v1 = xr[tid + 256], v2 = xr[tid + 512],
        v3 = xr[tid + 768], v4 = xr[tid + 1024];
  float s = v0 + v1 + v2 + v3 + v4;
  float ss = v0 * v0 + v1 * v1 + v2 * v2 + v3 * v3 + v4 * v4;
  #pragma unroll
  for (int off = 32; off; off >>= 1) {
    s += __shfl_down(s, off);
    ss += __shfl_down(ss, off);
  }
  __shared__ float red[8];
  __shared__ float mu_s, rstd_s;
  int wave = tid >> 6, lane = tid & 63;
  if (lane == 0) { red[wave] = s; red[4 + wave] = ss; }
  __syncthreads();
  if (tid == 0) {
    float S = red[0] + red[1] + red[2] + red[3];
    float SS = red[4] + red[5] + red[6] + red[7];
    float mu = S / C;
    float var = SS / C - mu * mu;
    mu_s = mu;
    rstd_s = rsqrtf(var + 1e-5f);
  }
  __syncthreads();
  float mu = mu_s, rstd = rstd_s;
  size_t o = (size_t)row * C + tid;
  out[o]        = f2b((v0 - mu) * rstd * g[tid]        + b[tid]);
  out[o + 256]  = f2b((v1 - mu) * rstd * g[tid + 256]  + b[tid + 256]);
  out[o + 512]  = f2b((v2 - mu) * rstd * g[tid + 512]  + b[tid + 512]);
  out[o + 768]  = f2b((v3 - mu) * rstd * g[tid + 768]  + b[tid + 768]);
  out[o + 1024] = f2b((v4 - mu) * rstd * g[tid + 1024] + b[tid + 1024]);
}

// ---- GEMM epilogue helpers (by-value f32x4, constant swizzles: SROA-proof) ----
DEV void st1(float v, int r_, int c_, int ldc, const float* resid,
             float* Cf, ushort* Cb) {
  size_t o = (size_t)r_ * ldc + c_;
  if (resid) v += resid[o];
  if (Cf) Cf[o] = v;
  if (Cb) Cb[o] = f2b(v);
}
DEV float epi4(f32x4 v, int rbase, int c_, int M, int N, int ldc,
               const float* bias, const float* resid, float* Cf, ushort* Cb) {
  float v0 = v.x, v1 = v.y, v2 = v.z, v3 = v.w;
  float am = fmaxf(fmaxf(fabsf(v0), fabsf(v1)), fmaxf(fabsf(v2), fabsf(v3)));
  if (c_ < N) {
    float bb = bias ? bias[c_] : 0.f;
    v0 += bb; v1 += bb; v2 += bb; v3 += bb;
    if (rbase + 0 < M) st1(v0, rbase + 0, c_, ldc, resid, Cf, Cb);
    if (rbase + 1 < M) st1(v1, rbase + 1, c_, ldc, resid, Cf, Cb);
    if (rbase + 2 < M) st1(v2, rbase + 2, c_, ldc, resid, Cf, Cb);
    if (rbase + 3 < M) st1(v3, rbase + 3, c_, ldc, resid, Cf, Cb);
  }
  return am;
}

// ---------------- bf16 NT GEMM: C[M,N] = A[M,K] @ BT[N,K]^T ----------------
// 128x128 tile, 4 waves (2x2 of 64x64), 16x16x32 MFMA, BK=32,
// global_load_lds width=16 staging. Used for odd-shaped (M=616) GEMMs.
__global__ __launch_bounds__(256) void k_gemm(
    const ushort* __restrict__ A, int lda,
    const ushort* __restrict__ BT, int ldb,
    float* __restrict__ Cf, ushort* __restrict__ Cb, int ldc,
    const float* __restrict__ bias, const float* __restrict__ resid,
    unsigned* am_slot, int M, int N, int K, int slcN) {
  __shared__ __align__(16) ushort SAB[8192];  // A[128][32] @0, B[128][32] @4096
  int tid = threadIdx.x;
  int wave = tid >> 6, lane = tid & 63;
  int q = lane >> 4, mi = lane & 15;
  int wr = (wave >> 1) * 64, wc = (wave & 1) * 64;
  int bm0 = blockIdx.y * 128, bn0 = blockIdx.x * 128;
  f32x4 c00 = {}, c01 = {}, c02 = {}, c03 = {};
  f32x4 c10 = {}, c11 = {}, c12 = {}, c13 = {};
  f32x4 c20 = {}, c21 = {}, c22 = {}, c23 = {};
  f32x4 c30 = {}, c31 = {}, c32 = {}, c33 = {};
  for (int k0 = 0; k0 < K; k0 += 32) {
    __syncthreads();
    #pragma unroll
    for (int t = 0; t < 4; t++) {
      int c = wave * 256 + t * 64 + lane;
      const ushort* gp;
      if (c < 512) {
        int r = c >> 2, kc = (c & 3) << 3;
        int gr = bm0 + r; if (gr >= M) gr = M - 1;
        gp = A + (size_t)gr * lda + k0 + kc;
      } else {
        int c2 = c - 512;
        int r = c2 >> 2, kc = (c2 & 3) << 3;
        int gn = bn0 + r; if (gn >= N) gn = N - 1;
        gp = BT + (size_t)gn * ldb + k0 + kc;
      }
      gl_lds16(&SAB[(wave * 256 + t * 64) * 8], gp);
    }
    __syncthreads();
    const ushort* Ab = &SAB[(wr + mi) * 32 + q * 8];
    const ushort* Bb = &SAB[4096 + (wc + mi) * 32 + q * 8];
    bf16x8 a0 = *(const bf16x8*)(Ab);
    bf16x8 a1 = *(const bf16x8*)(Ab + 512);
    bf16x8 a2 = *(const bf16x8*)(Ab + 1024);
    bf16x8 a3 = *(const bf16x8*)(Ab + 1536);
    bf16x8 b0 = *(const bf16x8*)(Bb);
    bf16x8 b1 = *(const bf16x8*)(Bb + 512);
    bf16x8 b2 = *(const bf16x8*)(Bb + 1024);
    bf16x8 b3 = *(const bf16x8*)(Bb + 1536);
    MF(a0, b0, c00); MF(a0, b1, c01); MF(a0, b2, c02); MF(a0, b3, c03);
    MF(a1, b0, c10); MF(a1, b1, c11); MF(a1, b2, c12); MF(a1, b3, c13);
    MF(a2, b0, c20); MF(a2, b1, c21); MF(a2, b2, c22); MF(a2, b3, c23);
    MF(a3, b0, c30); MF(a3, b1, c31); MF(a3, b2, c32); MF(a3, b3, c33);
  }
  int rb = bm0 + wr + q * 4, cb = bn0 + wc + mi;
  float am = 0.f;
  am = fmaxf(am, epi4(c00, rb +  0, cb +  0, M, N, ldc, bias, resid, Cf, Cb));
  am = fmaxf(am, epi4(c01, rb +  0, cb + 16, M, N, ldc, bias, resid, Cf, Cb));
  am = fmaxf(am, epi4(c02, rb +  0, cb + 32, M, N, ldc, bias, resid, Cf, Cb));
  am = fmaxf(am, epi4(c03, rb +  0, cb + 48, M, N, ldc, bias, resid, Cf, Cb));
  am = fmaxf(am, epi4(c10, rb + 16, cb +  0, M, N, ldc, bias, resid, Cf, Cb));
  am = fmaxf(am, epi4(c11, rb + 16, cb + 16, M, N, ldc, bias, resid, Cf, Cb));
  am = fmaxf(am, epi4(c12, rb + 16, cb + 32, M, N, ldc, bias, resid, Cf, Cb));
  am = fmaxf(am, epi4(c13, rb + 16, cb + 48, M, N, ldc, bias, resid, Cf, Cb));
  am = fmaxf(am, epi4(c20, rb + 32, cb +  0, M, N, ldc, bias, resid, Cf, Cb));
  am = fmaxf(am, epi4(c21, rb + 32, cb + 16, M, N, ldc, bias, resid, Cf, Cb));
  am = fmaxf(am, epi4(c22, rb + 32, cb + 32, M, N, ldc, bias, resid, Cf, Cb));
  am = fmaxf(am, epi4(c23, rb + 32, cb + 48, M, N, ldc, bias, resid, Cf, Cb));
  am = fmaxf(am, epi4(c30, rb + 48, cb +  0, M, N, ldc, bias, resid, Cf, Cb));
  am = fmaxf(am, epi4(c31, rb + 48, cb + 16, M, N, ldc, bias, resid, Cf, Cb));
  am = fmaxf(am, epi4(c32, rb + 48, cb + 32, M, N, ldc, bias, resid, Cf, Cb));
  am = fmaxf(am, epi4(c33, rb + 48, cb + 48, M, N, ldc, bias, resid, Cf, Cb));
  if (am_slot) {
    #pragma unroll
    for (int off = 32; off; off >>= 1) am = fmaxf(am, __shfl_down(am, off));
    if (lane == 0) atomicMax(am_slot + bn0 / slcN, __float_as_uint(am));
  }
}

// ------- vectorized multi-slice fake-quant: 8 bf16/thread, slot by col -------
__global__ void k_quant8(const ushort* __restrict__ in, ushort* __restrict__ out,
                         const unsigned* __restrict__ slotb, int n8,
                         int colw8, int ld, int slcw) {
  int i = blockIdx.x * 256 + threadIdx.x;
  if (i >= n8) return;
  int row = i / colw8, c8 = i - row * colw8;
  int col = c8 * 8;
  size_t a = (size_t)row * ld + col;
  float delta = fmaxf(__uint_as_float(slotb[col / slcw]), 1e-8f) * (1.f / 127.f);
  bf16x8 v = *(const bf16x8*)(in + a);
  bf16x8 r;
  #pragma unroll
  for (int j = 0; j < 8; j++) {
    float x = b2f((ushort)v[j]);
    float y = fminf(fmaxf(rintf(x / delta), -128.f), 127.f) * delta;
    r[j] = (short)f2b(y);
  }
  *(bf16x8*)(out + a) = r;
}

// ------- V transpose per head: vq[(b*Mr+m)*ldv + h*64+d] -> vT[bh][d][m] (zero-pad) -------
__global__ __launch_bounds__(256) void k_vt(const ushort* __restrict__ vq,
    ushort* __restrict__ vT, int H, int Mr, int Mpad, int ldv) {
  __shared__ __align__(16) ushort T[64][72];
  int bh = blockIdx.y, b = bh / H, h = bh % H;
  int m0 = blockIdx.x * 64;
  int tid = threadIdx.x;
  #pragma unroll
  for (int c = tid; c < 512; c += 256) {
    int mm = c >> 3, dc = (c & 7) << 3;
    int m = m0 + mm;
    int4 val = make_int4(0, 0, 0, 0);
    if (m < Mr) val = *(const int4*)(vq + ((size_t)b * Mr + m) * ldv + h * 64 + dc);
    *(int4*)&T[mm][dc] = val;
  }
  __syncthreads();
  #pragma unroll
  for (int c = tid; c < 512; c += 256) {
    int dd = c >> 3, mc = (c & 7) << 3;
    unsigned w0 = (unsigned)T[mc + 0][dd] | ((unsigned)T[mc + 1][dd] << 16);
    unsigned w1 = (unsigned)T[mc + 2][dd] | ((unsigned)T[mc + 3][dd] << 16);
    unsigned w2 = (unsigned)T[mc + 4][dd] | ((unsigned)T[mc + 5][dd] << 16);
    unsigned w3 = (unsigned)T[mc + 6][dd] | ((unsigned)T[mc + 7][dd] << 16);
    int4 val = make_int4((int)w0, (int)w1, (int)w2, (int)w3);
    *(int4*)(vT + ((size_t)bh * 64 + dd) * Mpad + m0 + mc) = val;
  }
}

#define NEGI -3.0e38f
// online-softmax tile update for one 16-row set (per-row math identical to QBLK=64 version)
#define ONLUPD(SA, SB, SC, SD, MRUN, ZRUN) do { \
  float e0  = b0_  ? (SA).x * cs : NEGI; \
  float e1  = b1_  ? (SA).y * cs : NEGI; \
  float e2  = b2_  ? (SA).z * cs : NEGI; \
  float e3  = b3_  ? (SA).w * cs : NEGI; \
  float e4  = b4_  ? (SB).x * cs : NEGI; \
  float e5  = b5_  ? (SB).y * cs : NEGI; \
  float e6  = b6_  ? (SB).z * cs : NEGI; \
  float e7  = b7_  ? (SB).w * cs : NEGI; \
  float e8  = b8_  ? (SC).x * cs : NEGI; \
  float e9  = b9_  ? (SC).y * cs : NEGI; \
  float e10 = b10_ ? (SC).z * cs : NEGI; \
  float e11 = b11_ ? (SC).w * cs : NEGI; \
  float e12 = b12_ ? (SD).x * cs : NEGI; \
  float e13 = b13_ ? (SD).y * cs : NEGI; \
  float e14 = b14_ ? (SD).z * cs : NEGI; \
  float e15 = b15_ ? (SD).w * cs : NEGI; \
  float tm = fmaxf(fmaxf(fmaxf(fmaxf(e0, e1), fmaxf(e2, e3)), \
                         fmaxf(fmaxf(e4, e5), fmaxf(e6, e7))), \
                   fmaxf(fmaxf(fmaxf(e8, e9), fmaxf(e10, e11)), \
                         fmaxf(fmaxf(e12, e13), fmaxf(e14, e15)))); \
  float mn = fmaxf(MRUN, tm); \
  float zs = exp2f(e0 - mn)  + exp2f(e1 - mn)  + exp2f(e2 - mn)  + exp2f(e3 - mn) \
           + exp2f(e4 - mn)  + exp2f(e5 - mn)  + exp2f(e6 - mn)  + exp2f(e7 - mn) \
           + exp2f(e8 - mn)  + exp2f(e9 - mn)  + exp2f(e10 - mn) + exp2f(e11 - mn) \
           + exp2f(e12 - mn) + exp2f(e13 - mn) + exp2f(e14 - mn) + exp2f(e15 - mn); \
  ZRUN = ZRUN * exp2f(MRUN - mn) + zs; MRUN = mn; \
} while (0)

// ------- attention phase 1, QBLK=128: per-row smax & Z (log2), max(1/Z) -> pmax -------
// Swapped QK^T: MF(k, q, s) => lane owns ONE q-row; two 16-row sets per wave.
__global__ __launch_bounds__(256) void k_attn1(
    const ushort* __restrict__ qq, const ushort* __restrict__ kq,
    float2* __restrict__ rs, unsigned* __restrict__ pmax,
    int H, int N, int Mr, int ldq, int ldk, float cs) {   // cs = scale * log2(e)
  __shared__ __align__(16) ushort Qs[128][72];
  __shared__ __align__(16) ushort Ks[64][72];
  int tid = threadIdx.x;
  int wave = tid >> 6, lane = tid & 63;
  int q = lane >> 4, mi = lane & 15;
  int bh = blockIdx.y, b = bh / H, h = bh % H;
  int r0 = blockIdx.x * 128;
  #pragma unroll
  for (int c = tid; c < 1024; c += 256) {
    int r = c >> 3, dc = (c & 7) << 3;
    *(int4*)&Qs[r][dc] = *(const int4*)(qq + ((size_t)b * N + r0 + r) * ldq + h * 64 + dc);
  }
  float m0r = NEGI, z0r = 0.f, m1r = NEGI, z1r = 0.f;
  int nt = (Mr + 63) >> 6;
  for (int mt = 0; mt < nt; mt++) {
    __syncthreads();
    #pragma unroll
    for (int c = tid; c < 512; c += 256) {
      int mm = c >> 3, dc = (c & 7) << 3;
      int m = mt * 64 + mm;
      int4 val = make_int4(0, 0, 0, 0);
      if (m < Mr) val = *(const int4*)(kq + ((size_t)b * Mr + m) * ldk + h * 64 + dc);
      *(int4*)&Ks[mm][dc] = val;
    }
    __syncthreads();
    f32x4 s0 = {}, s1 = {}, s2 = {}, s3 = {};
    f32x4 s4 = {}, s5 = {}, s6 = {}, s7 = {};
    #pragma unroll
    for (int kc = 0; kc < 2; kc++) {
      bf16x8 qv0 = *(const bf16x8*)&Qs[wave * 32 + mi][kc * 32 + q * 8];
      bf16x8 qv1 = *(const bf16x8*)&Qs[wave * 32 + 16 + mi][kc * 32 + q * 8];
      bf16x8 k0v = *(const bf16x8*)&Ks[mi][kc * 32 + q * 8];
      bf16x8 k1v = *(const bf16x8*)&Ks[16 + mi][kc * 32 + q * 8];
      bf16x8 k2v = *(const bf16x8*)&Ks[32 + mi][kc * 32 + q * 8];
      bf16x8 k3v = *(const bf16x8*)&Ks[48 + mi][kc * 32 + q * 8];
      MF(k0v, qv0, s0); MF(k1v, qv0, s1); MF(k2v, qv0, s2); MF(k3v, qv0, s3);
      MF(k0v, qv1, s4); MF(k1v, qv1, s5); MF(k2v, qv1, s6); MF(k3v, qv1, s7);
    }
    int kb = mt * 64 + q * 4;
    bool b0_  = kb + 0  < Mr, b1_  = kb + 1  < Mr, b2_  = kb + 2  < Mr, b3_  = kb + 3  < Mr;
    bool b4_  = kb + 16 < Mr, b5_  = kb + 17 < Mr, b6_  = kb + 18 < Mr, b7_  = kb + 19 < Mr;
    bool b8_  = kb + 32 < Mr, b9_  = kb + 33 < Mr, b10_ = kb + 34 < Mr, b11_ = kb + 35 < Mr;
    bool b12_ = kb + 48 < Mr, b13_ = kb + 49 < Mr, b14_ = kb + 50 < Mr, b15_ = kb + 51 < Mr;
    ONLUPD(s0, s1, s2, s3, m0r, z0r);
    ONLUPD(s4, s5, s6, s7, m1r, z1r);
  }
  // cross-q combine (4 lanes share a q-row: lane, lane^16, lane^32, lane^48)
  float mo0 = fmaxf(m0r, __shfl_xor(m0r, 16));
  mo0 = fmaxf(mo0, __shfl_xor(mo0, 32));
  float zz0 = z0r * exp2f(m0r - mo0);
  zz0 += __shfl_xor(zz0, 16);
  zz0 += __shfl_xor(zz0, 32);
  float mo1 = fmaxf(m1r, __shfl_xor(m1r, 16));
  mo1 = fmaxf(mo1, __shfl_xor(mo1, 32));
  float zz1 = z1r * exp2f(m1r - mo1);
  zz1 += __shfl_xor(zz1, 16);
  zz1 += __shfl_xor(zz1, 32);
  if (q == 0) {
    float2 st; st.x = mo0; st.y = zz0;
    rs[(size_t)bh * N + r0 + wave * 32 + mi] = st;
    st.x = mo1; st.y = zz1;
    rs[(size_t)bh * N + r0 + wave * 32 + 16 + mi] = st;
  }
  float pm = fmaxf(1.f / zz0, 1.f / zz1);
  #pragma unroll
  for (int off = 32; off; off >>= 1) pm = fmaxf(pm, __shfl_down(pm, off));
  if (lane == 0) atomicMax(pmax, __float_as_uint(pm));
}

// quantized-prob level: q8 = min(rint(2^(s*cs - mc)), 255), exact in bf16 via shift
DEV ushort q8lvl(float s, float cs, float mc) {
  float p = fminf(rintf(exp2f(fmaf(s, cs, -mc))), 255.f);
  return (ushort)(__float_as_uint(p) >> 16);
}

#define PWR(RB, SA, SB, SC, SD, M0_, M1_, M2_, M3_) do { \
  Ps[(RB) + 0][mi]      = ok0 ? q8lvl((SA).x, cs, M0_) : (ushort)0; \
  Ps[(RB) + 1][mi]      = ok0 ? q8lvl((SA).y, cs, M1_) : (ushort)0; \
  Ps[(RB) + 2][mi]      = ok0 ? q8lvl((SA).z, cs, M2_) : (ushort)0; \
  Ps[(RB) + 3][mi]      = ok0 ? q8lvl((SA).w, cs, M3_) : (ushort)0; \
  Ps[(RB) + 0][16 + mi] = ok1 ? q8lvl((SB).x, cs, M0_) : (ushort)0; \
  Ps[(RB) + 1][16 + mi] = ok1 ? q8lvl((SB).y, cs, M1_) : (ushort)0; \
  Ps[(RB) + 2][16 + mi] = ok1 ? q8lvl((SB).z, cs, M2_) : (ushort)0; \
  Ps[(RB) + 3][16 + mi] = ok1 ? q8lvl((SB).w, cs, M3_) : (ushort)0; \
  Ps[(RB) + 0][32 + mi] = ok2 ? q8lvl((SC).x, cs, M0_) : (ushort)0; \
  Ps[(RB) + 1][32 + mi] = ok2 ? q8lvl((SC).y, cs, M1_) : (ushort)0; \
  Ps[(RB) + 2][32 + mi] = ok2 ? q8lvl((SC).z, cs, M2_) : (ushort)0; \
  Ps[(RB) + 3][32 + mi] = ok2 ? q8lvl((SC).w, cs, M3_) : (ushort)0; \
  Ps[(RB) + 0][48 + mi] = ok3 ? q8lvl((SD).x, cs, M0_) : (ushort)0; \
  Ps[(RB) + 1][48 + mi] = ok3 ? q8lvl((SD).y, cs, M1_) : (ushort)0; \
  Ps[(RB) + 2][48 + mi] = ok3 ? q8lvl((SD).z, cs, M2_) : (ushort)0; \
  Ps[(RB) + 3][48 + mi] = ok3 ? q8lvl((SD).w, cs, M3_) : (ushort)0; \
} while (0)

#define OSTORE(RRBASE, OA, OB, OC, OD) do { \
  size_t base = ((size_t)b * N + (RRBASE)) * C + h * 64 + mi; \
  ao[base]              = f2b((OA).x * delta); ao[base + C]          = f2b((OA).y * delta); \
  ao[base + 2 * C]      = f2b((OA).z * delta); ao[base + 3 * C]      = f2b((OA).w * delta); \
  ao[base + 16]         = f2b((OB).x * delta); ao[base + C + 16]     = f2b((OB).y * delta); \
  ao[base + 2 * C + 16] = f2b((OB).z * delta); ao[base + 3 * C + 16] = f2b((OB).w * delta); \
  ao[base + 32]         = f2b((OC).x * delta); ao[base + C + 32]     = f2b((OC).y * delta); \
  ao[base + 2 * C + 32] = f2b((OC).z * delta); ao[base + 3 * C + 32] = f2b((OC).w * delta); \
  ao[base + 48]         = f2b((OD).x * delta); ao[base + C + 48]     = f2b((OD).y * delta); \
  ao[base + 2 * C + 48] = f2b((OD).z * delta); ao[base + 3 * C + 48] = f2b((OD).w * delta); \
} while (0)

// ------- attention phase 2, QBLK=128: recompute S, quantize IN REGISTER, P@V -------
__global__ __launch_bounds__(256) void k_attn2(
    const ushort* __restrict__ qq, const ushort* __restrict__ kq,
    const ushort* __restrict__ vT, const float2* __restrict__ rs,
    const unsigned* __restrict__ pmax, ushort* __restrict__ ao,
    int H, int N, int Mr, int Mpad, int ldq, int ldk, float cs) {
  const int C = 1280;
  __shared__ __align__(16) ushort Qs[128][72];
  __shared__ __align__(16) ushort Ks[64][72];
  __shared__ __align__(16) ushort Vs[64][72];
  __shared__ __align__(16) ushort Ps[128][72];
  int tid = threadIdx.x;
  int wave = tid >> 6, lane = tid & 63;
  int q = lane >> 4, mi = lane & 15;
  int bh = blockIdx.y, b = bh / H, h = bh % H;
  int r0 = blockIdx.x * 128;
  #pragma unroll
  for (int c = tid; c < 1024; c += 256) {
    int r = c >> 3, dc = (c & 7) << 3;
    *(int4*)&Qs[r][dc] = *(const int4*)(qq + ((size_t)b * N + r0 + r) * ldq + h * 64 + dc);
  }
  int rb0 = wave * 32 + q * 4, rb1 = rb0 + 16;
  float delta = fmaxf(__uint_as_float(*pmax), 1e-8f) * (1.f / 255.f);
  float ldl = __log2f(delta);
  float2 u0 = rs[(size_t)bh * N + r0 + rb0 + 0];
  float2 u1 = rs[(size_t)bh * N + r0 + rb0 + 1];
  float2 u2 = rs[(size_t)bh * N + r0 + rb0 + 2];
  float2 u3 = rs[(size_t)bh * N + r0 + rb0 + 3];
  float2 u4 = rs[(size_t)bh * N + r0 + rb1 + 0];
  float2 u5 = rs[(size_t)bh * N + r0 + rb1 + 1];
  float2 u6 = rs[(size_t)bh * N + r0 + rb1 + 2];
  float2 u7 = rs[(size_t)bh * N + r0 + rb1 + 3];
  float mc0 = u0.x + __log2f(u0.y) + ldl;
  float mc1 = u1.x + __log2f(u1.y) + ldl;
  float mc2 = u2.x + __log2f(u2.y) + ldl;
  float mc3 = u3.x + __log2f(u3.y) + ldl;
  float mc4 = u4.x + __log2f(u4.y) + ldl;
  float mc5 = u5.x + __log2f(u5.y) + ldl;
  float mc6 = u6.x + __log2f(u6.y) + ldl;
  float mc7 = u7.x + __log2f(u7.y) + ldl;
  f32x4 o0 = {}, o1 = {}, o2 = {}, o3 = {};
  f32x4 o4 = {}, o5 = {}, o6 = {}, o7 = {};
  int nt = (Mr + 63) >> 6;
  for (int mt = 0; mt < nt; mt++) {
    __syncthreads();
    #pragma unroll
    for (int c = tid; c < 512; c += 256) {
      int mm = c >> 3, dc = (c & 7) << 3;
      int m = mt * 64 + mm;
      int4 val = make_int4(0, 0, 0, 0);
      if (m < Mr) val = *(const int4*)(kq + ((size_t)b * Mr + m) * ldk + h * 64 + dc);
      *(int4*)&Ks[mm][dc] = val;
      *(int4*)&Vs[mm][dc] = *(const int4*)(vT + ((size_t)bh * 64 + mm) * Mpad + mt * 64 + dc);
    }
    __syncthreads();
    f32x4 s0 = {}, s1 = {}, s2 = {}, s3 = {};
    f32x4 s4 = {}, s5 = {}, s6 = {}, s7 = {};
    #pragma unroll
    for (int kc = 0; kc < 2; kc++) {
      bf16x8 aq0 = *(const bf16x8*)&Qs[wave * 32 + mi][kc * 32 + q * 8];
      bf16x8 aq1 = *(const bf16x8*)&Qs[wave * 32 + 16 + mi][kc * 32 + q * 8];
      bf16x8 k0v = *(const bf16x8*)&Ks[mi][kc * 32 + q * 8];
      bf16x8 k1v = *(const bf16x8*)&Ks[16 + mi][kc * 32 + q * 8];
      bf16x8 k2v = *(const bf16x8*)&Ks[32 + mi][kc * 32 + q * 8];
      bf16x8 k3v = *(const bf16x8*)&Ks[48 + mi][kc * 32 + q * 8];
      MF(aq0, k0v, s0); MF(aq0, k1v, s1); MF(aq0, k2v, s2); MF(aq0, k3v, s3);
      MF(aq1, k0v, s4); MF(aq1, k1v, s5); MF(aq1, k2v, s6); MF(aq1, k3v, s7);
    }
    int mlim = Mr - mt * 64;
    bool ok0 = (mi      < mlim);
    bool ok1 = (16 + mi < mlim);
    bool ok2 = (32 + mi < mlim);
    bool ok3 = (48 + mi < mlim);
    PWR(rb0, s0, s1, s2, s3, mc0, mc1, mc2, mc3);
    PWR(rb1, s4, s5, s6, s7, mc4, mc5, mc6, mc7);
    // wave-local RAW through LDS: rows 32w..32w+31 written & read by wave w only.
    asm volatile("s_waitcnt lgkmcnt(0)" ::: "memory");
    __builtin_amdgcn_sched_barrier(0);
    #pragma unroll
    for (int kc = 0; kc < 2; kc++) {
      bf16x8 ap0 = *(const bf16x8*)&Ps[wave * 32 + mi][kc * 32 + q * 8];
      bf16x8 ap1 = *(const bf16x8*)&Ps[wave * 32 + 16 + mi][kc * 32 + q * 8];
      bf16x8 v0 = *(const bf16x8*)&Vs[mi][kc * 32 + q * 8];
      bf16x8 v1 = *(const bf16x8*)&Vs[16 + mi][kc * 32 + q * 8];
      bf16x8 v2 = *(const bf16x8*)&Vs[32 + mi][kc * 32 + q * 8];
      bf16x8 v3 = *(const bf16x8*)&Vs[48 + mi][kc * 32 + q * 8];
      MF(ap0, v0, o0); MF(ap0, v1, o1); MF(ap0, v2, o2); MF(ap0, v3, o3);
      MF(ap1, v0, o4); MF(ap1, v1, o5); MF(ap1, v2, o6); MF(ap1, v3, o7);
    }
  }
  int rr0 = r0 + wave * 32 + q * 4;
  OSTORE(rr0, o0, o1, o2, o3);
  OSTORE(rr0 + 16, o4, o5, o6, o7);
}

// =====================================================================
// shared pipeline macros (T2 xor-swizzle + counted vmcnt + setprio)
// =====================================================================
#define BAR __builtin_amdgcn_s_barrier()
#define LGKM0 do { asm volatile("s_waitcnt lgkmcnt(0)" ::: "memory"); \
                   __builtin_amdgcn_sched_barrier(0); } while (0)
#define VM6 asm volatile("s_waitcnt vmcnt(6)" ::: "memory")
#define VM0 asm volatile("s_waitcnt vmcnt(0)" ::: "memory")
#define PRIO1 __builtin_amdgcn_s_setprio(1)
#define PRIO0 __builtin_amdgcn_s_setprio(0)

#define RDA01(P) do { \
  fa00 = *(const bf16x8*)&(P)[c0];        fa01 = *(const bf16x8*)&(P)[c1]; \
  fa10 = *(const bf16x8*)&(P)[1024 + c0]; fa11 = *(const bf16x8*)&(P)[1024 + c1]; } while (0)
#define RDA23(P) do { \
  fa20 = *(const bf16x8*)&(P)[2048 + c0]; fa21 = *(const bf16x8*)&(P)[2048 + c1]; \
  fa30 = *(const bf16x8*)&(P)[3072 + c0]; fa31 = *(const bf16x8*)&(P)[3072 + c1]; } while (0)
#define RDB(P, H) do { \
  b00 = *(const bf16x8*)&(P)[(H) + c0];        b01 = *(const bf16x8*)&(P)[(H) + c1]; \
  b10 = *(const bf16x8*)&(P)[(H) + 1024 + c0]; b11 = *(const bf16x8*)&(P)[(H) + 1024 + c1]; \
  b20 = *(const bf16x8*)&(P)[(H) + 2048 + c0]; b21 = *(const bf16x8*)&(P)[(H) + 2048 + c1]; \
  b30 = *(const bf16x8*)&(P)[(H) + 3072 + c0]; b31 = *(const bf16x8*)&(P)[(H) + 3072 + c1]; } while (0)
#define RDB8(P) RDB(P, 0)

#define MM8(AX0, AX1, AY0, AY1, C0, C1, C2, C3, D0, D1, D2, D3) \
  MF(AX0, b00, C0); MF(AX1, b01, C0); MF(AX0, b10, C1); MF(AX1, b11, C1); \
  MF(AX0, b20, C2); MF(AX1, b21, C2); MF(AX0, b30, C3); MF(AX1, b31, C3); \
  MF(AY0, b00, D0); MF(AY1, b01, D0); MF(AY0, b10, D1); MF(AY1, b11, D1); \
  MF(AY0, b20, D2); MF(AY1, b21, D2); MF(AY0, b30, D3); MF(AY1, b31, D3)

// =====================================================================
// k_gemm8: 8-wave 256x128-tile NT GEMM, BK=64, TRIPLE-buffered LDS (144 KiB),
// 2 phases/K-tile of 16 MFMA, counted vmcnt(6) (never 0 in main loop).
// Requires M%256==0, N%128==0, K%64==0, K/64>=5, (K/64-2)%3==0, blocks%8==0.
// =====================================================================
#define GB8(AP, BP, DB, KT) \
  RDA01(AP); RDB8(BP); \
  stB(DB, KT, 0); stB(DB, KT, 1); stA(DB, KT, 0); \
  BAR; LGKM0; \
  PRIO1; MM8(fa00, fa01, fa10, fa11, c00, c01, c02, c03, c10, c11, c12, c13); PRIO0; \
  BAR; \
  RDA23(AP); \
  stA(DB, KT, 1); stA(DB, KT, 2); stA(DB, KT, 3); \
  BAR; LGKM0; \
  PRIO1; MM8(fa20, fa21, fa30, fa31, c20, c21, c22, c23, c30, c31, c32, c33); PRIO0; \
  VM6; BAR;

#define GT8(AP, BP) \
  RDA01(AP); RDB8(BP); \
  BAR; LGKM0; \
  PRIO1; MM8(fa00, fa01, fa10, fa11, c00, c01, c02, c03, c10, c11, c12, c13); PRIO0; \
  BAR; \
  RDA23(AP); \
  BAR; LGKM0; \
  PRIO1; MM8(fa20, fa21, fa30, fa31, c20, c21, c22, c23, c30, c31, c32, c33); PRIO0;

__global__ __launch_bounds__(512) void k_gemm8(
    const ushort* __restrict__ A, int lda,
    const ushort* __restrict__ BT, int ldb,
    float* __restrict__ Cf, ushort* __restrict__ Cb, int ldc,
    const float* __restrict__ bias, const float* __restrict__ resid,
    unsigned* am_slot, int M, int N, int K, int slcN) {
  // per buf (24576 ushorts): A[256][64] @0, B[128][64] @16384. Swizzle: col ^= (row&7)*8.
  __shared__ __align__(16) ushort SAB[73728];  // 144 KiB, 3 bufs
  int tid = threadIdx.x;
  int wave = tid >> 6, lane = tid & 63;
  int q = lane >> 4, mi = lane & 15;
  int wm = wave >> 1, wn = wave & 1;
  int lr = lane >> 3;
  int lc = ((lane & 7) ^ lr) * 8;   // inverse-swizzled source col (elems)

  int NBN = N >> 7;
  int nblk = (M >> 8) * NBN;
  int cpx = nblk >> 3;
  int wg = blockIdx.x;
  int swz = (wg & 7) * cpx + (wg >> 3);   // bijective: nblk % 8 == 0
  int bm0 = (swz / NBN) << 8, bn0 = (swz % NBN) << 7;

  const int swzr = (mi & 7) * 8;
  int c0 = (q * 8) ^ swzr, c1 = (32 + q * 8) ^ swzr;
  const ushort* A0p = &SAB[(wm * 64 + mi) * 64];
  const ushort* B0p = &SAB[16384 + (wn * 64 + mi) * 64];
  const ushort* A1p = A0p + 24576; const ushort* B1p = B0p + 24576;
  const ushort* A2p = A0p + 49152; const ushort* B2p = B0p + 49152;

  const ushort* gA = A  + (size_t)(bm0 + wave * 8 + lr) * lda + lc;
  const ushort* gB = BT + (size_t)(bn0 + wave * 8 + lr) * ldb + lc;
  ushort* lA = &SAB[wave * 512];
  ushort* lB = &SAB[16384 + wave * 512];

  auto stA = [&](int bb, int kt, int call) {   // A: 4 calls x 64 rows
    gl_lds16(lA + bb * 24576 + call * 4096,
             gA + (size_t)call * 64 * lda + (size_t)kt * 64);
  };
  auto stB = [&](int bb, int kt, int call) {   // B: 2 calls x 64 rows
    gl_lds16(lB + bb * 24576 + call * 4096,
             gB + (size_t)call * 64 * ldb + (size_t)kt * 64);
  };

  f32x4 c00 = {}, c01 = {}, c02 = {}, c03 = {};
  f32x4 c10 = {}, c11 = {}, c12 = {}, c13 = {};
  f32x4 c20 = {}, c21 = {}, c22 = {}, c23 = {};
  f32x4 c30 = {}, c31 = {}, c32 = {}, c33 = {};
  bf16x8 fa00, fa01, fa10, fa11, fa20, fa21, fa30, fa31;
  bf16x8 b00, b01, b10, b11, b20, b21, b30, b31;

  // prologue: tile0 -> buf0, tile1 -> buf1 (6 calls each)
  stB(0, 0, 0); stB(0, 0, 1);
  stA(0, 0, 0); stA(0, 0, 1); stA(0, 0, 2); stA(0, 0, 3);
  stB(1, 1, 0); stB(1, 1, 1);
  stA(1, 1, 0); stA(1, 1, 1); stA(1, 1, 2); stA(1, 1, 3);
  VM6; BAR;

  int NT = K >> 6, NTm = NT - 2;  // NTm % 3 == 0 by contract
  for (int t = 0; t < NTm; t += 3) {
    GB8(A0p, B0p, 2, t + 2);
    GB8(A1p, B1p, 0, t + 3);
    GB8(A2p, B2p, 1, t + 4);
  }
  // tail: tile NT-2 (buf0), then tile NT-1 (buf1)
  GT8(A0p, B0p);
  VM0; BAR;
  GT8(A1p, B1p);

  int rb = bm0 + wm * 64 + q * 4, cb = bn0 + wn * 64 + mi;
  float am = 0.f;
  am = fmaxf(am, epi4(c00, rb +  0, cb +  0, M, N, ldc, bias, resid, Cf, Cb));
  am = fmaxf(am, epi4(c01, rb +  0, cb + 16, M, N, ldc, bias, resid, Cf, Cb));
  am = fmaxf(am, epi4(c02, rb +  0, cb + 32, M, N, ldc, bias, resid, Cf, Cb));
  am = fmaxf(am, epi4(c03, rb +  0, cb + 48, M, N, ldc, bias, resid, Cf, Cb));
  am = fmaxf(am, epi4(c10, rb + 16, cb +  0, M, N, ldc, bias, resid, Cf, Cb));
  am = fmaxf(am, epi4(c11, rb + 16, cb + 16, M, N, ldc, bias, resid, Cf, Cb));
  am = fmaxf(am, epi4(c12, rb + 16, cb + 32, M, N, ldc, bias, resid, Cf, Cb));
  am = fmaxf(am, epi4(c13, rb + 16, cb + 48, M, N, ldc, bias, resid, Cf, Cb));
  am = fmaxf(am, epi4(c20, rb + 32, cb +  0, M, N, ldc, bias, resid, Cf, Cb));
  am = fmaxf(am, epi4(c21, rb + 32, cb + 16, M, N, ldc, bias, resid, Cf, Cb));
  am = fmaxf(am, epi4(c22, rb + 32, cb + 32, M, N, ldc, bias, resid, Cf, Cb));
  am = fmaxf(am, epi4(c23, rb + 32, cb + 48, M, N, ldc, bias, resid, Cf, Cb));
  am = fmaxf(am, epi4(c30, rb + 48, cb +  0, M, N, ldc, bias, resid, Cf, Cb));
  am = fmaxf(am, epi4(c31, rb + 48, cb + 16, M, N, ldc, bias, resid, Cf, Cb));
  am = fmaxf(am, epi4(c32, rb + 48, cb + 32, M, N, ldc, bias, resid, Cf, Cb));
  am = fmaxf(am, epi4(c33, rb + 48, cb + 48, M, N, ldc, bias, resid, Cf, Cb));
  if (am_slot) {
    #pragma unroll
    for (int off = 32; off; off >>= 1) am = fmaxf(am, __shfl_down(am, off));
    if (lane == 0) atomicMax(am_slot + bn0 / slcN, __float_as_uint(am));
  }
}

// =====================================================================
// fused FF1 + GEGLU, 256x128(GG) tile, BK=64, 8 waves, 8-phase schedule
// =====================================================================
// gelu-tanh via sigmoid identity: 0.5*(1+tanh(x)) == sigmoid(2x)
DEV ushort ggel(float a, float g) {
  float u = 1.5957691216057308f * g * (1.f + 0.044715f * g * g);
  float s = 1.f / (1.f + __expf(-u));
  return f2b(a * g * s);
}
DEV void epi4g(f32x4 va, f32x4 vg, size_t base, float ba, float bg,
               ushort* __restrict__ GG) {
  GG[base]         = ggel(va.x + ba, vg.x + bg);
  GG[base + 5120]  = ggel(va.y + ba, vg.y + bg);
  GG[base + 10240] = ggel(va.z + ba, vg.z + bg);
  GG[base + 15360] = ggel(va.w + ba, vg.w + bg);
}
#define EPIN(nn, P0, Q0, P1, Q1, P2, Q2, P3, Q3) do { \
  int cg = colBase + nn * 16 + mi; \
  float ba = bias[cg], bg = bias[5120 + cg]; \
  size_t b0_ = (size_t)rowBase * 5120 + cg; \
  epi4g(P0, Q0, b0_,             ba, bg, GG); \
  epi4g(P1, Q1, b0_ + 16 * 5120, ba, bg, GG); \
  epi4g(P2, Q2, b0_ + 32 * 5120, ba, bg, GG); \
  epi4g(P3, Q3, b0_ + 48 * 5120, ba, bg, GG); \
} while (0)

__global__ __launch_bounds__(512) void k_ff1_8p(
    const ushort* __restrict__ A,    // LN [8192][1280]
    const ushort* __restrict__ BT,   // WF1T [10240][1280]
    const float* __restrict__ bias,  // bff1 [10240]
    ushort* __restrict__ GG) {       // [8192][5120]
  __shared__ __align__(16) ushort SAB[65536];  // 128 KiB
  int tid = threadIdx.x;
  int wave = tid >> 6, lane = tid & 63;
  int q = lane >> 4, mi = lane & 15;
  int wm = wave >> 1, wn = wave & 1;
  int lr = lane >> 3;
  int lc = ((lane & 7) ^ lr) * 8;  // inverse-swizzled source col (elems)

  int wg = blockIdx.x;
  int swz = (wg & 7) * 160 + (wg >> 3);
  int bm0 = (swz & 31) * 256, bn0 = (swz >> 5) * 128;

  const int swzr = (mi & 7) * 8;
  int c0 = (q * 8) ^ swzr, c1 = (32 + q * 8) ^ swzr;
  const ushort* A0p = &SAB[(wm * 64 + mi) * 64];
  const ushort* B0p = &SAB[16384 + (wn * 64 + mi) * 64];
  const ushort* A1p = A0p + 32768;
  const ushort* B1p = B0p + 32768;

  const ushort* gA  = A  + (size_t)(bm0 + wave * 8 + lr) * 1280 + lc;
  const ushort* gBa = BT + (size_t)(bn0 + wave * 8 + lr) * 1280 + lc;
  const ushort* gBg = BT + (size_t)(5120 + bn0 + wave * 8 + lr) * 1280 + lc;
  ushort* lA = &SAB[wave * 512];
  ushort* lB = &SAB[16384 + wave * 512];

  auto stA = [&](int bb, int kt, int call) {
    gl_lds16(lA + bb * 32768 + call * 4096,
             gA + (size_t)call * 81920 + (size_t)kt * 64);
  };
  auto stBa = [&](int bb, int kt, int call) {
    gl_lds16(lB + bb * 32768 + call * 4096,
             gBa + (size_t)call * 81920 + (size_t)kt * 64);
  };
  auto stBg = [&](int bb, int kt, int call) {
    gl_lds16(lB + bb * 32768 + (call + 2) * 4096,
             gBg + (size_t)call * 81920 + (size_t)kt * 64);
  };

  f32x4 cA00 = {}, cA01 = {}, cA02 = {}, cA03 = {};
  f32x4 cA10 = {}, cA11 = {}, cA12 = {}, cA13 = {};
  f32x4 cA20 = {}, cA21 = {}, cA22 = {}, cA23 = {};
  f32x4 cA30 = {}, cA31 = {}, cA32 = {}, cA33 = {};
  f32x4 cG00 = {}, cG01 = {}, cG02 = {}, cG03 = {};
  f32x4 cG10 = {}, cG11 = {}, cG12 = {}, cG13 = {};
  f32x4 cG20 = {}, cG21 = {}, cG22 = {}, cG23 = {};
  f32x4 cG30 = {}, cG31 = {}, cG32 = {}, cG33 = {};
  bf16x8 fa00, fa01, fa10, fa11, fa20, fa21, fa30, fa31;
  bf16x8 b00, b01, b10, b11, b20, b21, b30, b31;

  stBa(0, 0, 0); stBa(0, 0, 1); stBg(0, 0, 0); stBg(0, 0, 1);
  stA(0, 0, 0); stA(0, 0, 1); stA(0, 0, 2); stA(0, 0, 3);
  stBa(1, 1, 0); stBa(1, 1, 1);
  stA(1, 1, 0); stA(1, 1, 1); stA(1, 1, 2); stA(1, 1, 3);
  VM6; BAR;

  for (int it = 0; it < 10; ++it) {
    int t1 = 2 * it + 1;
    int s0 = t1 + 1; if (s0 > 19) s0 = 19;
    int s1 = t1 + 2; if (s1 > 19) s1 = 19;
    // ---- P1: buf0 m01 x Ba ----
    RDA01(A0p); RDB(B0p, 0);
    stBg(1, t1, 0); stBg(1, t1, 1);
    BAR; LGKM0;
    PRIO1; MM8(fa00, fa01, fa10, fa11, cA00, cA01, cA02, cA03,
               cA10, cA11, cA12, cA13); PRIO0;
    BAR;
    // ---- P2: buf0 m23 x Ba ----
    RDA23(A0p);
    stBa(0, s0, 0); stBa(0, s0, 1);
    BAR; LGKM0;
    PRIO1; MM8(fa20, fa21, fa30, fa31, cA20, cA21, cA22, cA23,
               cA30, cA31, cA32, cA33); PRIO0;
    BAR;
    // ---- P3: buf0 m01 x Bg ----
    RDB(B0p, 8192);
    stA(0, s0, 0); stA(0, s0, 1);
    BAR; LGKM0;
    PRIO1; MM8(fa00, fa01, fa10, fa11, cG00, cG01, cG02, cG03,
               cG10, cG11, cG12, cG13); PRIO0;
    BAR;
    // ---- P4: buf0 m23 x Bg ----
    stA(0, s0, 2); stA(0, s0, 3);
    BAR;
    PRIO1; MM8(fa20, fa21, fa30, fa31, cG20, cG21, cG22, cG23,
               cG30, cG31, cG32, cG33); PRIO0;
    VM6; BAR;
    // ---- P5: buf1 m01 x Ba ----
    RDA01(A1p); RDB(B1p, 0);
    stBg(0, s0, 0); stBg(0, s0, 1);
    BAR; LGKM0;
    PRIO1; MM8(fa00, fa01, fa10, fa11, cA00, cA01, cA02, cA03,
               cA10, cA11, cA12, cA13); PRIO0;
    BAR;
    // ---- P6: buf1 m23 x Ba ----
    RDA23(A1p);
    stBa(1, s1, 0); stBa(1, s1, 1);
    BAR; LGKM0;
    PRIO1; MM8(fa20, fa21, fa30, fa31, cA20, cA21, cA22, cA23,
               cA30, cA31, cA32, cA33); PRIO0;
    BAR;
    // ---- P7: buf1 m01 x Bg ----
    RDB(B1p, 8192);
    stA(1, s1, 0); stA(1, s1, 1);
    BAR; LGKM0;
    PRIO1; MM8(fa00, fa01, fa10, fa11, cG00, cG01, cG02, cG03,
               cG10, cG11, cG12, cG13); PRIO0;
    BAR;
    // ---- P8: buf1 m23 x Bg ----
    stA(1, s1, 2); stA(1, s1, 3);
    BAR;
    PRIO1; MM8(fa20, fa21, fa30, fa31, cG20, cG21, cG22, cG23,
               cG30, cG31, cG32, cG33); PRIO0;
    VM6; BAR;
  }

  int colBase = bn0 + wn * 64;
  int rowBase = bm0 + wm * 64 + q * 4;
  EPIN(0, cA00, cG00, cA10, cG10, cA20, cG20, cA30, cG30);
  EPIN(1, cA01, cG01, cA11, cG11, cA21, cG21, cA31, cG31);
  EPIN(2, cA02, cG02, cA12, cG12, cA22, cG22, cA32, cG32);
  EPIN(3, cA03, cG03, cA13, cG13, cA23, cG23, cA33, cG33);
}

extern "C" void kernel_launch(void* const* d_in, const int* in_sizes, int n_in,
                              void* d_out, int out_size, void* d_ws, size_t ws_size,
                              hipStream_t stream) {
  const float* x_in = (const float*)d_in[0];
  const float* ctx  = (const float*)d_in[1];
  const float* ln1g = (const float*)d_in[2];
  const float* ln1b = (const float*)d_in[3];
  const float* ln2g = (const float*)d_in[4];
  const float* ln2b = (const float*)d_in[5];
  const float* ln3g = (const float*)d_in[6];
  const float* ln3b = (const float*)d_in[7];
  const float* Wq1  = (const float*)d_in[8];
  const float* Wk1  = (const float*)d_in[9];
  const float* Wv1  = (const float*)d_in[10];
  const float* Wo1  = (const float*)d_in[11];
  const float* bo1  = (const float*)d_in[12];
  const float* Wq2  = (const float*)d_in[13];
  const float* Wk2  = (const float*)d_in[14];
  const float* Wv2  = (const float*)d_in[15];
  const float* Wo2  = (const float*)d_in[16];
  const float* bo2  = (const float*)d_in[17];
  const float* Wff1 = (const float*)d_in[18];
  const float* bff1 = (const float*)d_in[19];
  const float* Wff2 = (const float*)d_in[20];
  const float* bff2 = (const float*)d_in[21];
  float* out = (float*)d_out;   // also doubles as the fp32 residual stream "xcur"

  const int NR = 8192;   // B*N
  const int C = 1280, H = 20, Nseq = 1024, CC = 768;
  const int MR2 = 616;   // B*M (cross rows)
  const float CS = 0.18033688011112042f;  // 0.125 * log2(e)

  char* ws = (char*)d_ws;
  size_t off = 0;
  auto alloc = [&](size_t bytes) -> void* {
    void* p = ws + off;
    off += (bytes + 255) & ~(size_t)255;
    return p;
  };
  unsigned* scal = (unsigned*)alloc(64);
  // NOTE: Wq1T/Wk1T/Wv1T contiguous (each C*C*2 = 3,276,800, 256-mult) -> WQKV1T [3840][1280]
  ushort* Wq1T  = (ushort*)alloc((size_t)C * C * 2);
  ushort* Wk1T  = (ushort*)alloc((size_t)C * C * 2);
  ushort* Wv1T  = (ushort*)alloc((size_t)C * C * 2);
  ushort* Wo1T  = (ushort*)alloc((size_t)C * C * 2);
  ushort* Wq2T  = (ushort*)alloc((size_t)C * C * 2);
  // Wk2T/Wv2T contiguous (each C*CC*2 = 1,966,080, 256-mult) -> WKV2T [2560][768]
  ushort* Wk2T  = (ushort*)alloc((size_t)C * CC * 2);
  ushort* Wv2T  = (ushort*)alloc((size_t)C * CC * 2);
  ushort* Wo2T  = (ushort*)alloc((size_t)C * C * 2);
  ushort* WF1T  = (ushort*)alloc((size_t)10240 * C * 2);
  ushort* WF2T  = (ushort*)alloc((size_t)C * 5120 * 2);
  ushort* LN    = (ushort*)alloc((size_t)NR * C * 2);   // also AO (attn output)
  size_t regionR = off;  // attention region; stage-3 GG overlays it
  ushort* QKV   = (ushort*)alloc((size_t)NR * 3840 * 2);  // packed Q|K|V, ld=3840
  ushort* VT    = (ushort*)alloc((size_t)160 * 64 * 1024 * 2);
  float2* RS    = (float2*)alloc((size_t)160 * 1024 * 8);
  ushort* CTXB  = (ushort*)alloc((size_t)MR2 * CC * 2);
  ushort* KV2   = (ushort*)alloc((size_t)MR2 * 2560 * 2);  // packed K|V cross, ld=2560
  size_t need = off;
  ushort* AO = LN;                       // alias: LN dead once QKV gemm ran
  ushort* GG = (ushort*)(ws + regionR);  // 84 MB, overlays QKV..KV2 in stage 3
  if (ws_size < need) return;  // diagnostic: absmax==poison => ws too small

  // --- init & weight prep ---
  k_zero<<<1, 64, 0, stream>>>(scal, 8);
  k_wt<<<dim3(40, 40), 256, 0, stream>>>(Wq1, Wq1T, C, C);
  k_wt<<<dim3(40, 40), 256, 0, stream>>>(Wk1, Wk1T, C, C);
  k_wt<<<dim3(40, 40), 256, 0, stream>>>(Wv1, Wv1T, C, C);
  k_wt<<<dim3(40, 40), 256, 0, stream>>>(Wo1, Wo1T, C, C);
  k_wt<<<dim3(40, 40), 256, 0, stream>>>(Wq2, Wq2T, C, C);
  k_wt<<<dim3(40, 24), 256, 0, stream>>>(Wk2, Wk2T, CC, C);
  k_wt<<<dim3(40, 24), 256, 0, stream>>>(Wv2, Wv2T, CC, C);
  k_wt<<<dim3(40, 40), 256, 0, stream>>>(Wo2, Wo2T, C, C);
  k_wt<<<dim3(320, 40), 256, 0, stream>>>(Wff1, WF1T, C, 10240);
  k_wt<<<dim3(40, 160), 256, 0, stream>>>(Wff2, WF2T, 5120, C);

  // ================= stage 1: self-attention =================
  k_ln<<<NR, 256, 0, stream>>>(x_in, ln1g, ln1b, LN);
  // fused Q|K|V gemm: N=3840, grid 960 (93.75% CU util vs 62.5% for 3x320)
  k_gemm8<<<dim3(960), 512, 0, stream>>>(LN, C, Wq1T, C, nullptr, QKV, 3840,
                                         nullptr, nullptr, scal + 0, NR, 3840, C, 1280);
  k_quant8<<<(NR * 3840 / 8 + 255) / 256, 256, 0, stream>>>(QKV, QKV, scal + 0,
                                                            NR * 480, 480, 3840, 1280);
  k_vt<<<dim3(16, 160), 256, 0, stream>>>(QKV + 2560, VT, H, 1024, 1024, 3840);
  k_attn1<<<dim3(8, 160), 256, 0, stream>>>(QKV, QKV + 1280, RS, scal + 3,
                                            H, Nseq, 1024, 3840, 3840, CS);
  k_attn2<<<dim3(8, 160), 256, 0, stream>>>(QKV, QKV + 1280, VT, RS, scal + 3, AO,
                                            H, Nseq, 1024, 1024, 3840, 3840, CS);
  k_gemm8<<<dim3(320), 512, 0, stream>>>(AO, C, Wo1T, C, out, nullptr, C,
                                         bo1, x_in, nullptr, NR, C, C, C);

  // ================= stage 2: cross-attention =================
  k_ln<<<NR, 256, 0, stream>>>(out, ln2g, ln2b, LN);
  k_gemm8<<<dim3(320), 512, 0, stream>>>(LN, C, Wq2T, C, nullptr, QKV, 3840,
                                         nullptr, nullptr, scal + 4, NR, C, C, C);
  k_quant8<<<(NR * C / 8 + 255) / 256, 256, 0, stream>>>(QKV, QKV, scal + 4,
                                                         NR * 160, 160, 3840, 1280);
  k_cvt<<<(MR2 * CC + 255) / 256, 256, 0, stream>>>(ctx, CTXB, MR2 * CC);
  // fused K|V cross gemm: N=2560
  k_gemm<<<dim3(20, 5), 256, 0, stream>>>(CTXB, CC, Wk2T, CC, nullptr, KV2, 2560,
                                          nullptr, nullptr, scal + 5, MR2, 2560, CC, 1280);
  k_quant8<<<(MR2 * 2560 / 8 + 255) / 256, 256, 0, stream>>>(KV2, KV2, scal + 5,
                                                             MR2 * 320, 320, 2560, 1280);
  k_vt<<<dim3(2, 160), 256, 0, stream>>>(KV2 + 1280, VT, H, 77, 128, 2560);
  k_attn1<<<dim3(8, 160), 256, 0, stream>>>(QKV, KV2, RS, scal + 7,
                                            H, Nseq, 77, 3840, 2560, CS);
  k_attn2<<<dim3(8, 160), 256, 0, stream>>>(QKV, KV2, VT, RS, scal + 7, AO,
                                            H, Nseq, 77, 128, 3840, 2560, CS);
  k_gemm8<<<dim3(320), 512, 0, stream>>>(AO, C, Wo2T, C, out, nullptr, C,
                                         bo2, out, nullptr, NR, C, C, C);

  // ================= stage 3: GEGLU FF (fused, 8-phase) =================
  k_ln<<<NR, 256, 0, stream>>>(out, ln3g, ln3b, LN);
  k_ff1_8p<<<dim3(1280), 512, 0, stream>>>(LN, WF1T, bff1, GG);
  k_gemm8<<<dim3(320), 512, 0, stream>>>(GG, 5120, WF2T, 5120, out, nullptr, C,
                                         bff2, out, nullptr, NR, C, 5120, C);
}

// Round 7
// 1543.617 us; speedup vs baseline: 1.2522x; 1.0050x over previous
//
#include <hip/hip_runtime.h>

typedef __attribute__((ext_vector_type(8))) short bf16x8;
typedef __attribute__((ext_vector_type(4))) float f32x4;

#define DEV __device__ __forceinline__
#define MF(A, B, CACC) CACC = __builtin_amdgcn_mfma_f32_16x16x32_bf16(A, B, CACC, 0, 0, 0)

DEV ushort f2b(float f) {
  unsigned u = __float_as_uint(f);
  u += 0x7fffu + ((u >> 16) & 1u);   // RNE to bf16
  return (ushort)(u >> 16);
}
DEV float b2f(ushort u) { return __uint_as_float(((unsigned)u) << 16); }

// async global->LDS, 16B per lane; lds base must be wave-uniform (HW adds lane*16)
DEV void gl_lds16(ushort* lds_base, const ushort* gp) {
  __builtin_amdgcn_global_load_lds(
      (__attribute__((address_space(1))) const void*)gp,
      (__attribute__((address_space(3))) void*)lds_base, 16, 0, 0);
}

// ---------------- zero scalar slots ----------------
__global__ void k_zero(unsigned* p, int n) {
  int i = blockIdx.x * blockDim.x + threadIdx.x;
  if (i < n) p[i] = 0u;
}

// ------------- weight transpose fp32 W[K][N] -> bf16 WT[N][K] -------------
__global__ __launch_bounds__(256) void k_wt(const float* __restrict__ W,
                                            ushort* __restrict__ WT, int K, int N) {
  __shared__ float T[32][33];
  int k0 = blockIdx.y * 32, n0 = blockIdx.x * 32;
  int tx = threadIdx.x & 31, ty = threadIdx.x >> 5;
  #pragma unroll
  for (int r = ty; r < 32; r += 8) {
    int k = k0 + r, n = n0 + tx;
    T[r][tx] = (k < K && n < N) ? W[(size_t)k * N + n] : 0.f;
  }
  __syncthreads();
  #pragma unroll
  for (int r = ty; r < 32; r += 8) {
    int n = n0 + r, k = k0 + tx;
    if (n < N && k < K) WT[(size_t)n * K + k] = f2b(T[tx][r]);
  }
}

// ---------------- f32 -> bf16 elementwise ----------------
__global__ void k_cvt(const float* __restrict__ in, ushort* __restrict__ out, int n) {
  int i = blockIdx.x * 256 + threadIdx.x;
  if (i < n) out[i] = f2b(in[i]);
}

// ---------------- layernorm (C==1280), out bf16 ----------------
__global__ __launch_bounds__(256) void k_ln(const float* __restrict__ x,
    const float* __restrict__ g, const float* __restrict__ b,
    ushort* __restrict__ out) {
  const int C = 1280;
  int row = blockIdx.x, tid = threadIdx.x;
  const float* xr = x + (size_t)row * C;
  float v0 = xr[tid], v1 = xr[tid + 256], v2 = xr[tid + 512],
        v3 = xr[tid + 768], v4 = xr[tid + 1024];
  float s = v0 + v1 + v2 + v3 + v4;
  float ss = v0 * v0 + v1 * v1 + v2 * v2 + v3 * v3 + v4 * v4;
  #pragma unroll
  for (int off = 32; off; off >>= 1) {
    s += __shfl_down(s, off);
    ss += __shfl_down(ss, off);
  }
  __shared__ float red[8];
  __shared__ float mu_s, rstd_s;
  int wave = tid >> 6, lane = tid & 63;
  if (lane == 0) { red[wave] = s; red[4 + wave] = ss; }
  __syncthreads();
  if (tid == 0) {
    float S = red[0] + red[1] + red[2] + red[3];
    float SS = red[4] + red[5] + red[6] + red[7];
    float mu = S / C;
    float var = SS / C - mu * mu;
    mu_s = mu;
    rstd_s = rsqrtf(var + 1e-5f);
  }
  __syncthreads();
  float mu = mu_s, rstd = rstd_s;
  size_t o = (size_t)row * C + tid;
  out[o]        = f2b((v0 - mu) * rstd * g[tid]        + b[tid]);
  out[o + 256]  = f2b((v1 - mu) * rstd * g[tid + 256]  + b[tid + 256]);
  out[o + 512]  = f2b((v2 - mu) * rstd * g[tid + 512]  + b[tid + 512]);
  out[o + 768]  = f2b((v3 - mu) * rstd * g[tid + 768]  + b[tid + 768]);
  out[o + 1024] = f2b((v4 - mu) * rstd * g[tid + 1024] + b[tid + 1024]);
}

// ---- GEMM epilogue helpers (by-value f32x4, constant swizzles: SROA-proof) ----
DEV void st1(float v, int r_, int c_, int ldc, const float* resid,
             float* Cf, ushort* Cb) {
  size_t o = (size_t)r_ * ldc + c_;
  if (resid) v += resid[o];
  if (Cf) Cf[o] = v;
  if (Cb) Cb[o] = f2b(v);
}
DEV float epi4(f32x4 v, int rbase, int c_, int M, int N, int ldc,
               const float* bias, const float* resid, float* Cf, ushort* Cb) {
  float v0 = v.x, v1 = v.y, v2 = v.z, v3 = v.w;
  float am = fmaxf(fmaxf(fabsf(v0), fabsf(v1)), fmaxf(fabsf(v2), fabsf(v3)));
  if (c_ < N) {
    float bb = bias ? bias[c_] : 0.f;
    v0 += bb; v1 += bb; v2 += bb; v3 += bb;
    if (rbase + 0 < M) st1(v0, rbase + 0, c_, ldc, resid, Cf, Cb);
    if (rbase + 1 < M) st1(v1, rbase + 1, c_, ldc, resid, Cf, Cb);
    if (rbase + 2 < M) st1(v2, rbase + 2, c_, ldc, resid, Cf, Cb);
    if (rbase + 3 < M) st1(v3, rbase + 3, c_, ldc, resid, Cf, Cb);
  }
  return am;
}

// ---------------- bf16 NT GEMM: C[M,N] = A[M,K] @ BT[N,K]^T ----------------
// 128x128 tile, 4 waves (2x2 of 64x64), 16x16x32 MFMA, BK=32,
// global_load_lds width=16 staging. Used for odd-shaped (M=616) GEMMs.
__global__ __launch_bounds__(256) void k_gemm(
    const ushort* __restrict__ A, int lda,
    const ushort* __restrict__ BT, int ldb,
    float* __restrict__ Cf, ushort* __restrict__ Cb, int ldc,
    const float* __restrict__ bias, const float* __restrict__ resid,
    unsigned* am_slot, int M, int N, int K, int slcN) {
  __shared__ __align__(16) ushort SAB[8192];  // A[128][32] @0, B[128][32] @4096
  int tid = threadIdx.x;
  int wave = tid >> 6, lane = tid & 63;
  int q = lane >> 4, mi = lane & 15;
  int wr = (wave >> 1) * 64, wc = (wave & 1) * 64;
  int bm0 = blockIdx.y * 128, bn0 = blockIdx.x * 128;
  f32x4 c00 = {}, c01 = {}, c02 = {}, c03 = {};
  f32x4 c10 = {}, c11 = {}, c12 = {}, c13 = {};
  f32x4 c20 = {}, c21 = {}, c22 = {}, c23 = {};
  f32x4 c30 = {}, c31 = {}, c32 = {}, c33 = {};
  for (int k0 = 0; k0 < K; k0 += 32) {
    __syncthreads();
    #pragma unroll
    for (int t = 0; t < 4; t++) {
      int c = wave * 256 + t * 64 + lane;
      const ushort* gp;
      if (c < 512) {
        int r = c >> 2, kc = (c & 3) << 3;
        int gr = bm0 + r; if (gr >= M) gr = M - 1;
        gp = A + (size_t)gr * lda + k0 + kc;
      } else {
        int c2 = c - 512;
        int r = c2 >> 2, kc = (c2 & 3) << 3;
        int gn = bn0 + r; if (gn >= N) gn = N - 1;
        gp = BT + (size_t)gn * ldb + k0 + kc;
      }
      gl_lds16(&SAB[(wave * 256 + t * 64) * 8], gp);
    }
    __syncthreads();
    const ushort* Ab = &SAB[(wr + mi) * 32 + q * 8];
    const ushort* Bb = &SAB[4096 + (wc + mi) * 32 + q * 8];
    bf16x8 a0 = *(const bf16x8*)(Ab);
    bf16x8 a1 = *(const bf16x8*)(Ab + 512);
    bf16x8 a2 = *(const bf16x8*)(Ab + 1024);
    bf16x8 a3 = *(const bf16x8*)(Ab + 1536);
    bf16x8 b0 = *(const bf16x8*)(Bb);
    bf16x8 b1 = *(const bf16x8*)(Bb + 512);
    bf16x8 b2 = *(const bf16x8*)(Bb + 1024);
    bf16x8 b3 = *(const bf16x8*)(Bb + 1536);
    MF(a0, b0, c00); MF(a0, b1, c01); MF(a0, b2, c02); MF(a0, b3, c03);
    MF(a1, b0, c10); MF(a1, b1, c11); MF(a1, b2, c12); MF(a1, b3, c13);
    MF(a2, b0, c20); MF(a2, b1, c21); MF(a2, b2, c22); MF(a2, b3, c23);
    MF(a3, b0, c30); MF(a3, b1, c31); MF(a3, b2, c32); MF(a3, b3, c33);
  }
  int rb = bm0 + wr + q * 4, cb = bn0 + wc + mi;
  float am = 0.f;
  am = fmaxf(am, epi4(c00, rb +  0, cb +  0, M, N, ldc, bias, resid, Cf, Cb));
  am = fmaxf(am, epi4(c01, rb +  0, cb + 16, M, N, ldc, bias, resid, Cf, Cb));
  am = fmaxf(am, epi4(c02, rb +  0, cb + 32, M, N, ldc, bias, resid, Cf, Cb));
  am = fmaxf(am, epi4(c03, rb +  0, cb + 48, M, N, ldc, bias, resid, Cf, Cb));
  am = fmaxf(am, epi4(c10, rb + 16, cb +  0, M, N, ldc, bias, resid, Cf, Cb));
  am = fmaxf(am, epi4(c11, rb + 16, cb + 16, M, N, ldc, bias, resid, Cf, Cb));
  am = fmaxf(am, epi4(c12, rb + 16, cb + 32, M, N, ldc, bias, resid, Cf, Cb));
  am = fmaxf(am, epi4(c13, rb + 16, cb + 48, M, N, ldc, bias, resid, Cf, Cb));
  am = fmaxf(am, epi4(c20, rb + 32, cb +  0, M, N, ldc, bias, resid, Cf, Cb));
  am = fmaxf(am, epi4(c21, rb + 32, cb + 16, M, N, ldc, bias, resid, Cf, Cb));
  am = fmaxf(am, epi4(c22, rb + 32, cb + 32, M, N, ldc, bias, resid, Cf, Cb));
  am = fmaxf(am, epi4(c23, rb + 32, cb + 48, M, N, ldc, bias, resid, Cf, Cb));
  am = fmaxf(am, epi4(c30, rb + 48, cb +  0, M, N, ldc, bias, resid, Cf, Cb));
  am = fmaxf(am, epi4(c31, rb + 48, cb + 16, M, N, ldc, bias, resid, Cf, Cb));
  am = fmaxf(am, epi4(c32, rb + 48, cb + 32, M, N, ldc, bias, resid, Cf, Cb));
  am = fmaxf(am, epi4(c33, rb + 48, cb + 48, M, N, ldc, bias, resid, Cf, Cb));
  if (am_slot) {
    #pragma unroll
    for (int off = 32; off; off >>= 1) am = fmaxf(am, __shfl_down(am, off));
    if (lane == 0) atomicMax(am_slot + bn0 / slcN, __float_as_uint(am));
  }
}

// ------- vectorized multi-slice fake-quant: 8 bf16/thread, slot by col -------
__global__ void k_quant8(const ushort* __restrict__ in, ushort* __restrict__ out,
                         const unsigned* __restrict__ slotb, int n8,
                         int colw8, int ld, int slcw) {
  int i = blockIdx.x * 256 + threadIdx.x;
  if (i >= n8) return;
  int row = i / colw8, c8 = i - row * colw8;
  int col = c8 * 8;
  size_t a = (size_t)row * ld + col;
  float delta = fmaxf(__uint_as_float(slotb[col / slcw]), 1e-8f) * (1.f / 127.f);
  bf16x8 v = *(const bf16x8*)(in + a);
  bf16x8 r;
  #pragma unroll
  for (int j = 0; j < 8; j++) {
    float x = b2f((ushort)v[j]);
    float y = fminf(fmaxf(rintf(x / delta), -128.f), 127.f) * delta;
    r[j] = (short)f2b(y);
  }
  *(bf16x8*)(out + a) = r;
}

// ------- V transpose per head: vq[(b*Mr+m)*ldv + h*64+d] -> vT[bh][d][m] (zero-pad) -------
__global__ __launch_bounds__(256) void k_vt(const ushort* __restrict__ vq,
    ushort* __restrict__ vT, int H, int Mr, int Mpad, int ldv) {
  __shared__ __align__(16) ushort T[64][72];
  int bh = blockIdx.y, b = bh / H, h = bh % H;
  int m0 = blockIdx.x * 64;
  int tid = threadIdx.x;
  #pragma unroll
  for (int c = tid; c < 512; c += 256) {
    int mm = c >> 3, dc = (c & 7) << 3;
    int m = m0 + mm;
    int4 val = make_int4(0, 0, 0, 0);
    if (m < Mr) val = *(const int4*)(vq + ((size_t)b * Mr + m) * ldv + h * 64 + dc);
    *(int4*)&T[mm][dc] = val;
  }
  __syncthreads();
  #pragma unroll
  for (int c = tid; c < 512; c += 256) {
    int dd = c >> 3, mc = (c & 7) << 3;
    unsigned w0 = (unsigned)T[mc + 0][dd] | ((unsigned)T[mc + 1][dd] << 16);
    unsigned w1 = (unsigned)T[mc + 2][dd] | ((unsigned)T[mc + 3][dd] << 16);
    unsigned w2 = (unsigned)T[mc + 4][dd] | ((unsigned)T[mc + 5][dd] << 16);
    unsigned w3 = (unsigned)T[mc + 6][dd] | ((unsigned)T[mc + 7][dd] << 16);
    int4 val = make_int4((int)w0, (int)w1, (int)w2, (int)w3);
    *(int4*)(vT + ((size_t)bh * 64 + dd) * Mpad + m0 + mc) = val;
  }
}

#define NEGI -3.0e38f
#define VMA4 asm volatile("s_waitcnt vmcnt(4)" ::: "memory")
#define VMA2 asm volatile("s_waitcnt vmcnt(2)" ::: "memory")
#define VMA0 asm volatile("s_waitcnt vmcnt(0)" ::: "memory")
#define LGK0 asm volatile("s_waitcnt lgkmcnt(0)" ::: "memory")
#define RBAR __builtin_amdgcn_s_barrier()

// online-softmax tile update for one 16-row set (per-row math identical to before)
#define ONLUPD(SA, SB, SC, SD, MRUN, ZRUN) do { \
  float e0  = b0_  ? (SA).x * cs : NEGI; \
  float e1  = b1_  ? (SA).y * cs : NEGI; \
  float e2  = b2_  ? (SA).z * cs : NEGI; \
  float e3  = b3_  ? (SA).w * cs : NEGI; \
  float e4  = b4_  ? (SB).x * cs : NEGI; \
  float e5  = b5_  ? (SB).y * cs : NEGI; \
  float e6  = b6_  ? (SB).z * cs : NEGI; \
  float e7  = b7_  ? (SB).w * cs : NEGI; \
  float e8  = b8_  ? (SC).x * cs : NEGI; \
  float e9  = b9_  ? (SC).y * cs : NEGI; \
  float e10 = b10_ ? (SC).z * cs : NEGI; \
  float e11 = b11_ ? (SC).w * cs : NEGI; \
  float e12 = b12_ ? (SD).x * cs : NEGI; \
  float e13 = b13_ ? (SD).y * cs : NEGI; \
  float e14 = b14_ ? (SD).z * cs : NEGI; \
  float e15 = b15_ ? (SD).w * cs : NEGI; \
  float tm = fmaxf(fmaxf(fmaxf(fmaxf(e0, e1), fmaxf(e2, e3)), \
                         fmaxf(fmaxf(e4, e5), fmaxf(e6, e7))), \
                   fmaxf(fmaxf(fmaxf(e8, e9), fmaxf(e10, e11)), \
                         fmaxf(fmaxf(e12, e13), fmaxf(e14, e15)))); \
  float mn = fmaxf(MRUN, tm); \
  float zs = exp2f(e0 - mn)  + exp2f(e1 - mn)  + exp2f(e2 - mn)  + exp2f(e3 - mn) \
           + exp2f(e4 - mn)  + exp2f(e5 - mn)  + exp2f(e6 - mn)  + exp2f(e7 - mn) \
           + exp2f(e8 - mn)  + exp2f(e9 - mn)  + exp2f(e10 - mn) + exp2f(e11 - mn) \
           + exp2f(e12 - mn) + exp2f(e13 - mn) + exp2f(e14 - mn) + exp2f(e15 - mn); \
  ZRUN = ZRUN * exp2f(MRUN - mn) + zs; MRUN = mn; \
} while (0)

// ------- attention phase 1, QBLK=128, gl_lds16 K staging (2-deep, swizzled) -------
// Swapped QK^T: MF(k, q, s) => lane owns ONE q-row; two 16-row sets per wave.
// K LDS: linear [64][64] per buf; chunk swizzle p = ck ^ (row&7) both sides.
__global__ __launch_bounds__(256) void k_attn1(
    const ushort* __restrict__ qq, const ushort* __restrict__ kq,
    float2* __restrict__ rs, unsigned* __restrict__ pmax,
    int H, int N, int Mr, int ldq, int ldk, float cs) {   // cs = scale * log2(e)
  __shared__ __align__(16) ushort Qs[128][72];
  __shared__ __align__(16) ushort KL[2][4096];
  int tid = threadIdx.x;
  int wave = tid >> 6, lane = tid & 63;
  int q = lane >> 4, mi = lane & 15;
  int bh = blockIdx.y, b = bh / H, h = bh % H;
  int r0 = blockIdx.x * 128;
  #pragma unroll
  for (int c = tid; c < 1024; c += 256) {
    int r = c >> 3, dc = (c & 7) << 3;
    *(int4*)&Qs[r][dc] = *(const int4*)(qq + ((size_t)b * N + r0 + r) * ldq + h * 64 + dc);
  }
  int lr8 = lane >> 3;                    // 0..7 (row within 8-row stripe)
  int ck = (lane & 7) ^ lr8;              // inverse-swizzled source chunk
  const ushort* kbase = kq + (size_t)b * Mr * ldk + h * 64 + ck * 8;
  auto stK = [&](int mt, int bb) {
    #pragma unroll
    for (int c = 0; c < 2; c++) {
      int base8 = c * 4 + wave;
      int m = mt * 64 + base8 * 8 + lr8; if (m >= Mr) m = Mr - 1;
      gl_lds16(&KL[bb][base8 * 512], kbase + (size_t)m * ldk);
    }
  };
  int nt = (Mr + 63) >> 6;
  stK(0, 0);
  if (nt > 1) { stK(1, 1); VMA2; } else VMA0;
  LGK0;   // own Q ds_writes done
  RBAR;   // all waves' Q writes + tile0 visible

  float m0r = NEGI, z0r = 0.f, m1r = NEGI, z1r = 0.f;
  int co0 = (q ^ (mi & 7)) * 8;           // kc=0 swizzled elem offset
  int co1 = ((4 + q) ^ (mi & 7)) * 8;     // kc=1
  for (int mt = 0; mt < nt; mt++) {
    const ushort* KB = &KL[mt & 1][0];
    f32x4 s0 = {}, s1 = {}, s2 = {}, s3 = {};
    f32x4 s4 = {}, s5 = {}, s6 = {}, s7 = {};
    #pragma unroll
    for (int kc = 0; kc < 2; kc++) {
      int co = kc ? co1 : co0;
      bf16x8 qv0 = *(const bf16x8*)&Qs[wave * 32 + mi][kc * 32 + q * 8];
      bf16x8 qv1 = *(const bf16x8*)&Qs[wave * 32 + 16 + mi][kc * 32 + q * 8];
      bf16x8 k0v = *(const bf16x8*)&KB[mi * 64 + co];
      bf16x8 k1v = *(const bf16x8*)&KB[(16 + mi) * 64 + co];
      bf16x8 k2v = *(const bf16x8*)&KB[(32 + mi) * 64 + co];
      bf16x8 k3v = *(const bf16x8*)&KB[(48 + mi) * 64 + co];
      MF(k0v, qv0, s0); MF(k1v, qv0, s1); MF(k2v, qv0, s2); MF(k3v, qv0, s3);
      MF(k0v, qv1, s4); MF(k1v, qv1, s5); MF(k2v, qv1, s6); MF(k3v, qv1, s7);
    }
    int kb = mt * 64 + q * 4;
    bool b0_  = kb + 0  < Mr, b1_  = kb + 1  < Mr, b2_  = kb + 2  < Mr, b3_  = kb + 3  < Mr;
    bool b4_  = kb + 16 < Mr, b5_  = kb + 17 < Mr, b6_  = kb + 18 < Mr, b7_  = kb + 19 < Mr;
    bool b8_  = kb + 32 < Mr, b9_  = kb + 33 < Mr, b10_ = kb + 34 < Mr, b11_ = kb + 35 < Mr;
    bool b12_ = kb + 48 < Mr, b13_ = kb + 49 < Mr, b14_ = kb + 50 < Mr, b15_ = kb + 51 < Mr;
    ONLUPD(s0, s1, s2, s3, m0r, z0r);
    ONLUPD(s4, s5, s6, s7, m1r, z1r);
    RBAR;                                   // all waves done reading buf (mt&1)
    if (mt + 2 < nt) { stK(mt + 2, mt & 1); VMA2; }
    else VMA0;
    RBAR;                                   // tile mt+1 ready for everyone
  }
  // cross-q combine (4 lanes share a q-row: lane, lane^16, lane^32, lane^48)
  float mo0 = fmaxf(m0r, __shfl_xor(m0r, 16));
  mo0 = fmaxf(mo0, __shfl_xor(mo0, 32));
  float zz0 = z0r * exp2f(m0r - mo0);
  zz0 += __shfl_xor(zz0, 16);
  zz0 += __shfl_xor(zz0, 32);
  float mo1 = fmaxf(m1r, __shfl_xor(m1r, 16));
  mo1 = fmaxf(mo1, __shfl_xor(mo1, 32));
  float zz1 = z1r * exp2f(m1r - mo1);
  zz1 += __shfl_xor(zz1, 16);
  zz1 += __shfl_xor(zz1, 32);
  if (q == 0) {
    float2 st; st.x = mo0; st.y = zz0;
    rs[(size_t)bh * N + r0 + wave * 32 + mi] = st;
    st.x = mo1; st.y = zz1;
    rs[(size_t)bh * N + r0 + wave * 32 + 16 + mi] = st;
  }
  float pm = fmaxf(1.f / zz0, 1.f / zz1);
  #pragma unroll
  for (int off = 32; off; off >>= 1) pm = fmaxf(pm, __shfl_down(pm, off));
  if (lane == 0) atomicMax(pmax, __float_as_uint(pm));
}

// quantized-prob level: q8 = min(rint(2^(s*cs - mc)), 255), exact in bf16 via shift
DEV ushort q8lvl(float s, float cs, float mc) {
  float p = fminf(rintf(exp2f(fmaf(s, cs, -mc))), 255.f);
  return (ushort)(__float_as_uint(p) >> 16);
}

#define PWR(RB, SA, SB, SC, SD, M0_, M1_, M2_, M3_) do { \
  Ps[(RB) + 0][mi]      = ok0 ? q8lvl((SA).x, cs, M0_) : (ushort)0; \
  Ps[(RB) + 1][mi]      = ok0 ? q8lvl((SA).y, cs, M1_) : (ushort)0; \
  Ps[(RB) + 2][mi]      = ok0 ? q8lvl((SA).z, cs, M2_) : (ushort)0; \
  Ps[(RB) + 3][mi]      = ok0 ? q8lvl((SA).w, cs, M3_) : (ushort)0; \
  Ps[(RB) + 0][16 + mi] = ok1 ? q8lvl((SB).x, cs, M0_) : (ushort)0; \
  Ps[(RB) + 1][16 + mi] = ok1 ? q8lvl((SB).y, cs, M1_) : (ushort)0; \
  Ps[(RB) + 2][16 + mi] = ok1 ? q8lvl((SB).z, cs, M2_) : (ushort)0; \
  Ps[(RB) + 3][16 + mi] = ok1 ? q8lvl((SB).w, cs, M3_) : (ushort)0; \
  Ps[(RB) + 0][32 + mi] = ok2 ? q8lvl((SC).x, cs, M0_) : (ushort)0; \
  Ps[(RB) + 1][32 + mi] = ok2 ? q8lvl((SC).y, cs, M1_) : (ushort)0; \
  Ps[(RB) + 2][32 + mi] = ok2 ? q8lvl((SC).z, cs, M2_) : (ushort)0; \
  Ps[(RB) + 3][32 + mi] = ok2 ? q8lvl((SC).w, cs, M3_) : (ushort)0; \
  Ps[(RB) + 0][48 + mi] = ok3 ? q8lvl((SD).x, cs, M0_) : (ushort)0; \
  Ps[(RB) + 1][48 + mi] = ok3 ? q8lvl((SD).y, cs, M1_) : (ushort)0; \
  Ps[(RB) + 2][48 + mi] = ok3 ? q8lvl((SD).z, cs, M2_) : (ushort)0; \
  Ps[(RB) + 3][48 + mi] = ok3 ? q8lvl((SD).w, cs, M3_) : (ushort)0; \
} while (0)

#define OSTORE(RRBASE, OA, OB, OC, OD) do { \
  size_t base = ((size_t)b * N + (RRBASE)) * C + h * 64 + mi; \
  ao[base]              = f2b((OA).x * delta); ao[base + C]          = f2b((OA).y * delta); \
  ao[base + 2 * C]      = f2b((OA).z * delta); ao[base + 3 * C]      = f2b((OA).w * delta); \
  ao[base + 16]         = f2b((OB).x * delta); ao[base + C + 16]     = f2b((OB).y * delta); \
  ao[base + 2 * C + 16] = f2b((OB).z * delta); ao[base + 3 * C + 16] = f2b((OB).w * delta); \
  ao[base + 32]         = f2b((OC).x * delta); ao[base + C + 32]     = f2b((OC).y * delta); \
  ao[base + 2 * C + 32] = f2b((OC).z * delta); ao[base + 3 * C + 32] = f2b((OC).w * delta); \
  ao[base + 48]         = f2b((OD).x * delta); ao[base + C + 48]     = f2b((OD).y * delta); \
  ao[base + 2 * C + 48] = f2b((OD).z * delta); ao[base + 3 * C + 48] = f2b((OD).w * delta); \
} while (0)

// ------- attention phase 2, QBLK=128, gl_lds16 K+V staging (2-deep, swizzled) -------
__global__ __launch_bounds__(256) void k_attn2(
    const ushort* __restrict__ qq, const ushort* __restrict__ kq,
    const ushort* __restrict__ vT, const float2* __restrict__ rs,
    const unsigned* __restrict__ pmax, ushort* __restrict__ ao,
    int H, int N, int Mr, int Mpad, int ldq, int ldk, float cs) {
  const int C = 1280;
  __shared__ __align__(16) ushort Qs[128][72];
  __shared__ __align__(16) ushort Ps[128][72];
  __shared__ __align__(16) ushort KL[2][4096];
  __shared__ __align__(16) ushort VL[2][4096];
  int tid = threadIdx.x;
  int wave = tid >> 6, lane = tid & 63;
  int q = lane >> 4, mi = lane & 15;
  int bh = blockIdx.y, b = bh / H, h = bh % H;
  int r0 = blockIdx.x * 128;
  #pragma unroll
  for (int c = tid; c < 1024; c += 256) {
    int r = c >> 3, dc = (c & 7) << 3;
    *(int4*)&Qs[r][dc] = *(const int4*)(qq + ((size_t)b * N + r0 + r) * ldq + h * 64 + dc);
  }
  int lr8 = lane >> 3;
  int ck = (lane & 7) ^ lr8;
  const ushort* kbase = kq + (size_t)b * Mr * ldk + h * 64 + ck * 8;
  const ushort* vbase = vT + ((size_t)bh * 64) * Mpad + ck * 8;
  auto stKV = [&](int mt, int bb) {
    #pragma unroll
    for (int c = 0; c < 2; c++) {
      int base8 = c * 4 + wave;
      int rloc = base8 * 8 + lr8;
      int m = mt * 64 + rloc; if (m >= Mr) m = Mr - 1;
      gl_lds16(&KL[bb][base8 * 512], kbase + (size_t)m * ldk);
      gl_lds16(&VL[bb][base8 * 512], vbase + (size_t)rloc * Mpad + mt * 64);
    }
  };
  int rb0 = wave * 32 + q * 4, rb1 = rb0 + 16;
  float delta = fmaxf(__uint_as_float(*pmax), 1e-8f) * (1.f / 255.f);
  float ldl = __log2f(delta);
  float2 u0 = rs[(size_t)bh * N + r0 + rb0 + 0];
  float2 u1 = rs[(size_t)bh * N + r0 + rb0 + 1];
  float2 u2 = rs[(size_t)bh * N + r0 + rb0 + 2];
  float2 u3 = rs[(size_t)bh * N + r0 + rb0 + 3];
  float2 u4 = rs[(size_t)bh * N + r0 + rb1 + 0];
  float2 u5 = rs[(size_t)bh * N + r0 + rb1 + 1];
  float2 u6 = rs[(size_t)bh * N + r0 + rb1 + 2];
  float2 u7 = rs[(size_t)bh * N + r0 + rb1 + 3];
  float mc0 = u0.x + __log2f(u0.y) + ldl;
  float mc1 = u1.x + __log2f(u1.y) + ldl;
  float mc2 = u2.x + __log2f(u2.y) + ldl;
  float mc3 = u3.x + __log2f(u3.y) + ldl;
  float mc4 = u4.x + __log2f(u4.y) + ldl;
  float mc5 = u5.x + __log2f(u5.y) + ldl;
  float mc6 = u6.x + __log2f(u6.y) + ldl;
  float mc7 = u7.x + __log2f(u7.y) + ldl;
  int nt = (Mr + 63) >> 6;
  stKV(0, 0);
  if (nt > 1) { stKV(1, 1); VMA4; } else VMA0;
  LGK0;
  RBAR;

  f32x4 o0 = {}, o1 = {}, o2 = {}, o3 = {};
  f32x4 o4 = {}, o5 = {}, o6 = {}, o7 = {};
  int co0 = (q ^ (mi & 7)) * 8;
  int co1 = ((4 + q) ^ (mi & 7)) * 8;
  for (int mt = 0; mt < nt; mt++) {
    const ushort* KB = &KL[mt & 1][0];
    const ushort* VB = &VL[mt & 1][0];
    f32x4 s0 = {}, s1 = {}, s2 = {}, s3 = {};
    f32x4 s4 = {}, s5 = {}, s6 = {}, s7 = {};
    #pragma unroll
    for (int kc = 0; kc < 2; kc++) {
      int co = kc ? co1 : co0;
      bf16x8 aq0 = *(const bf16x8*)&Qs[wave * 32 + mi][kc * 32 + q * 8];
      bf16x8 aq1 = *(const bf16x8*)&Qs[wave * 32 + 16 + mi][kc * 32 + q * 8];
      bf16x8 k0v = *(const bf16x8*)&KB[mi * 64 + co];
      bf16x8 k1v = *(const bf16x8*)&KB[(16 + mi) * 64 + co];
      bf16x8 k2v = *(const bf16x8*)&KB[(32 + mi) * 64 + co];
      bf16x8 k3v = *(const bf16x8*)&KB[(48 + mi) * 64 + co];
      MF(aq0, k0v, s0); MF(aq0, k1v, s1); MF(aq0, k2v, s2); MF(aq0, k3v, s3);
      MF(aq1, k0v, s4); MF(aq1, k1v, s5); MF(aq1, k2v, s6); MF(aq1, k3v, s7);
    }
    int mlim = Mr - mt * 64;
    bool ok0 = (mi      < mlim);
    bool ok1 = (16 + mi < mlim);
    bool ok2 = (32 + mi < mlim);
    bool ok3 = (48 + mi < mlim);
    PWR(rb0, s0, s1, s2, s3, mc0, mc1, mc2, mc3);
    PWR(rb1, s4, s5, s6, s7, mc4, mc5, mc6, mc7);
    // wave-local RAW through LDS: rows 32w..32w+31 written & read by wave w only.
    LGK0;
    __builtin_amdgcn_sched_barrier(0);
    #pragma unroll
    for (int kc = 0; kc < 2; kc++) {
      int co = kc ? co1 : co0;
      bf16x8 ap0 = *(const bf16x8*)&Ps[wave * 32 + mi][kc * 32 + q * 8];
      bf16x8 ap1 = *(const bf16x8*)&Ps[wave * 32 + 16 + mi][kc * 32 + q * 8];
      bf16x8 v0 = *(const bf16x8*)&VB[mi * 64 + co];
      bf16x8 v1 = *(const bf16x8*)&VB[(16 + mi) * 64 + co];
      bf16x8 v2 = *(const bf16x8*)&VB[(32 + mi) * 64 + co];
      bf16x8 v3 = *(const bf16x8*)&VB[(48 + mi) * 64 + co];
      MF(ap0, v0, o0); MF(ap0, v1, o1); MF(ap0, v2, o2); MF(ap0, v3, o3);
      MF(ap1, v0, o4); MF(ap1, v1, o5); MF(ap1, v2, o6); MF(ap1, v3, o7);
    }
    RBAR;                                   // all waves done reading buf (mt&1)
    if (mt + 2 < nt) { stKV(mt + 2, mt & 1); VMA4; }
    else VMA0;
    RBAR;                                   // tile mt+1 ready for everyone
  }
  int rr0 = r0 + wave * 32 + q * 4;
  OSTORE(rr0, o0, o1, o2, o3);
  OSTORE(rr0 + 16, o4, o5, o6, o7);
}

// =====================================================================
// shared pipeline macros (T2 xor-swizzle + counted vmcnt + setprio)
// =====================================================================
#define BAR __builtin_amdgcn_s_barrier()
#define LGKM0 do { asm volatile("s_waitcnt lgkmcnt(0)" ::: "memory"); \
                   __builtin_amdgcn_sched_barrier(0); } while (0)
#define VM6 asm volatile("s_waitcnt vmcnt(6)" ::: "memory")
#define VM0 asm volatile("s_waitcnt vmcnt(0)" ::: "memory")
#define PRIO1 __builtin_amdgcn_s_setprio(1)
#define PRIO0 __builtin_amdgcn_s_setprio(0)

#define RDA01(P) do { \
  fa00 = *(const bf16x8*)&(P)[c0];        fa01 = *(const bf16x8*)&(P)[c1]; \
  fa10 = *(const bf16x8*)&(P)[1024 + c0]; fa11 = *(const bf16x8*)&(P)[1024 + c1]; } while (0)
#define RDA23(P) do { \
  fa20 = *(const bf16x8*)&(P)[2048 + c0]; fa21 = *(const bf16x8*)&(P)[2048 + c1]; \
  fa30 = *(const bf16x8*)&(P)[3072 + c0]; fa31 = *(const bf16x8*)&(P)[3072 + c1]; } while (0)
#define RDB(P, H) do { \
  b00 = *(const bf16x8*)&(P)[(H) + c0];        b01 = *(const bf16x8*)&(P)[(H) + c1]; \
  b10 = *(const bf16x8*)&(P)[(H) + 1024 + c0]; b11 = *(const bf16x8*)&(P)[(H) + 1024 + c1]; \
  b20 = *(const bf16x8*)&(P)[(H) + 2048 + c0]; b21 = *(const bf16x8*)&(P)[(H) + 2048 + c1]; \
  b30 = *(const bf16x8*)&(P)[(H) + 3072 + c0]; b31 = *(const bf16x8*)&(P)[(H) + 3072 + c1]; } while (0)
#define RDB8(P) RDB(P, 0)

#define MM8(AX0, AX1, AY0, AY1, C0, C1, C2, C3, D0, D1, D2, D3) \
  MF(AX0, b00, C0); MF(AX1, b01, C0); MF(AX0, b10, C1); MF(AX1, b11, C1); \
  MF(AX0, b20, C2); MF(AX1, b21, C2); MF(AX0, b30, C3); MF(AX1, b31, C3); \
  MF(AY0, b00, D0); MF(AY1, b01, D0); MF(AY0, b10, D1); MF(AY1, b11, D1); \
  MF(AY0, b20, D2); MF(AY1, b21, D2); MF(AY0, b30, D3); MF(AY1, b31, D3)

// =====================================================================
// k_gemm8: 8-wave 256x128-tile NT GEMM, BK=64, TRIPLE-buffered LDS (144 KiB),
// 2 phases/K-tile of 16 MFMA, counted vmcnt(6) (never 0 in main loop).
// Requires M%256==0, N%128==0, K%64==0, K/64>=5, (K/64-2)%3==0, blocks%8==0.
// =====================================================================
#define GB8(AP, BP, DB, KT) \
  RDA01(AP); RDB8(BP); \
  stB(DB, KT, 0); stB(DB, KT, 1); stA(DB, KT, 0); \
  BAR; LGKM0; \
  PRIO1; MM8(fa00, fa01, fa10, fa11, c00, c01, c02, c03, c10, c11, c12, c13); PRIO0; \
  BAR; \
  RDA23(AP); \
  stA(DB, KT, 1); stA(DB, KT, 2); stA(DB, KT, 3); \
  BAR; LGKM0; \
  PRIO1; MM8(fa20, fa21, fa30, fa31, c20, c21, c22, c23, c30, c31, c32, c33); PRIO0; \
  VM6; BAR;

#define GT8(AP, BP) \
  RDA01(AP); RDB8(BP); \
  BAR; LGKM0; \
  PRIO1; MM8(fa00, fa01, fa10, fa11, c00, c01, c02, c03, c10, c11, c12, c13); PRIO0; \
  BAR; \
  RDA23(AP); \
  BAR; LGKM0; \
  PRIO1; MM8(fa20, fa21, fa30, fa31, c20, c21, c22, c23, c30, c31, c32, c33); PRIO0;

__global__ __launch_bounds__(512) void k_gemm8(
    const ushort* __restrict__ A, int lda,
    const ushort* __restrict__ BT, int ldb,
    float* __restrict__ Cf, ushort* __restrict__ Cb, int ldc,
    const float* __restrict__ bias, const float* __restrict__ resid,
    unsigned* am_slot, int M, int N, int K, int slcN) {
  // per buf (24576 ushorts): A[256][64] @0, B[128][64] @16384. Swizzle: col ^= (row&7)*8.
  __shared__ __align__(16) ushort SAB[73728];  // 144 KiB, 3 bufs
  int tid = threadIdx.x;
  int wave = tid >> 6, lane = tid & 63;
  int q = lane >> 4, mi = lane & 15;
  int wm = wave >> 1, wn = wave & 1;
  int lr = lane >> 3;
  int lc = ((lane & 7) ^ lr) * 8;   // inverse-swizzled source col (elems)

  int NBN = N >> 7;
  int nblk = (M >> 8) * NBN;
  int cpx = nblk >> 3;
  int wg = blockIdx.x;
  int swz = (wg & 7) * cpx + (wg >> 3);   // bijective: nblk % 8 == 0
  int bm0 = (swz / NBN) << 8, bn0 = (swz % NBN) << 7;

  const int swzr = (mi & 7) * 8;
  int c0 = (q * 8) ^ swzr, c1 = (32 + q * 8) ^ swzr;
  const ushort* A0p = &SAB[(wm * 64 + mi) * 64];
  const ushort* B0p = &SAB[16384 + (wn * 64 + mi) * 64];
  const ushort* A1p = A0p + 24576; const ushort* B1p = B0p + 24576;
  const ushort* A2p = A0p + 49152; const ushort* B2p = B0p + 49152;

  const ushort* gA = A  + (size_t)(bm0 + wave * 8 + lr) * lda + lc;
  const ushort* gB = BT + (size_t)(bn0 + wave * 8 + lr) * ldb + lc;
  ushort* lA = &SAB[wave * 512];
  ushort* lB = &SAB[16384 + wave * 512];

  auto stA = [&](int bb, int kt, int call) {   // A: 4 calls x 64 rows
    gl_lds16(lA + bb * 24576 + call * 4096,
             gA + (size_t)call * 64 * lda + (size_t)kt * 64);
  };
  auto stB = [&](int bb, int kt, int call) {   // B: 2 calls x 64 rows
    gl_lds16(lB + bb * 24576 + call * 4096,
             gB + (size_t)call * 64 * ldb + (size_t)kt * 64);
  };

  f32x4 c00 = {}, c01 = {}, c02 = {}, c03 = {};
  f32x4 c10 = {}, c11 = {}, c12 = {}, c13 = {};
  f32x4 c20 = {}, c21 = {}, c22 = {}, c23 = {};
  f32x4 c30 = {}, c31 = {}, c32 = {}, c33 = {};
  bf16x8 fa00, fa01, fa10, fa11, fa20, fa21, fa30, fa31;
  bf16x8 b00, b01, b10, b11, b20, b21, b30, b31;

  // prologue: tile0 -> buf0, tile1 -> buf1 (6 calls each)
  stB(0, 0, 0); stB(0, 0, 1);
  stA(0, 0, 0); stA(0, 0, 1); stA(0, 0, 2); stA(0, 0, 3);
  stB(1, 1, 0); stB(1, 1, 1);
  stA(1, 1, 0); stA(1, 1, 1); stA(1, 1, 2); stA(1, 1, 3);
  VM6; BAR;

  int NT = K >> 6, NTm = NT - 2;  // NTm % 3 == 0 by contract
  for (int t = 0; t < NTm; t += 3) {
    GB8(A0p, B0p, 2, t + 2);
    GB8(A1p, B1p, 0, t + 3);
    GB8(A2p, B2p, 1, t + 4);
  }
  // tail: tile NT-2 (buf0), then tile NT-1 (buf1)
  GT8(A0p, B0p);
  VM0; BAR;
  GT8(A1p, B1p);

  int rb = bm0 + wm * 64 + q * 4, cb = bn0 + wn * 64 + mi;
  float am = 0.f;
  am = fmaxf(am, epi4(c00, rb +  0, cb +  0, M, N, ldc, bias, resid, Cf, Cb));
  am = fmaxf(am, epi4(c01, rb +  0, cb + 16, M, N, ldc, bias, resid, Cf, Cb));
  am = fmaxf(am, epi4(c02, rb +  0, cb + 32, M, N, ldc, bias, resid, Cf, Cb));
  am = fmaxf(am, epi4(c03, rb +  0, cb + 48, M, N, ldc, bias, resid, Cf, Cb));
  am = fmaxf(am, epi4(c10, rb + 16, cb +  0, M, N, ldc, bias, resid, Cf, Cb));
  am = fmaxf(am, epi4(c11, rb + 16, cb + 16, M, N, ldc, bias, resid, Cf, Cb));
  am = fmaxf(am, epi4(c12, rb + 16, cb + 32, M, N, ldc, bias, resid, Cf, Cb));
  am = fmaxf(am, epi4(c13, rb + 16, cb + 48, M, N, ldc, bias, resid, Cf, Cb));
  am = fmaxf(am, epi4(c20, rb + 32, cb +  0, M, N, ldc, bias, resid, Cf, Cb));
  am = fmaxf(am, epi4(c21, rb + 32, cb + 16, M, N, ldc, bias, resid, Cf, Cb));
  am = fmaxf(am, epi4(c22, rb + 32, cb + 32, M, N, ldc, bias, resid, Cf, Cb));
  am = fmaxf(am, epi4(c23, rb + 32, cb + 48, M, N, ldc, bias, resid, Cf, Cb));
  am = fmaxf(am, epi4(c30, rb + 48, cb +  0, M, N, ldc, bias, resid, Cf, Cb));
  am = fmaxf(am, epi4(c31, rb + 48, cb + 16, M, N, ldc, bias, resid, Cf, Cb));
  am = fmaxf(am, epi4(c32, rb + 48, cb + 32, M, N, ldc, bias, resid, Cf, Cb));
  am = fmaxf(am, epi4(c33, rb + 48, cb + 48, M, N, ldc, bias, resid, Cf, Cb));
  if (am_slot) {
    #pragma unroll
    for (int off = 32; off; off >>= 1) am = fmaxf(am, __shfl_down(am, off));
    if (lane == 0) atomicMax(am_slot + bn0 / slcN, __float_as_uint(am));
  }
}

// =====================================================================
// fused FF1 + GEGLU, 256x128(GG) tile, BK=64, 8 waves, 8-phase schedule
// =====================================================================
// gelu-tanh via sigmoid identity: 0.5*(1+tanh(x)) == sigmoid(2x)
DEV ushort ggel(float a, float g) {
  float u = 1.5957691216057308f * g * (1.f + 0.044715f * g * g);
  float s = 1.f / (1.f + __expf(-u));
  return f2b(a * g * s);
}
DEV void epi4g(f32x4 va, f32x4 vg, size_t base, float ba, float bg,
               ushort* __restrict__ GG) {
  GG[base]         = ggel(va.x + ba, vg.x + bg);
  GG[base + 5120]  = ggel(va.y + ba, vg.y + bg);
  GG[base + 10240] = ggel(va.z + ba, vg.z + bg);
  GG[base + 15360] = ggel(va.w + ba, vg.w + bg);
}
#define EPIN(nn, P0, Q0, P1, Q1, P2, Q2, P3, Q3) do { \
  int cg = colBase + nn * 16 + mi; \
  float ba = bias[cg], bg = bias[5120 + cg]; \
  size_t b0_ = (size_t)rowBase * 5120 + cg; \
  epi4g(P0, Q0, b0_,             ba, bg, GG); \
  epi4g(P1, Q1, b0_ + 16 * 5120, ba, bg, GG); \
  epi4g(P2, Q2, b0_ + 32 * 5120, ba, bg, GG); \
  epi4g(P3, Q3, b0_ + 48 * 5120, ba, bg, GG); \
} while (0)

__global__ __launch_bounds__(512) void k_ff1_8p(
    const ushort* __restrict__ A,    // LN [8192][1280]
    const ushort* __restrict__ BT,   // WF1T [10240][1280]
    const float* __restrict__ bias,  // bff1 [10240]
    ushort* __restrict__ GG) {       // [8192][5120]
  __shared__ __align__(16) ushort SAB[65536];  // 128 KiB
  int tid = threadIdx.x;
  int wave = tid >> 6, lane = tid & 63;
  int q = lane >> 4, mi = lane & 15;
  int wm = wave >> 1, wn = wave & 1;
  int lr = lane >> 3;
  int lc = ((lane & 7) ^ lr) * 8;  // inverse-swizzled source col (elems)

  int wg = blockIdx.x;
  int swz = (wg & 7) * 160 + (wg >> 3);
  int bm0 = (swz & 31) * 256, bn0 = (swz >> 5) * 128;

  const int swzr = (mi & 7) * 8;
  int c0 = (q * 8) ^ swzr, c1 = (32 + q * 8) ^ swzr;
  const ushort* A0p = &SAB[(wm * 64 + mi) * 64];
  const ushort* B0p = &SAB[16384 + (wn * 64 + mi) * 64];
  const ushort* A1p = A0p + 32768;
  const ushort* B1p = B0p + 32768;

  const ushort* gA  = A  + (size_t)(bm0 + wave * 8 + lr) * 1280 + lc;
  const ushort* gBa = BT + (size_t)(bn0 + wave * 8 + lr) * 1280 + lc;
  const ushort* gBg = BT + (size_t)(5120 + bn0 + wave * 8 + lr) * 1280 + lc;
  ushort* lA = &SAB[wave * 512];
  ushort* lB = &SAB[16384 + wave * 512];

  auto stA = [&](int bb, int kt, int call) {
    gl_lds16(lA + bb * 32768 + call * 4096,
             gA + (size_t)call * 81920 + (size_t)kt * 64);
  };
  auto stBa = [&](int bb, int kt, int call) {
    gl_lds16(lB + bb * 32768 + call * 4096,
             gBa + (size_t)call * 81920 + (size_t)kt * 64);
  };
  auto stBg = [&](int bb, int kt, int call) {
    gl_lds16(lB + bb * 32768 + (call + 2) * 4096,
             gBg + (size_t)call * 81920 + (size_t)kt * 64);
  };

  f32x4 cA00 = {}, cA01 = {}, cA02 = {}, cA03 = {};
  f32x4 cA10 = {}, cA11 = {}, cA12 = {}, cA13 = {};
  f32x4 cA20 = {}, cA21 = {}, cA22 = {}, cA23 = {};
  f32x4 cA30 = {}, cA31 = {}, cA32 = {}, cA33 = {};
  f32x4 cG00 = {}, cG01 = {}, cG02 = {}, cG03 = {};
  f32x4 cG10 = {}, cG11 = {}, cG12 = {}, cG13 = {};
  f32x4 cG20 = {}, cG21 = {}, cG22 = {}, cG23 = {};
  f32x4 cG30 = {}, cG31 = {}, cG32 = {}, cG33 = {};
  bf16x8 fa00, fa01, fa10, fa11, fa20, fa21, fa30, fa31;
  bf16x8 b00, b01, b10, b11, b20, b21, b30, b31;

  stBa(0, 0, 0); stBa(0, 0, 1); stBg(0, 0, 0); stBg(0, 0, 1);
  stA(0, 0, 0); stA(0, 0, 1); stA(0, 0, 2); stA(0, 0, 3);
  stBa(1, 1, 0); stBa(1, 1, 1);
  stA(1, 1, 0); stA(1, 1, 1); stA(1, 1, 2); stA(1, 1, 3);
  VM6; BAR;

  for (int it = 0; it < 10; ++it) {
    int t1 = 2 * it + 1;
    int s0 = t1 + 1; if (s0 > 19) s0 = 19;
    int s1 = t1 + 2; if (s1 > 19) s1 = 19;
    // ---- P1: buf0 m01 x Ba ----
    RDA01(A0p); RDB(B0p, 0);
    stBg(1, t1, 0); stBg(1, t1, 1);
    BAR; LGKM0;
    PRIO1; MM8(fa00, fa01, fa10, fa11, cA00, cA01, cA02, cA03,
               cA10, cA11, cA12, cA13); PRIO0;
    BAR;
    // ---- P2: buf0 m23 x Ba ----
    RDA23(A0p);
    stBa(0, s0, 0); stBa(0, s0, 1);
    BAR; LGKM0;
    PRIO1; MM8(fa20, fa21, fa30, fa31, cA20, cA21, cA22, cA23,
               cA30, cA31, cA32, cA33); PRIO0;
    BAR;
    // ---- P3: buf0 m01 x Bg ----
    RDB(B0p, 8192);
    stA(0, s0, 0); stA(0, s0, 1);
    BAR; LGKM0;
    PRIO1; MM8(fa00, fa01, fa10, fa11, cG00, cG01, cG02, cG03,
               cG10, cG11, cG12, cG13); PRIO0;
    BAR;
    // ---- P4: buf0 m23 x Bg ----
    stA(0, s0, 2); stA(0, s0, 3);
    BAR;
    PRIO1; MM8(fa20, fa21, fa30, fa31, cG20, cG21, cG22, cG23,
               cG30, cG31, cG32, cG33); PRIO0;
    VM6; BAR;
    // ---- P5: buf1 m01 x Ba ----
    RDA01(A1p); RDB(B1p, 0);
    stBg(0, s0, 0); stBg(0, s0, 1);
    BAR; LGKM0;
    PRIO1; MM8(fa00, fa01, fa10, fa11, cA00, cA01, cA02, cA03,
               cA10, cA11, cA12, cA13); PRIO0;
    BAR;
    // ---- P6: buf1 m23 x Ba ----
    RDA23(A1p);
    stBa(1, s1, 0); stBa(1, s1, 1);
    BAR; LGKM0;
    PRIO1; MM8(fa20, fa21, fa30, fa31, cA20, cA21, cA22, cA23,
               cA30, cA31, cA32, cA33); PRIO0;
    BAR;
    // ---- P7: buf1 m01 x Bg ----
    RDB(B1p, 8192);
    stA(1, s1, 0); stA(1, s1, 1);
    BAR; LGKM0;
    PRIO1; MM8(fa00, fa01, fa10, fa11, cG00, cG01, cG02, cG03,
               cG10, cG11, cG12, cG13); PRIO0;
    BAR;
    // ---- P8: buf1 m23 x Bg ----
    stA(1, s1, 2); stA(1, s1, 3);
    BAR;
    PRIO1; MM8(fa20, fa21, fa30, fa31, cG20, cG21, cG22, cG23,
               cG30, cG31, cG32, cG33); PRIO0;
    VM6; BAR;
  }

  int colBase = bn0 + wn * 64;
  int rowBase = bm0 + wm * 64 + q * 4;
  EPIN(0, cA00, cG00, cA10, cG10, cA20, cG20, cA30, cG30);
  EPIN(1, cA01, cG01, cA11, cG11, cA21, cG21, cA31, cG31);
  EPIN(2, cA02, cG02, cA12, cG12, cA22, cG22, cA32, cG32);
  EPIN(3, cA03, cG03, cA13, cG13, cA23, cG23, cA33, cG33);
}

extern "C" void kernel_launch(void* const* d_in, const int* in_sizes, int n_in,
                              void* d_out, int out_size, void* d_ws, size_t ws_size,
                              hipStream_t stream) {
  const float* x_in = (const float*)d_in[0];
  const float* ctx  = (const float*)d_in[1];
  const float* ln1g = (const float*)d_in[2];
  const float* ln1b = (const float*)d_in[3];
  const float* ln2g = (const float*)d_in[4];
  const float* ln2b = (const float*)d_in[5];
  const float* ln3g = (const float*)d_in[6];
  const float* ln3b = (const float*)d_in[7];
  const float* Wq1  = (const float*)d_in[8];
  const float* Wk1  = (const float*)d_in[9];
  const float* Wv1  = (const float*)d_in[10];
  const float* Wo1  = (const float*)d_in[11];
  const float* bo1  = (const float*)d_in[12];
  const float* Wq2  = (const float*)d_in[13];
  const float* Wk2  = (const float*)d_in[14];
  const float* Wv2  = (const float*)d_in[15];
  const float* Wo2  = (const float*)d_in[16];
  const float* bo2  = (const float*)d_in[17];
  const float* Wff1 = (const float*)d_in[18];
  const float* bff1 = (const float*)d_in[19];
  const float* Wff2 = (const float*)d_in[20];
  const float* bff2 = (const float*)d_in[21];
  float* out = (float*)d_out;   // also doubles as the fp32 residual stream "xcur"

  const int NR = 8192;   // B*N
  const int C = 1280, H = 20, Nseq = 1024, CC = 768;
  const int MR2 = 616;   // B*M (cross rows)
  const float CS = 0.18033688011112042f;  // 0.125 * log2(e)

  char* ws = (char*)d_ws;
  size_t off = 0;
  auto alloc = [&](size_t bytes) -> void* {
    void* p = ws + off;
    off += (bytes + 255) & ~(size_t)255;
    return p;
  };
  unsigned* scal = (unsigned*)alloc(64);
  // NOTE: Wq1T/Wk1T/Wv1T contiguous (each C*C*2 = 3,276,800, 256-mult) -> WQKV1T [3840][1280]
  ushort* Wq1T  = (ushort*)alloc((size_t)C * C * 2);
  ushort* Wk1T  = (ushort*)alloc((size_t)C * C * 2);
  ushort* Wv1T  = (ushort*)alloc((size_t)C * C * 2);
  ushort* Wo1T  = (ushort*)alloc((size_t)C * C * 2);
  ushort* Wq2T  = (ushort*)alloc((size_t)C * C * 2);
  // Wk2T/Wv2T contiguous (each C*CC*2 = 1,966,080, 256-mult) -> WKV2T [2560][768]
  ushort* Wk2T  = (ushort*)alloc((size_t)C * CC * 2);
  ushort* Wv2T  = (ushort*)alloc((size_t)C * CC * 2);
  ushort* Wo2T  = (ushort*)alloc((size_t)C * C * 2);
  ushort* WF1T  = (ushort*)alloc((size_t)10240 * C * 2);
  ushort* WF2T  = (ushort*)alloc((size_t)C * 5120 * 2);
  ushort* LN    = (ushort*)alloc((size_t)NR * C * 2);   // also AO (attn output)
  size_t regionR = off;  // attention region; stage-3 GG overlays it
  ushort* QKV   = (ushort*)alloc((size_t)NR * 3840 * 2);  // packed Q|K|V, ld=3840
  ushort* VT    = (ushort*)alloc((size_t)160 * 64 * 1024 * 2);
  float2* RS    = (float2*)alloc((size_t)160 * 1024 * 8);
  ushort* CTXB  = (ushort*)alloc((size_t)MR2 * CC * 2);
  ushort* KV2   = (ushort*)alloc((size_t)MR2 * 2560 * 2);  // packed K|V cross, ld=2560
  size_t need = off;
  ushort* AO = LN;                       // alias: LN dead once QKV gemm ran
  ushort* GG = (ushort*)(ws + regionR);  // 84 MB, overlays QKV..KV2 in stage 3
  if (ws_size < need) return;  // diagnostic: absmax==poison => ws too small

  // --- init & weight prep ---
  k_zero<<<1, 64, 0, stream>>>(scal, 8);
  k_wt<<<dim3(40, 40), 256, 0, stream>>>(Wq1, Wq1T, C, C);
  k_wt<<<dim3(40, 40), 256, 0, stream>>>(Wk1, Wk1T, C, C);
  k_wt<<<dim3(40, 40), 256, 0, stream>>>(Wv1, Wv1T, C, C);
  k_wt<<<dim3(40, 40), 256, 0, stream>>>(Wo1, Wo1T, C, C);
  k_wt<<<dim3(40, 40), 256, 0, stream>>>(Wq2, Wq2T, C, C);
  k_wt<<<dim3(40, 24), 256, 0, stream>>>(Wk2, Wk2T, CC, C);
  k_wt<<<dim3(40, 24), 256, 0, stream>>>(Wv2, Wv2T, CC, C);
  k_wt<<<dim3(40, 40), 256, 0, stream>>>(Wo2, Wo2T, C, C);
  k_wt<<<dim3(320, 40), 256, 0, stream>>>(Wff1, WF1T, C, 10240);
  k_wt<<<dim3(40, 160), 256, 0, stream>>>(Wff2, WF2T, 5120, C);

  // ================= stage 1: self-attention =================
  k_ln<<<NR, 256, 0, stream>>>(x_in, ln1g, ln1b, LN);
  // fused Q|K|V gemm: N=3840, grid 960 (93.75% CU util vs 62.5% for 3x320)
  k_gemm8<<<dim3(960), 512, 0, stream>>>(LN, C, Wq1T, C, nullptr, QKV, 3840,
                                         nullptr, nullptr, scal + 0, NR, 3840, C, 1280);
  k_quant8<<<(NR * 3840 / 8 + 255) / 256, 256, 0, stream>>>(QKV, QKV, scal + 0,
                                                            NR * 480, 480, 3840, 1280);
  k_vt<<<dim3(16, 160), 256, 0, stream>>>(QKV + 2560, VT, H, 1024, 1024, 3840);
  k_attn1<<<dim3(8, 160), 256, 0, stream>>>(QKV, QKV + 1280, RS, scal + 3,
                                            H, Nseq, 1024, 3840, 3840, CS);
  k_attn2<<<dim3(8, 160), 256, 0, stream>>>(QKV, QKV + 1280, VT, RS, scal + 3, AO,
                                            H, Nseq, 1024, 1024, 3840, 3840, CS);
  k_gemm8<<<dim3(320), 512, 0, stream>>>(AO, C, Wo1T, C, out, nullptr, C,
                                         bo1, x_in, nullptr, NR, C, C, C);

  // ================= stage 2: cross-attention =================
  k_ln<<<NR, 256, 0, stream>>>(out, ln2g, ln2b, LN);
  k_gemm8<<<dim3(320), 512, 0, stream>>>(LN, C, Wq2T, C, nullptr, QKV, 3840,
                                         nullptr, nullptr, scal + 4, NR, C, C, C);
  k_quant8<<<(NR * C / 8 + 255) / 256, 256, 0, stream>>>(QKV, QKV, scal + 4,
                                                         NR * 160, 160, 3840, 1280);
  k_cvt<<<(MR2 * CC + 255) / 256, 256, 0, stream>>>(ctx, CTXB, MR2 * CC);
  // fused K|V cross gemm: N=2560
  k_gemm<<<dim3(20, 5), 256, 0, stream>>>(CTXB, CC, Wk2T, CC, nullptr, KV2, 2560,
                                          nullptr, nullptr, scal + 5, MR2, 2560, CC, 1280);
  k_quant8<<<(MR2 * 2560 / 8 + 255) / 256, 256, 0, stream>>>(KV2, KV2, scal + 5,
                                                             MR2 * 320, 320, 2560, 1280);
  k_vt<<<dim3(2, 160), 256, 0, stream>>>(KV2 + 1280, VT, H, 77, 128, 2560);
  k_attn1<<<dim3(8, 160), 256, 0, stream>>>(QKV, KV2, RS, scal + 7,
                                            H, Nseq, 77, 3840, 2560, CS);
  k_attn2<<<dim3(8, 160), 256, 0, stream>>>(QKV, KV2, VT, RS, scal + 7, AO,
                                            H, Nseq, 77, 128, 3840, 2560, CS);
  k_gemm8<<<dim3(320), 512, 0, stream>>>(AO, C, Wo2T, C, out, nullptr, C,
                                         bo2, out, nullptr, NR, C, C, C);

  // ================= stage 3: GEGLU FF (fused, 8-phase) =================
  k_ln<<<NR, 256, 0, stream>>>(out, ln3g, ln3b, LN);
  k_ff1_8p<<<dim3(1280), 512, 0, stream>>>(LN, WF1T, bff1, GG);
  k_gemm8<<<dim3(320), 512, 0, stream>>>(GG, 5120, WF2T, 5120, out, nullptr, C,
                                         bff2, out, nullptr, NR, C, 5120, C);
}

// Round 8
// 1467.913 us; speedup vs baseline: 1.3168x; 1.0516x over previous
//
#include <hip/hip_runtime.h>

typedef __attribute__((ext_vector_type(8))) short bf16x8;
typedef __attribute__((ext_vector_type(4))) float f32x4;

#define DEV __device__ __forceinline__
#define MF(A, B, CACC) CACC = __builtin_amdgcn_mfma_f32_16x16x32_bf16(A, B, CACC, 0, 0, 0)

DEV ushort f2b(float f) {
  unsigned u = __float_as_uint(f);
  u += 0x7fffu + ((u >> 16) & 1u);   // RNE to bf16
  return (ushort)(u >> 16);
}
DEV float b2f(ushort u) { return __uint_as_float(((unsigned)u) << 16); }

// async global->LDS, 16B per lane; lds base must be wave-uniform (HW adds lane*16)
DEV void gl_lds16(ushort* lds_base, const ushort* gp) {
  __builtin_amdgcn_global_load_lds(
      (__attribute__((address_space(1))) const void*)gp,
      (__attribute__((address_space(3))) void*)lds_base, 16, 0, 0);
}

// sym fake-quant of 8 bf16 in an int4 (bit-identical to the old k_quant8 path)
DEV int4 q8v(int4 val, float dq) {
  ushort* p = (ushort*)&val;
  #pragma unroll
  for (int j = 0; j < 8; j++) {
    float x = b2f(p[j]);
    float y = fminf(fmaxf(rintf(x / dq), -128.f), 127.f) * dq;
    p[j] = f2b(y);
  }
  return val;
}

// ------------- batched weight transpose fp32 W[K][N] -> bf16 WT[N][K] -------------
struct WtJobs {
  const float* W[10];
  ushort* WT[10];
  int Kd[10], Nd[10], nbx[10], bend[10];
};
__global__ __launch_bounds__(256) void k_wtb(WtJobs jb, unsigned* scal) {
  if (blockIdx.x == 0 && threadIdx.x < 8) scal[threadIdx.x] = 0u;
  int bid = blockIdx.x;
  int i = 0;
  while (bid >= jb.bend[i]) i++;
  int base = i ? jb.bend[i - 1] : 0;
  int local = bid - base;
  int nbx = jb.nbx[i];
  int k0 = (local / nbx) * 32, n0 = (local % nbx) * 32;
  const float* __restrict__ W = jb.W[i];
  ushort* __restrict__ WT = jb.WT[i];
  int K = jb.Kd[i], N = jb.Nd[i];
  __shared__ float T[32][33];
  int tx = threadIdx.x & 31, ty = threadIdx.x >> 5;
  #pragma unroll
  for (int r = ty; r < 32; r += 8) {
    int k = k0 + r, n = n0 + tx;
    T[r][tx] = (k < K && n < N) ? W[(size_t)k * N + n] : 0.f;
  }
  __syncthreads();
  #pragma unroll
  for (int r = ty; r < 32; r += 8) {
    int n = n0 + r, k = k0 + tx;
    if (n < N && k < K) WT[(size_t)n * K + k] = f2b(T[tx][r]);
  }
}

// ---------------- f32 -> bf16 elementwise ----------------
__global__ void k_cvt(const float* __restrict__ in, ushort* __restrict__ out, int n) {
  int i = blockIdx.x * 256 + threadIdx.x;
  if (i < n) out[i] = f2b(in[i]);
}

// ---------------- layernorm (C==1280), out bf16 ----------------
__global__ __launch_bounds__(256) void k_ln(const float* __restrict__ x,
    const float* __restrict__ g, const float* __restrict__ b,
    ushort* __restrict__ out) {
  const int C = 1280;
  int row = blockIdx.x, tid = threadIdx.x;
  const float* xr = x + (size_t)row * C;
  float v0 = xr[tid], v1 = xr[tid + 256], v2 = xr[tid + 512],
        v3 = xr[tid + 768], v4 = xr[tid + 1024];
  float s = v0 + v1 + v2 + v3 + v4;
  float ss = v0 * v0 + v1 * v1 + v2 * v2 + v3 * v3 + v4 * v4;
  #pragma unroll
  for (int off = 32; off; off >>= 1) {
    s += __shfl_down(s, off);
    ss += __shfl_down(ss, off);
  }
  __shared__ float red[8];
  __shared__ float mu_s, rstd_s;
  int wave = tid >> 6, lane = tid & 63;
  if (lane == 0) { red[wave] = s; red[4 + wave] = ss; }
  __syncthreads();
  if (tid == 0) {
    float S = red[0] + red[1] + red[2] + red[3];
    float SS = red[4] + red[5] + red[6] + red[7];
    float mu = S / C;
    float var = SS / C - mu * mu;
    mu_s = mu;
    rstd_s = rsqrtf(var + 1e-5f);
  }
  __syncthreads();
  float mu = mu_s, rstd = rstd_s;
  size_t o = (size_t)row * C + tid;
  out[o]        = f2b((v0 - mu) * rstd * g[tid]        + b[tid]);
  out[o + 256]  = f2b((v1 - mu) * rstd * g[tid + 256]  + b[tid + 256]);
  out[o + 512]  = f2b((v2 - mu) * rstd * g[tid + 512]  + b[tid + 512]);
  out[o + 768]  = f2b((v3 - mu) * rstd * g[tid + 768]  + b[tid + 768]);
  out[o + 1024] = f2b((v4 - mu) * rstd * g[tid + 1024] + b[tid + 1024]);
}

// ---- GEMM epilogue helpers (by-value f32x4, constant swizzles: SROA-proof) ----
DEV void st1(float v, int r_, int c_, int ldc, const float* resid,
             float* Cf, ushort* Cb) {
  size_t o = (size_t)r_ * ldc + c_;
  if (resid) v += resid[o];
  if (Cf) Cf[o] = v;
  if (Cb) Cb[o] = f2b(v);
}
DEV float epi4(f32x4 v, int rbase, int c_, int M, int N, int ldc,
               const float* bias, const float* resid, float* Cf, ushort* Cb) {
  float v0 = v.x, v1 = v.y, v2 = v.z, v3 = v.w;
  float am = fmaxf(fmaxf(fabsf(v0), fabsf(v1)), fmaxf(fabsf(v2), fabsf(v3)));
  if (c_ < N) {
    float bb = bias ? bias[c_] : 0.f;
    v0 += bb; v1 += bb; v2 += bb; v3 += bb;
    if (rbase + 0 < M) st1(v0, rbase + 0, c_, ldc, resid, Cf, Cb);
    if (rbase + 1 < M) st1(v1, rbase + 1, c_, ldc, resid, Cf, Cb);
    if (rbase + 2 < M) st1(v2, rbase + 2, c_, ldc, resid, Cf, Cb);
    if (rbase + 3 < M) st1(v3, rbase + 3, c_, ldc, resid, Cf, Cb);
  }
  return am;
}

// ---------------- bf16 NT GEMM: C[M,N] = A[M,K] @ BT[N,K]^T ----------------
// 128x128 tile, 4 waves (2x2 of 64x64), 16x16x32 MFMA, BK=32,
// global_load_lds width=16 staging. Used for odd-shaped (M=616) GEMMs.
__global__ __launch_bounds__(256) void k_gemm(
    const ushort* __restrict__ A, int lda,
    const ushort* __restrict__ BT, int ldb,
    float* __restrict__ Cf, ushort* __restrict__ Cb, int ldc,
    const float* __restrict__ bias, const float* __restrict__ resid,
    unsigned* am_slot, int M, int N, int K, int slcN) {
  __shared__ __align__(16) ushort SAB[8192];  // A[128][32] @0, B[128][32] @4096
  int tid = threadIdx.x;
  int wave = tid >> 6, lane = tid & 63;
  int q = lane >> 4, mi = lane & 15;
  int wr = (wave >> 1) * 64, wc = (wave & 1) * 64;
  int bm0 = blockIdx.y * 128, bn0 = blockIdx.x * 128;
  f32x4 c00 = {}, c01 = {}, c02 = {}, c03 = {};
  f32x4 c10 = {}, c11 = {}, c12 = {}, c13 = {};
  f32x4 c20 = {}, c21 = {}, c22 = {}, c23 = {};
  f32x4 c30 = {}, c31 = {}, c32 = {}, c33 = {};
  for (int k0 = 0; k0 < K; k0 += 32) {
    __syncthreads();
    #pragma unroll
    for (int t = 0; t < 4; t++) {
      int c = wave * 256 + t * 64 + lane;
      const ushort* gp;
      if (c < 512) {
        int r = c >> 2, kc = (c & 3) << 3;
        int gr = bm0 + r; if (gr >= M) gr = M - 1;
        gp = A + (size_t)gr * lda + k0 + kc;
      } else {
        int c2 = c - 512;
        int r = c2 >> 2, kc = (c2 & 3) << 3;
        int gn = bn0 + r; if (gn >= N) gn = N - 1;
        gp = BT + (size_t)gn * ldb + k0 + kc;
      }
      gl_lds16(&SAB[(wave * 256 + t * 64) * 8], gp);
    }
    __syncthreads();
    const ushort* Ab = &SAB[(wr + mi) * 32 + q * 8];
    const ushort* Bb = &SAB[4096 + (wc + mi) * 32 + q * 8];
    bf16x8 a0 = *(const bf16x8*)(Ab);
    bf16x8 a1 = *(const bf16x8*)(Ab + 512);
    bf16x8 a2 = *(const bf16x8*)(Ab + 1024);
    bf16x8 a3 = *(const bf16x8*)(Ab + 1536);
    bf16x8 b0 = *(const bf16x8*)(Bb);
    bf16x8 b1 = *(const bf16x8*)(Bb + 512);
    bf16x8 b2 = *(const bf16x8*)(Bb + 1024);
    bf16x8 b3 = *(const bf16x8*)(Bb + 1536);
    MF(a0, b0, c00); MF(a0, b1, c01); MF(a0, b2, c02); MF(a0, b3, c03);
    MF(a1, b0, c10); MF(a1, b1, c11); MF(a1, b2, c12); MF(a1, b3, c13);
    MF(a2, b0, c20); MF(a2, b1, c21); MF(a2, b2, c22); MF(a2, b3, c23);
    MF(a3, b0, c30); MF(a3, b1, c31); MF(a3, b2, c32); MF(a3, b3, c33);
  }
  int rb = bm0 + wr + q * 4, cb = bn0 + wc + mi;
  float am = 0.f;
  am = fmaxf(am, epi4(c00, rb +  0, cb +  0, M, N, ldc, bias, resid, Cf, Cb));
  am = fmaxf(am, epi4(c01, rb +  0, cb + 16, M, N, ldc, bias, resid, Cf, Cb));
  am = fmaxf(am, epi4(c02, rb +  0, cb + 32, M, N, ldc, bias, resid, Cf, Cb));
  am = fmaxf(am, epi4(c03, rb +  0, cb + 48, M, N, ldc, bias, resid, Cf, Cb));
  am = fmaxf(am, epi4(c10, rb + 16, cb +  0, M, N, ldc, bias, resid, Cf, Cb));
  am = fmaxf(am, epi4(c11, rb + 16, cb + 16, M, N, ldc, bias, resid, Cf, Cb));
  am = fmaxf(am, epi4(c12, rb + 16, cb + 32, M, N, ldc, bias, resid, Cf, Cb));
  am = fmaxf(am, epi4(c13, rb + 16, cb + 48, M, N, ldc, bias, resid, Cf, Cb));
  am = fmaxf(am, epi4(c20, rb + 32, cb +  0, M, N, ldc, bias, resid, Cf, Cb));
  am = fmaxf(am, epi4(c21, rb + 32, cb + 16, M, N, ldc, bias, resid, Cf, Cb));
  am = fmaxf(am, epi4(c22, rb + 32, cb + 32, M, N, ldc, bias, resid, Cf, Cb));
  am = fmaxf(am, epi4(c23, rb + 32, cb + 48, M, N, ldc, bias, resid, Cf, Cb));
  am = fmaxf(am, epi4(c30, rb + 48, cb +  0, M, N, ldc, bias, resid, Cf, Cb));
  am = fmaxf(am, epi4(c31, rb + 48, cb + 16, M, N, ldc, bias, resid, Cf, Cb));
  am = fmaxf(am, epi4(c32, rb + 48, cb + 32, M, N, ldc, bias, resid, Cf, Cb));
  am = fmaxf(am, epi4(c33, rb + 48, cb + 48, M, N, ldc, bias, resid, Cf, Cb));
  if (am_slot) {
    #pragma unroll
    for (int off = 32; off; off >>= 1) am = fmaxf(am, __shfl_down(am, off));
    if (lane == 0) atomicMax(am_slot + bn0 / slcN, __float_as_uint(am));
  }
}

// ------- vectorized multi-slice fake-quant: 8 bf16/thread, slot by col -------
__global__ void k_quant8(const ushort* __restrict__ in, ushort* __restrict__ out,
                         const unsigned* __restrict__ slotb, int n8,
                         int colw8, int ld, int slcw) {
  int i = blockIdx.x * 256 + threadIdx.x;
  if (i >= n8) return;
  int row = i / colw8, c8 = i - row * colw8;
  int col = c8 * 8;
  size_t a = (size_t)row * ld + col;
  float delta = fmaxf(__uint_as_float(slotb[col / slcw]), 1e-8f) * (1.f / 127.f);
  bf16x8 v = *(const bf16x8*)(in + a);
  bf16x8 r;
  #pragma unroll
  for (int j = 0; j < 8; j++) {
    float x = b2f((ushort)v[j]);
    float y = fminf(fmaxf(rintf(x / delta), -128.f), 127.f) * delta;
    r[j] = (short)f2b(y);
  }
  *(bf16x8*)(out + a) = r;
}

// ------- V transpose per head + fused quant: vq raw -> vT quantized [bh][d][m] -------
__global__ __launch_bounds__(256) void k_vt(const ushort* __restrict__ vq,
    ushort* __restrict__ vT, const unsigned* __restrict__ slot,
    int H, int Mr, int Mpad, int ldv) {
  __shared__ __align__(16) ushort T[64][72];
  int bh = blockIdx.y, b = bh / H, h = bh % H;
  int m0 = blockIdx.x * 64;
  int tid = threadIdx.x;
  float dq = fmaxf(__uint_as_float(*slot), 1e-8f) * (1.f / 127.f);
  #pragma unroll
  for (int c = tid; c < 512; c += 256) {
    int mm = c >> 3, dc = (c & 7) << 3;
    int m = m0 + mm;
    int4 val = make_int4(0, 0, 0, 0);
    if (m < Mr)
      val = q8v(*(const int4*)(vq + ((size_t)b * Mr + m) * ldv + h * 64 + dc), dq);
    *(int4*)&T[mm][dc] = val;
  }
  __syncthreads();
  #pragma unroll
  for (int c = tid; c < 512; c += 256) {
    int dd = c >> 3, mc = (c & 7) << 3;
    unsigned w0 = (unsigned)T[mc + 0][dd] | ((unsigned)T[mc + 1][dd] << 16);
    unsigned w1 = (unsigned)T[mc + 2][dd] | ((unsigned)T[mc + 3][dd] << 16);
    unsigned w2 = (unsigned)T[mc + 4][dd] | ((unsigned)T[mc + 5][dd] << 16);
    unsigned w3 = (unsigned)T[mc + 6][dd] | ((unsigned)T[mc + 7][dd] << 16);
    int4 val = make_int4((int)w0, (int)w1, (int)w2, (int)w3);
    *(int4*)(vT + ((size_t)bh * 64 + dd) * Mpad + m0 + mc) = val;
  }
}

#define NEGI -3.0e38f
#define VMA4 asm volatile("s_waitcnt vmcnt(4)" ::: "memory")
#define VMA2 asm volatile("s_waitcnt vmcnt(2)" ::: "memory")
#define VMA0 asm volatile("s_waitcnt vmcnt(0)" ::: "memory")
#define LGK0 asm volatile("s_waitcnt lgkmcnt(0)" ::: "memory")
#define RBAR __builtin_amdgcn_s_barrier()

// online-softmax tile update for one 16-row set (per-row math identical to before)
#define ONLUPD(SA, SB, SC, SD, MRUN, ZRUN) do { \
  float e0  = b0_  ? (SA).x * cs : NEGI; \
  float e1  = b1_  ? (SA).y * cs : NEGI; \
  float e2  = b2_  ? (SA).z * cs : NEGI; \
  float e3  = b3_  ? (SA).w * cs : NEGI; \
  float e4  = b4_  ? (SB).x * cs : NEGI; \
  float e5  = b5_  ? (SB).y * cs : NEGI; \
  float e6  = b6_  ? (SB).z * cs : NEGI; \
  float e7  = b7_  ? (SB).w * cs : NEGI; \
  float e8  = b8_  ? (SC).x * cs : NEGI; \
  float e9  = b9_  ? (SC).y * cs : NEGI; \
  float e10 = b10_ ? (SC).z * cs : NEGI; \
  float e11 = b11_ ? (SC).w * cs : NEGI; \
  float e12 = b12_ ? (SD).x * cs : NEGI; \
  float e13 = b13_ ? (SD).y * cs : NEGI; \
  float e14 = b14_ ? (SD).z * cs : NEGI; \
  float e15 = b15_ ? (SD).w * cs : NEGI; \
  float tm = fmaxf(fmaxf(fmaxf(fmaxf(e0, e1), fmaxf(e2, e3)), \
                         fmaxf(fmaxf(e4, e5), fmaxf(e6, e7))), \
                   fmaxf(fmaxf(fmaxf(e8, e9), fmaxf(e10, e11)), \
                         fmaxf(fmaxf(e12, e13), fmaxf(e14, e15)))); \
  float mn = fmaxf(MRUN, tm); \
  float zs = exp2f(e0 - mn)  + exp2f(e1 - mn)  + exp2f(e2 - mn)  + exp2f(e3 - mn) \
           + exp2f(e4 - mn)  + exp2f(e5 - mn)  + exp2f(e6 - mn)  + exp2f(e7 - mn) \
           + exp2f(e8 - mn)  + exp2f(e9 - mn)  + exp2f(e10 - mn) + exp2f(e11 - mn) \
           + exp2f(e12 - mn) + exp2f(e13 - mn) + exp2f(e14 - mn) + exp2f(e15 - mn); \
  ZRUN = ZRUN * exp2f(MRUN - mn) + zs; MRUN = mn; \
} while (0)

// ------- attention phase 1, QBLK=128, gl_lds16 K staging (2-deep, swizzled) -------
// Swapped QK^T: MF(k, q, s) => lane owns ONE q-row; two 16-row sets per wave.
// Q quantized inline at load (bit-identical to old pre-pass).
__global__ __launch_bounds__(256) void k_attn1(
    const ushort* __restrict__ qq, const ushort* __restrict__ kq,
    float2* __restrict__ rs, unsigned* __restrict__ pmax,
    const unsigned* __restrict__ qslot,
    int H, int N, int Mr, int ldq, int ldk, float cs) {   // cs = scale * log2(e)
  __shared__ __align__(16) ushort Qs[128][72];
  __shared__ __align__(16) ushort KL[2][4096];
  int tid = threadIdx.x;
  int wave = tid >> 6, lane = tid & 63;
  int q = lane >> 4, mi = lane & 15;
  int bh = blockIdx.y, b = bh / H, h = bh % H;
  int r0 = blockIdx.x * 128;
  float dqq = fmaxf(__uint_as_float(*qslot), 1e-8f) * (1.f / 127.f);
  #pragma unroll
  for (int c = tid; c < 1024; c += 256) {
    int r = c >> 3, dc = (c & 7) << 3;
    int4 val = *(const int4*)(qq + ((size_t)b * N + r0 + r) * ldq + h * 64 + dc);
    *(int4*)&Qs[r][dc] = q8v(val, dqq);
  }
  int lr8 = lane >> 3;                    // 0..7 (row within 8-row stripe)
  int ck = (lane & 7) ^ lr8;              // inverse-swizzled source chunk
  const ushort* kbase = kq + (size_t)b * Mr * ldk + h * 64 + ck * 8;
  auto stK = [&](int mt, int bb) {
    #pragma unroll
    for (int c = 0; c < 2; c++) {
      int base8 = c * 4 + wave;
      int m = mt * 64 + base8 * 8 + lr8; if (m >= Mr) m = Mr - 1;
      gl_lds16(&KL[bb][base8 * 512], kbase + (size_t)m * ldk);
    }
  };
  int nt = (Mr + 63) >> 6;
  stK(0, 0);
  if (nt > 1) { stK(1, 1); VMA2; } else VMA0;
  LGK0;   // own Q ds_writes done
  RBAR;   // all waves' Q writes + tile0 visible

  float m0r = NEGI, z0r = 0.f, m1r = NEGI, z1r = 0.f;
  int co0 = (q ^ (mi & 7)) * 8;           // kc=0 swizzled elem offset
  int co1 = ((4 + q) ^ (mi & 7)) * 8;     // kc=1
  for (int mt = 0; mt < nt; mt++) {
    const ushort* KB = &KL[mt & 1][0];
    f32x4 s0 = {}, s1 = {}, s2 = {}, s3 = {};
    f32x4 s4 = {}, s5 = {}, s6 = {}, s7 = {};
    #pragma unroll
    for (int kc = 0; kc < 2; kc++) {
      int co = kc ? co1 : co0;
      bf16x8 qv0 = *(const bf16x8*)&Qs[wave * 32 + mi][kc * 32 + q * 8];
      bf16x8 qv1 = *(const bf16x8*)&Qs[wave * 32 + 16 + mi][kc * 32 + q * 8];
      bf16x8 k0v = *(const bf16x8*)&KB[mi * 64 + co];
      bf16x8 k1v = *(const bf16x8*)&KB[(16 + mi) * 64 + co];
      bf16x8 k2v = *(const bf16x8*)&KB[(32 + mi) * 64 + co];
      bf16x8 k3v = *(const bf16x8*)&KB[(48 + mi) * 64 + co];
      MF(k0v, qv0, s0); MF(k1v, qv0, s1); MF(k2v, qv0, s2); MF(k3v, qv0, s3);
      MF(k0v, qv1, s4); MF(k1v, qv1, s5); MF(k2v, qv1, s6); MF(k3v, qv1, s7);
    }
    int kb = mt * 64 + q * 4;
    bool b0_  = kb + 0  < Mr, b1_  = kb + 1  < Mr, b2_  = kb + 2  < Mr, b3_  = kb + 3  < Mr;
    bool b4_  = kb + 16 < Mr, b5_  = kb + 17 < Mr, b6_  = kb + 18 < Mr, b7_  = kb + 19 < Mr;
    bool b8_  = kb + 32 < Mr, b9_  = kb + 33 < Mr, b10_ = kb + 34 < Mr, b11_ = kb + 35 < Mr;
    bool b12_ = kb + 48 < Mr, b13_ = kb + 49 < Mr, b14_ = kb + 50 < Mr, b15_ = kb + 51 < Mr;
    ONLUPD(s0, s1, s2, s3, m0r, z0r);
    ONLUPD(s4, s5, s6, s7, m1r, z1r);
    RBAR;                                   // all waves done reading buf (mt&1)
    if (mt + 2 < nt) { stK(mt + 2, mt & 1); VMA2; }
    else VMA0;
    RBAR;                                   // tile mt+1 ready for everyone
  }
  // cross-q combine (4 lanes share a q-row: lane, lane^16, lane^32, lane^48)
  float mo0 = fmaxf(m0r, __shfl_xor(m0r, 16));
  mo0 = fmaxf(mo0, __shfl_xor(mo0, 32));
  float zz0 = z0r * exp2f(m0r - mo0);
  zz0 += __shfl_xor(zz0, 16);
  zz0 += __shfl_xor(zz0, 32);
  float mo1 = fmaxf(m1r, __shfl_xor(m1r, 16));
  mo1 = fmaxf(mo1, __shfl_xor(mo1, 32));
  float zz1 = z1r * exp2f(m1r - mo1);
  zz1 += __shfl_xor(zz1, 16);
  zz1 += __shfl_xor(zz1, 32);
  if (q == 0) {
    float2 st; st.x = mo0; st.y = zz0;
    rs[(size_t)bh * N + r0 + wave * 32 + mi] = st;
    st.x = mo1; st.y = zz1;
    rs[(size_t)bh * N + r0 + wave * 32 + 16 + mi] = st;
  }
  float pm = fmaxf(1.f / zz0, 1.f / zz1);
  #pragma unroll
  for (int off = 32; off; off >>= 1) pm = fmaxf(pm, __shfl_down(pm, off));
  if (lane == 0) atomicMax(pmax, __float_as_uint(pm));
}

// quantized-prob level: q8 = min(rint(2^(s*cs - mc)), 255), exact in bf16 via shift
DEV ushort q8lvl(float s, float cs, float mc) {
  float p = fminf(rintf(exp2f(fmaf(s, cs, -mc))), 255.f);
  return (ushort)(__float_as_uint(p) >> 16);
}

#define PWR(RB, SA, SB, SC, SD, M0_, M1_, M2_, M3_) do { \
  Ps[(RB) + 0][mi]      = ok0 ? q8lvl((SA).x, cs, M0_) : (ushort)0; \
  Ps[(RB) + 1][mi]      = ok0 ? q8lvl((SA).y, cs, M1_) : (ushort)0; \
  Ps[(RB) + 2][mi]      = ok0 ? q8lvl((SA).z, cs, M2_) : (ushort)0; \
  Ps[(RB) + 3][mi]      = ok0 ? q8lvl((SA).w, cs, M3_) : (ushort)0; \
  Ps[(RB) + 0][16 + mi] = ok1 ? q8lvl((SB).x, cs, M0_) : (ushort)0; \
  Ps[(RB) + 1][16 + mi] = ok1 ? q8lvl((SB).y, cs, M1_) : (ushort)0; \
  Ps[(RB) + 2][16 + mi] = ok1 ? q8lvl((SB).z, cs, M2_) : (ushort)0; \
  Ps[(RB) + 3][16 + mi] = ok1 ? q8lvl((SB).w, cs, M3_) : (ushort)0; \
  Ps[(RB) + 0][32 + mi] = ok2 ? q8lvl((SC).x, cs, M0_) : (ushort)0; \
  Ps[(RB) + 1][32 + mi] = ok2 ? q8lvl((SC).y, cs, M1_) : (ushort)0; \
  Ps[(RB) + 2][32 + mi] = ok2 ? q8lvl((SC).z, cs, M2_) : (ushort)0; \
  Ps[(RB) + 3][32 + mi] = ok2 ? q8lvl((SC).w, cs, M3_) : (ushort)0; \
  Ps[(RB) + 0][48 + mi] = ok3 ? q8lvl((SD).x, cs, M0_) : (ushort)0; \
  Ps[(RB) + 1][48 + mi] = ok3 ? q8lvl((SD).y, cs, M1_) : (ushort)0; \
  Ps[(RB) + 2][48 + mi] = ok3 ? q8lvl((SD).z, cs, M2_) : (ushort)0; \
  Ps[(RB) + 3][48 + mi] = ok3 ? q8lvl((SD).w, cs, M3_) : (ushort)0; \
} while (0)

#define OSTORE(RRBASE, OA, OB, OC, OD) do { \
  size_t base = ((size_t)b * N + (RRBASE)) * C + h * 64 + mi; \
  ao[base]              = f2b((OA).x * delta); ao[base + C]          = f2b((OA).y * delta); \
  ao[base + 2 * C]      = f2b((OA).z * delta); ao[base + 3 * C]      = f2b((OA).w * delta); \
  ao[base + 16]         = f2b((OB).x * delta); ao[base + C + 16]     = f2b((OB).y * delta); \
  ao[base + 2 * C + 16] = f2b((OB).z * delta); ao[base + 3 * C + 16] = f2b((OB).w * delta); \
  ao[base + 32]         = f2b((OC).x * delta); ao[base + C + 32]     = f2b((OC).y * delta); \
  ao[base + 2 * C + 32] = f2b((OC).z * delta); ao[base + 3 * C + 32] = f2b((OC).w * delta); \
  ao[base + 48]         = f2b((OD).x * delta); ao[base + C + 48]     = f2b((OD).y * delta); \
  ao[base + 2 * C + 48] = f2b((OD).z * delta); ao[base + 3 * C + 48] = f2b((OD).w * delta); \
} while (0)

// ------- attention phase 2, QBLK=128, gl_lds16 K+V staging (2-deep, swizzled) -------
__global__ __launch_bounds__(256) void k_attn2(
    const ushort* __restrict__ qq, const ushort* __restrict__ kq,
    const ushort* __restrict__ vT, const float2* __restrict__ rs,
    const unsigned* __restrict__ pmax, const unsigned* __restrict__ qslot,
    ushort* __restrict__ ao,
    int H, int N, int Mr, int Mpad, int ldq, int ldk, float cs) {
  const int C = 1280;
  __shared__ __align__(16) ushort Qs[128][72];
  __shared__ __align__(16) ushort Ps[128][72];
  __shared__ __align__(16) ushort KL[2][4096];
  __shared__ __align__(16) ushort VL[2][4096];
  int tid = threadIdx.x;
  int wave = tid >> 6, lane = tid & 63;
  int q = lane >> 4, mi = lane & 15;
  int bh = blockIdx.y, b = bh / H, h = bh % H;
  int r0 = blockIdx.x * 128;
  float dqq = fmaxf(__uint_as_float(*qslot), 1e-8f) * (1.f / 127.f);
  #pragma unroll
  for (int c = tid; c < 1024; c += 256) {
    int r = c >> 3, dc = (c & 7) << 3;
    int4 val = *(const int4*)(qq + ((size_t)b * N + r0 + r) * ldq + h * 64 + dc);
    *(int4*)&Qs[r][dc] = q8v(val, dqq);
  }
  int lr8 = lane >> 3;
  int ck = (lane & 7) ^ lr8;
  const ushort* kbase = kq + (size_t)b * Mr * ldk + h * 64 + ck * 8;
  const ushort* vbase = vT + ((size_t)bh * 64) * Mpad + ck * 8;
  auto stKV = [&](int mt, int bb) {
    #pragma unroll
    for (int c = 0; c < 2; c++) {
      int base8 = c * 4 + wave;
      int rloc = base8 * 8 + lr8;
      int m = mt * 64 + rloc; if (m >= Mr) m = Mr - 1;
      gl_lds16(&KL[bb][base8 * 512], kbase + (size_t)m * ldk);
      gl_lds16(&VL[bb][base8 * 512], vbase + (size_t)rloc * Mpad + mt * 64);
    }
  };
  int rb0 = wave * 32 + q * 4, rb1 = rb0 + 16;
  float delta = fmaxf(__uint_as_float(*pmax), 1e-8f) * (1.f / 255.f);
  float ldl = __log2f(delta);
  float2 u0 = rs[(size_t)bh * N + r0 + rb0 + 0];
  float2 u1 = rs[(size_t)bh * N + r0 + rb0 + 1];
  float2 u2 = rs[(size_t)bh * N + r0 + rb0 + 2];
  float2 u3 = rs[(size_t)bh * N + r0 + rb0 + 3];
  float2 u4 = rs[(size_t)bh * N + r0 + rb1 + 0];
  float2 u5 = rs[(size_t)bh * N + r0 + rb1 + 1];
  float2 u6 = rs[(size_t)bh * N + r0 + rb1 + 2];
  float2 u7 = rs[(size_t)bh * N + r0 + rb1 + 3];
  float mc0 = u0.x + __log2f(u0.y) + ldl;
  float mc1 = u1.x + __log2f(u1.y) + ldl;
  float mc2 = u2.x + __log2f(u2.y) + ldl;
  float mc3 = u3.x + __log2f(u3.y) + ldl;
  float mc4 = u4.x + __log2f(u4.y) + ldl;
  float mc5 = u5.x + __log2f(u5.y) + ldl;
  float mc6 = u6.x + __log2f(u6.y) + ldl;
  float mc7 = u7.x + __log2f(u7.y) + ldl;
  int nt = (Mr + 63) >> 6;
  stKV(0, 0);
  if (nt > 1) { stKV(1, 1); VMA4; } else VMA0;
  LGK0;
  RBAR;

  f32x4 o0 = {}, o1 = {}, o2 = {}, o3 = {};
  f32x4 o4 = {}, o5 = {}, o6 = {}, o7 = {};
  int co0 = (q ^ (mi & 7)) * 8;
  int co1 = ((4 + q) ^ (mi & 7)) * 8;
  for (int mt = 0; mt < nt; mt++) {
    const ushort* KB = &KL[mt & 1][0];
    const ushort* VB = &VL[mt & 1][0];
    f32x4 s0 = {}, s1 = {}, s2 = {}, s3 = {};
    f32x4 s4 = {}, s5 = {}, s6 = {}, s7 = {};
    #pragma unroll
    for (int kc = 0; kc < 2; kc++) {
      int co = kc ? co1 : co0;
      bf16x8 aq0 = *(const bf16x8*)&Qs[wave * 32 + mi][kc * 32 + q * 8];
      bf16x8 aq1 = *(const bf16x8*)&Qs[wave * 32 + 16 + mi][kc * 32 + q * 8];
      bf16x8 k0v = *(const bf16x8*)&KB[mi * 64 + co];
      bf16x8 k1v = *(const bf16x8*)&KB[(16 + mi) * 64 + co];
      bf16x8 k2v = *(const bf16x8*)&KB[(32 + mi) * 64 + co];
      bf16x8 k3v = *(const bf16x8*)&KB[(48 + mi) * 64 + co];
      MF(aq0, k0v, s0); MF(aq0, k1v, s1); MF(aq0, k2v, s2); MF(aq0, k3v, s3);
      MF(aq1, k0v, s4); MF(aq1, k1v, s5); MF(aq1, k2v, s6); MF(aq1, k3v, s7);
    }
    int mlim = Mr - mt * 64;
    bool ok0 = (mi      < mlim);
    bool ok1 = (16 + mi < mlim);
    bool ok2 = (32 + mi < mlim);
    bool ok3 = (48 + mi < mlim);
    PWR(rb0, s0, s1, s2, s3, mc0, mc1, mc2, mc3);
    PWR(rb1, s4, s5, s6, s7, mc4, mc5, mc6, mc7);
    // wave-local RAW through LDS: rows 32w..32w+31 written & read by wave w only.
    LGK0;
    __builtin_amdgcn_sched_barrier(0);
    #pragma unroll
    for (int kc = 0; kc < 2; kc++) {
      int co = kc ? co1 : co0;
      bf16x8 ap0 = *(const bf16x8*)&Ps[wave * 32 + mi][kc * 32 + q * 8];
      bf16x8 ap1 = *(const bf16x8*)&Ps[wave * 32 + 16 + mi][kc * 32 + q * 8];
      bf16x8 v0 = *(const bf16x8*)&VB[mi * 64 + co];
      bf16x8 v1 = *(const bf16x8*)&VB[(16 + mi) * 64 + co];
      bf16x8 v2 = *(const bf16x8*)&VB[(32 + mi) * 64 + co];
      bf16x8 v3 = *(const bf16x8*)&VB[(48 + mi) * 64 + co];
      MF(ap0, v0, o0); MF(ap0, v1, o1); MF(ap0, v2, o2); MF(ap0, v3, o3);
      MF(ap1, v0, o4); MF(ap1, v1, o5); MF(ap1, v2, o6); MF(ap1, v3, o7);
    }
    RBAR;                                   // all waves done reading buf (mt&1)
    if (mt + 2 < nt) { stKV(mt + 2, mt & 1); VMA4; }
    else VMA0;
    RBAR;                                   // tile mt+1 ready for everyone
  }
  int rr0 = r0 + wave * 32 + q * 4;
  OSTORE(rr0, o0, o1, o2, o3);
  OSTORE(rr0 + 16, o4, o5, o6, o7);
}

// =====================================================================
// shared pipeline macros (T2 xor-swizzle + counted vmcnt + setprio)
// =====================================================================
#define BAR __builtin_amdgcn_s_barrier()
#define LGKM0 do { asm volatile("s_waitcnt lgkmcnt(0)" ::: "memory"); \
                   __builtin_amdgcn_sched_barrier(0); } while (0)
#define VM6 asm volatile("s_waitcnt vmcnt(6)" ::: "memory")
#define VM0 asm volatile("s_waitcnt vmcnt(0)" ::: "memory")
#define PRIO1 __builtin_amdgcn_s_setprio(1)
#define PRIO0 __builtin_amdgcn_s_setprio(0)

#define RDA01(P) do { \
  fa00 = *(const bf16x8*)&(P)[c0];        fa01 = *(const bf16x8*)&(P)[c1]; \
  fa10 = *(const bf16x8*)&(P)[1024 + c0]; fa11 = *(const bf16x8*)&(P)[1024 + c1]; } while (0)
#define RDA23(P) do { \
  fa20 = *(const bf16x8*)&(P)[2048 + c0]; fa21 = *(const bf16x8*)&(P)[2048 + c1]; \
  fa30 = *(const bf16x8*)&(P)[3072 + c0]; fa31 = *(const bf16x8*)&(P)[3072 + c1]; } while (0)
#define RDB(P, H) do { \
  b00 = *(const bf16x8*)&(P)[(H) + c0];        b01 = *(const bf16x8*)&(P)[(H) + c1]; \
  b10 = *(const bf16x8*)&(P)[(H) + 1024 + c0]; b11 = *(const bf16x8*)&(P)[(H) + 1024 + c1]; \
  b20 = *(const bf16x8*)&(P)[(H) + 2048 + c0]; b21 = *(const bf16x8*)&(P)[(H) + 2048 + c1]; \
  b30 = *(const bf16x8*)&(P)[(H) + 3072 + c0]; b31 = *(const bf16x8*)&(P)[(H) + 3072 + c1]; } while (0)
#define RDB8(P) RDB(P, 0)

#define MM8(AX0, AX1, AY0, AY1, C0, C1, C2, C3, D0, D1, D2, D3) \
  MF(AX0, b00, C0); MF(AX1, b01, C0); MF(AX0, b10, C1); MF(AX1, b11, C1); \
  MF(AX0, b20, C2); MF(AX1, b21, C2); MF(AX0, b30, C3); MF(AX1, b31, C3); \
  MF(AY0, b00, D0); MF(AY1, b01, D0); MF(AY0, b10, D1); MF(AY1, b11, D1); \
  MF(AY0, b20, D2); MF(AY1, b21, D2); MF(AY0, b30, D3); MF(AY1, b31, D3)

// =====================================================================
// k_gemm8: 8-wave 256x128-tile NT GEMM, BK=64, TRIPLE-buffered LDS (144 KiB),
// 2 phases/K-tile of 16 MFMA, counted vmcnt(6) (never 0 in main loop).
// Requires M%256==0, N%128==0, K%64==0, K/64>=5, (K/64-2)%3==0, blocks%8==0.
// =====================================================================
#define GB8(AP, BP, DB, KT) \
  RDA01(AP); RDB8(BP); \
  stB(DB, KT, 0); stB(DB, KT, 1); stA(DB, KT, 0); \
  BAR; LGKM0; \
  PRIO1; MM8(fa00, fa01, fa10, fa11, c00, c01, c02, c03, c10, c11, c12, c13); PRIO0; \
  BAR; \
  RDA23(AP); \
  stA(DB, KT, 1); stA(DB, KT, 2); stA(DB, KT, 3); \
  BAR; LGKM0; \
  PRIO1; MM8(fa20, fa21, fa30, fa31, c20, c21, c22, c23, c30, c31, c32, c33); PRIO0; \
  VM6; BAR;

#define GT8(AP, BP) \
  RDA01(AP); RDB8(BP); \
  BAR; LGKM0; \
  PRIO1; MM8(fa00, fa01, fa10, fa11, c00, c01, c02, c03, c10, c11, c12, c13); PRIO0; \
  BAR; \
  RDA23(AP); \
  BAR; LGKM0; \
  PRIO1; MM8(fa20, fa21, fa30, fa31, c20, c21, c22, c23, c30, c31, c32, c33); PRIO0;

__global__ __launch_bounds__(512) void k_gemm8(
    const ushort* __restrict__ A, int lda,
    const ushort* __restrict__ BT, int ldb,
    float* __restrict__ Cf, ushort* __restrict__ Cb, int ldc,
    const float* __restrict__ bias, const float* __restrict__ resid,
    unsigned* am_slot, int M, int N, int K, int slcN) {
  // per buf (24576 ushorts): A[256][64] @0, B[128][64] @16384. Swizzle: col ^= (row&7)*8.
  __shared__ __align__(16) ushort SAB[73728];  // 144 KiB, 3 bufs
  int tid = threadIdx.x;
  int wave = tid >> 6, lane = tid & 63;
  int q = lane >> 4, mi = lane & 15;
  int wm = wave >> 1, wn = wave & 1;
  int lr = lane >> 3;
  int lc = ((lane & 7) ^ lr) * 8;   // inverse-swizzled source col (elems)

  int NBN = N >> 7;
  int nblk = (M >> 8) * NBN;
  int cpx = nblk >> 3;
  int wg = blockIdx.x;
  int swz = (wg & 7) * cpx + (wg >> 3);   // bijective: nblk % 8 == 0
  int bm0 = (swz / NBN) << 8, bn0 = (swz % NBN) << 7;

  const int swzr = (mi & 7) * 8;
  int c0 = (q * 8) ^ swzr, c1 = (32 + q * 8) ^ swzr;
  const ushort* A0p = &SAB[(wm * 64 + mi) * 64];
  const ushort* B0p = &SAB[16384 + (wn * 64 + mi) * 64];
  const ushort* A1p = A0p + 24576; const ushort* B1p = B0p + 24576;
  const ushort* A2p = A0p + 49152; const ushort* B2p = B0p + 49152;

  const ushort* gA = A  + (size_t)(bm0 + wave * 8 + lr) * lda + lc;
  const ushort* gB = BT + (size_t)(bn0 + wave * 8 + lr) * ldb + lc;
  ushort* lA = &SAB[wave * 512];
  ushort* lB = &SAB[16384 + wave * 512];

  auto stA = [&](int bb, int kt, int call) {   // A: 4 calls x 64 rows
    gl_lds16(lA + bb * 24576 + call * 4096,
             gA + (size_t)call * 64 * lda + (size_t)kt * 64);
  };
  auto stB = [&](int bb, int kt, int call) {   // B: 2 calls x 64 rows
    gl_lds16(lB + bb * 24576 + call * 4096,
             gB + (size_t)call * 64 * ldb + (size_t)kt * 64);
  };

  f32x4 c00 = {}, c01 = {}, c02 = {}, c03 = {};
  f32x4 c10 = {}, c11 = {}, c12 = {}, c13 = {};
  f32x4 c20 = {}, c21 = {}, c22 = {}, c23 = {};
  f32x4 c30 = {}, c31 = {}, c32 = {}, c33 = {};
  bf16x8 fa00, fa01, fa10, fa11, fa20, fa21, fa30, fa31;
  bf16x8 b00, b01, b10, b11, b20, b21, b30, b31;

  // prologue: tile0 -> buf0, tile1 -> buf1 (6 calls each)
  stB(0, 0, 0); stB(0, 0, 1);
  stA(0, 0, 0); stA(0, 0, 1); stA(0, 0, 2); stA(0, 0, 3);
  stB(1, 1, 0); stB(1, 1, 1);
  stA(1, 1, 0); stA(1, 1, 1); stA(1, 1, 2); stA(1, 1, 3);
  VM6; BAR;

  int NT = K >> 6, NTm = NT - 2;  // NTm % 3 == 0 by contract
  for (int t = 0; t < NTm; t += 3) {
    GB8(A0p, B0p, 2, t + 2);
    GB8(A1p, B1p, 0, t + 3);
    GB8(A2p, B2p, 1, t + 4);
  }
  // tail: tile NT-2 (buf0), then tile NT-1 (buf1)
  GT8(A0p, B0p);
  VM0; BAR;
  GT8(A1p, B1p);

  int rb = bm0 + wm * 64 + q * 4, cb = bn0 + wn * 64 + mi;
  float am = 0.f;
  am = fmaxf(am, epi4(c00, rb +  0, cb +  0, M, N, ldc, bias, resid, Cf, Cb));
  am = fmaxf(am, epi4(c01, rb +  0, cb + 16, M, N, ldc, bias, resid, Cf, Cb));
  am = fmaxf(am, epi4(c02, rb +  0, cb + 32, M, N, ldc, bias, resid, Cf, Cb));
  am = fmaxf(am, epi4(c03, rb +  0, cb + 48, M, N, ldc, bias, resid, Cf, Cb));
  am = fmaxf(am, epi4(c10, rb + 16, cb +  0, M, N, ldc, bias, resid, Cf, Cb));
  am = fmaxf(am, epi4(c11, rb + 16, cb + 16, M, N, ldc, bias, resid, Cf, Cb));
  am = fmaxf(am, epi4(c12, rb + 16, cb + 32, M, N, ldc, bias, resid, Cf, Cb));
  am = fmaxf(am, epi4(c13, rb + 16, cb + 48, M, N, ldc, bias, resid, Cf, Cb));
  am = fmaxf(am, epi4(c20, rb + 32, cb +  0, M, N, ldc, bias, resid, Cf, Cb));
  am = fmaxf(am, epi4(c21, rb + 32, cb + 16, M, N, ldc, bias, resid, Cf, Cb));
  am = fmaxf(am, epi4(c22, rb + 32, cb + 32, M, N, ldc, bias, resid, Cf, Cb));
  am = fmaxf(am, epi4(c23, rb + 32, cb + 48, M, N, ldc, bias, resid, Cf, Cb));
  am = fmaxf(am, epi4(c30, rb + 48, cb +  0, M, N, ldc, bias, resid, Cf, Cb));
  am = fmaxf(am, epi4(c31, rb + 48, cb + 16, M, N, ldc, bias, resid, Cf, Cb));
  am = fmaxf(am, epi4(c32, rb + 48, cb + 32, M, N, ldc, bias, resid, Cf, Cb));
  am = fmaxf(am, epi4(c33, rb + 48, cb + 48, M, N, ldc, bias, resid, Cf, Cb));
  if (am_slot) {
    #pragma unroll
    for (int off = 32; off; off >>= 1) am = fmaxf(am, __shfl_down(am, off));
    if (lane == 0) atomicMax(am_slot + bn0 / slcN, __float_as_uint(am));
  }
}

// =====================================================================
// fused FF1 + GEGLU, 256x128(GG) tile, BK=64, 8 waves, 8-phase schedule
// =====================================================================
// gelu-tanh via sigmoid identity: 0.5*(1+tanh(x)) == sigmoid(2x)
DEV ushort ggel(float a, float g) {
  float u = 1.5957691216057308f * g * (1.f + 0.044715f * g * g);
  float s = 1.f / (1.f + __expf(-u));
  return f2b(a * g * s);
}
DEV void epi4g(f32x4 va, f32x4 vg, size_t base, float ba, float bg,
               ushort* __restrict__ GG) {
  GG[base]         = ggel(va.x + ba, vg.x + bg);
  GG[base + 5120]  = ggel(va.y + ba, vg.y + bg);
  GG[base + 10240] = ggel(va.z + ba, vg.z + bg);
  GG[base + 15360] = ggel(va.w + ba, vg.w + bg);
}
#define EPIN(nn, P0, Q0, P1, Q1, P2, Q2, P3, Q3) do { \
  int cg = colBase + nn * 16 + mi; \
  float ba = bias[cg], bg = bias[5120 + cg]; \
  size_t b0_ = (size_t)rowBase * 5120 + cg; \
  epi4g(P0, Q0, b0_,             ba, bg, GG); \
  epi4g(P1, Q1, b0_ + 16 * 5120, ba, bg, GG); \
  epi4g(P2, Q2, b0_ + 32 * 5120, ba, bg, GG); \
  epi4g(P3, Q3, b0_ + 48 * 5120, ba, bg, GG); \
} while (0)

__global__ __launch_bounds__(512) void k_ff1_8p(
    const ushort* __restrict__ A,    // LN [8192][1280]
    const ushort* __restrict__ BT,   // WF1T [10240][1280]
    const float* __restrict__ bias,  // bff1 [10240]
    ushort* __restrict__ GG) {       // [8192][5120]
  __shared__ __align__(16) ushort SAB[65536];  // 128 KiB
  int tid = threadIdx.x;
  int wave = tid >> 6, lane = tid & 63;
  int q = lane >> 4, mi = lane & 15;
  int wm = wave >> 1, wn = wave & 1;
  int lr = lane >> 3;
  int lc = ((lane & 7) ^ lr) * 8;  // inverse-swizzled source col (elems)

  int wg = blockIdx.x;
  int swz = (wg & 7) * 160 + (wg >> 3);
  int bm0 = (swz & 31) * 256, bn0 = (swz >> 5) * 128;

  const int swzr = (mi & 7) * 8;
  int c0 = (q * 8) ^ swzr, c1 = (32 + q * 8) ^ swzr;
  const ushort* A0p = &SAB[(wm * 64 + mi) * 64];
  const ushort* B0p = &SAB[16384 + (wn * 64 + mi) * 64];
  const ushort* A1p = A0p + 32768;
  const ushort* B1p = B0p + 32768;

  const ushort* gA  = A  + (size_t)(bm0 + wave * 8 + lr) * 1280 + lc;
  const ushort* gBa = BT + (size_t)(bn0 + wave * 8 + lr) * 1280 + lc;
  const ushort* gBg = BT + (size_t)(5120 + bn0 + wave * 8 + lr) * 1280 + lc;
  ushort* lA = &SAB[wave * 512];
  ushort* lB = &SAB[16384 + wave * 512];

  auto stA = [&](int bb, int kt, int call) {
    gl_lds16(lA + bb * 32768 + call * 4096,
             gA + (size_t)call * 81920 + (size_t)kt * 64);
  };
  auto stBa = [&](int bb, int kt, int call) {
    gl_lds16(lB + bb * 32768 + call * 4096,
             gBa + (size_t)call * 81920 + (size_t)kt * 64);
  };
  auto stBg = [&](int bb, int kt, int call) {
    gl_lds16(lB + bb * 32768 + (call + 2) * 4096,
             gBg + (size_t)call * 81920 + (size_t)kt * 64);
  };

  f32x4 cA00 = {}, cA01 = {}, cA02 = {}, cA03 = {};
  f32x4 cA10 = {}, cA11 = {}, cA12 = {}, cA13 = {};
  f32x4 cA20 = {}, cA21 = {}, cA22 = {}, cA23 = {};
  f32x4 cA30 = {}, cA31 = {}, cA32 = {}, cA33 = {};
  f32x4 cG00 = {}, cG01 = {}, cG02 = {}, cG03 = {};
  f32x4 cG10 = {}, cG11 = {}, cG12 = {}, cG13 = {};
  f32x4 cG20 = {}, cG21 = {}, cG22 = {}, cG23 = {};
  f32x4 cG30 = {}, cG31 = {}, cG32 = {}, cG33 = {};
  bf16x8 fa00, fa01, fa10, fa11, fa20, fa21, fa30, fa31;
  bf16x8 b00, b01, b10, b11, b20, b21, b30, b31;

  stBa(0, 0, 0); stBa(0, 0, 1); stBg(0, 0, 0); stBg(0, 0, 1);
  stA(0, 0, 0); stA(0, 0, 1); stA(0, 0, 2); stA(0, 0, 3);
  stBa(1, 1, 0); stBa(1, 1, 1);
  stA(1, 1, 0); stA(1, 1, 1); stA(1, 1, 2); stA(1, 1, 3);
  VM6; BAR;

  for (int it = 0; it < 10; ++it) {
    int t1 = 2 * it + 1;
    int s0 = t1 + 1; if (s0 > 19) s0 = 19;
    int s1 = t1 + 2; if (s1 > 19) s1 = 19;
    // ---- P1: buf0 m01 x Ba ----
    RDA01(A0p); RDB(B0p, 0);
    stBg(1, t1, 0); stBg(1, t1, 1);
    BAR; LGKM0;
    PRIO1; MM8(fa00, fa01, fa10, fa11, cA00, cA01, cA02, cA03,
               cA10, cA11, cA12, cA13); PRIO0;
    BAR;
    // ---- P2: buf0 m23 x Ba ----
    RDA23(A0p);
    stBa(0, s0, 0); stBa(0, s0, 1);
    BAR; LGKM0;
    PRIO1; MM8(fa20, fa21, fa30, fa31, cA20, cA21, cA22, cA23,
               cA30, cA31, cA32, cA33); PRIO0;
    BAR;
    // ---- P3: buf0 m01 x Bg ----
    RDB(B0p, 8192);
    stA(0, s0, 0); stA(0, s0, 1);
    BAR; LGKM0;
    PRIO1; MM8(fa00, fa01, fa10, fa11, cG00, cG01, cG02, cG03,
               cG10, cG11, cG12, cG13); PRIO0;
    BAR;
    // ---- P4: buf0 m23 x Bg ----
    stA(0, s0, 2); stA(0, s0, 3);
    BAR;
    PRIO1; MM8(fa20, fa21, fa30, fa31, cG20, cG21, cG22, cG23,
               cG30, cG31, cG32, cG33); PRIO0;
    VM6; BAR;
    // ---- P5: buf1 m01 x Ba ----
    RDA01(A1p); RDB(B1p, 0);
    stBg(0, s0, 0); stBg(0, s0, 1);
    BAR; LGKM0;
    PRIO1; MM8(fa00, fa01, fa10, fa11, cA00, cA01, cA02, cA03,
               cA10, cA11, cA12, cA13); PRIO0;
    BAR;
    // ---- P6: buf1 m23 x Ba ----
    RDA23(A1p);
    stBa(1, s1, 0); stBa(1, s1, 1);
    BAR; LGKM0;
    PRIO1; MM8(fa20, fa21, fa30, fa31, cA20, cA21, cA22, cA23,
               cA30, cA31, cA32, cA33); PRIO0;
    BAR;
    // ---- P7: buf1 m01 x Bg ----
    RDB(B1p, 8192);
    stA(1, s1, 0); stA(1, s1, 1);
    BAR; LGKM0;
    PRIO1; MM8(fa00, fa01, fa10, fa11, cG00, cG01, cG02, cG03,
               cG10, cG11, cG12, cG13); PRIO0;
    BAR;
    // ---- P8: buf1 m23 x Bg ----
    stA(1, s1, 2); stA(1, s1, 3);
    BAR;
    PRIO1; MM8(fa20, fa21, fa30, fa31, cG20, cG21, cG22, cG23,
               cG30, cG31, cG32, cG33); PRIO0;
    VM6; BAR;
  }

  int colBase = bn0 + wn * 64;
  int rowBase = bm0 + wm * 64 + q * 4;
  EPIN(0, cA00, cG00, cA10, cG10, cA20, cG20, cA30, cG30);
  EPIN(1, cA01, cG01, cA11, cG11, cA21, cG21, cA31, cG31);
  EPIN(2, cA02, cG02, cA12, cG12, cA22, cG22, cA32, cG32);
  EPIN(3, cA03, cG03, cA13, cG13, cA23, cG23, cA33, cG33);
}

extern "C" void kernel_launch(void* const* d_in, const int* in_sizes, int n_in,
                              void* d_out, int out_size, void* d_ws, size_t ws_size,
                              hipStream_t stream) {
  const float* x_in = (const float*)d_in[0];
  const float* ctx  = (const float*)d_in[1];
  const float* ln1g = (const float*)d_in[2];
  const float* ln1b = (const float*)d_in[3];
  const float* ln2g = (const float*)d_in[4];
  const float* ln2b = (const float*)d_in[5];
  const float* ln3g = (const float*)d_in[6];
  const float* ln3b = (const float*)d_in[7];
  const float* Wq1  = (const float*)d_in[8];
  const float* Wk1  = (const float*)d_in[9];
  const float* Wv1  = (const float*)d_in[10];
  const float* Wo1  = (const float*)d_in[11];
  const float* bo1  = (const float*)d_in[12];
  const float* Wq2  = (const float*)d_in[13];
  const float* Wk2  = (const float*)d_in[14];
  const float* Wv2  = (const float*)d_in[15];
  const float* Wo2  = (const float*)d_in[16];
  const float* bo2  = (const float*)d_in[17];
  const float* Wff1 = (const float*)d_in[18];
  const float* bff1 = (const float*)d_in[19];
  const float* Wff2 = (const float*)d_in[20];
  const float* bff2 = (const float*)d_in[21];
  float* out = (float*)d_out;   // also doubles as the fp32 residual stream "xcur"

  const int NR = 8192;   // B*N
  const int C = 1280, H = 20, Nseq = 1024, CC = 768;
  const int MR2 = 616;   // B*M (cross rows)
  const float CS = 0.18033688011112042f;  // 0.125 * log2(e)

  char* ws = (char*)d_ws;
  size_t off = 0;
  auto alloc = [&](size_t bytes) -> void* {
    void* p = ws + off;
    off += (bytes + 255) & ~(size_t)255;
    return p;
  };
  unsigned* scal = (unsigned*)alloc(64);
  // NOTE: Wq1T/Wk1T/Wv1T contiguous (each C*C*2 = 3,276,800, 256-mult) -> WQKV1T [3840][1280]
  ushort* Wq1T  = (ushort*)alloc((size_t)C * C * 2);
  ushort* Wk1T  = (ushort*)alloc((size_t)C * C * 2);
  ushort* Wv1T  = (ushort*)alloc((size_t)C * C * 2);
  ushort* Wo1T  = (ushort*)alloc((size_t)C * C * 2);
  ushort* Wq2T  = (ushort*)alloc((size_t)C * C * 2);
  // Wk2T/Wv2T contiguous (each C*CC*2 = 1,966,080, 256-mult) -> WKV2T [2560][768]
  ushort* Wk2T  = (ushort*)alloc((size_t)C * CC * 2);
  ushort* Wv2T  = (ushort*)alloc((size_t)C * CC * 2);
  ushort* Wo2T  = (ushort*)alloc((size_t)C * C * 2);
  ushort* WF1T  = (ushort*)alloc((size_t)10240 * C * 2);
  ushort* WF2T  = (ushort*)alloc((size_t)C * 5120 * 2);
  ushort* LN    = (ushort*)alloc((size_t)NR * C * 2);   // also AO (attn output)
  size_t regionR = off;  // attention region; stage-3 GG overlays it
  ushort* QKV   = (ushort*)alloc((size_t)NR * 3840 * 2);  // packed Q|K|V, ld=3840
  ushort* VT    = (ushort*)alloc((size_t)160 * 64 * 1024 * 2);
  float2* RS    = (float2*)alloc((size_t)160 * 1024 * 8);
  ushort* CTXB  = (ushort*)alloc((size_t)MR2 * CC * 2);
  ushort* KV2   = (ushort*)alloc((size_t)MR2 * 2560 * 2);  // packed K|V cross, ld=2560
  size_t need = off;
  ushort* AO = LN;                       // alias: LN dead once QKV gemm ran
  ushort* GG = (ushort*)(ws + regionR);  // 84 MB, overlays QKV..KV2 in stage 3
  if (ws_size < need) return;  // diagnostic: absmax==poison => ws too small

  // --- init & weight prep: ONE batched launch (replaces k_zero + 10x k_wt) ---
  WtJobs jb;
  auto setj = [&](int i, const float* W, ushort* WT, int K, int N) {
    jb.W[i] = W; jb.WT[i] = WT; jb.Kd[i] = K; jb.Nd[i] = N;
    jb.nbx[i] = (N + 31) / 32;
    int nb = jb.nbx[i] * ((K + 31) / 32);
    jb.bend[i] = (i ? jb.bend[i - 1] : 0) + nb;
  };
  setj(0, Wq1, Wq1T, C, C);
  setj(1, Wk1, Wk1T, C, C);
  setj(2, Wv1, Wv1T, C, C);
  setj(3, Wo1, Wo1T, C, C);
  setj(4, Wq2, Wq2T, C, C);
  setj(5, Wk2, Wk2T, CC, C);
  setj(6, Wv2, Wv2T, CC, C);
  setj(7, Wo2, Wo2T, C, C);
  setj(8, Wff1, WF1T, C, 10240);
  setj(9, Wff2, WF2T, 5120, C);
  k_wtb<<<dim3(jb.bend[9]), 256, 0, stream>>>(jb, scal);

  // ================= stage 1: self-attention =================
  k_ln<<<NR, 256, 0, stream>>>(x_in, ln1g, ln1b, LN);
  // fused Q|K|V gemm: N=3840, grid 960 (93.75% CU util vs 62.5% for 3x320)
  k_gemm8<<<dim3(960), 512, 0, stream>>>(LN, C, Wq1T, C, nullptr, QKV, 3840,
                                         nullptr, nullptr, scal + 0, NR, 3840, C, 1280);
  // quantize only the K slice in memory (Q inline in attn, V inline in k_vt)
  k_quant8<<<(NR * 160 + 255) / 256, 256, 0, stream>>>(QKV + 1280, QKV + 1280, scal + 1,
                                                       NR * 160, 160, 3840, 1280);
  k_vt<<<dim3(16, 160), 256, 0, stream>>>(QKV + 2560, VT, scal + 2, H, 1024, 1024, 3840);
  k_attn1<<<dim3(8, 160), 256, 0, stream>>>(QKV, QKV + 1280, RS, scal + 3, scal + 0,
                                            H, Nseq, 1024, 3840, 3840, CS);
  k_attn2<<<dim3(8, 160), 256, 0, stream>>>(QKV, QKV + 1280, VT, RS, scal + 3, scal + 0,
                                            AO, H, Nseq, 1024, 1024, 3840, 3840, CS);
  k_gemm8<<<dim3(320), 512, 0, stream>>>(AO, C, Wo1T, C, out, nullptr, C,
                                         bo1, x_in, nullptr, NR, C, C, C);

  // ================= stage 2: cross-attention =================
  k_ln<<<NR, 256, 0, stream>>>(out, ln2g, ln2b, LN);
  k_gemm8<<<dim3(320), 512, 0, stream>>>(LN, C, Wq2T, C, nullptr, QKV, 3840,
                                         nullptr, nullptr, scal + 4, NR, C, C, C);
  k_cvt<<<(MR2 * CC + 255) / 256, 256, 0, stream>>>(ctx, CTXB, MR2 * CC);
  // fused K|V cross gemm: N=2560
  k_gemm<<<dim3(20, 5), 256, 0, stream>>>(CTXB, CC, Wk2T, CC, nullptr, KV2, 2560,
                                          nullptr, nullptr, scal + 5, MR2, 2560, CC, 1280);
  // quantize only the K slice of KV2 (V inline in k_vt, Q inline in attn)
  k_quant8<<<(MR2 * 160 + 255) / 256, 256, 0, stream>>>(KV2, KV2, scal + 5,
                                                        MR2 * 160, 160, 2560, 1280);
  k_vt<<<dim3(2, 160), 256, 0, stream>>>(KV2 + 1280, VT, scal + 6, H, 77, 128, 2560);
  k_attn1<<<dim3(8, 160), 256, 0, stream>>>(QKV, KV2, RS, scal + 7, scal + 4,
                                            H, Nseq, 77, 3840, 2560, CS);
  k_attn2<<<dim3(8, 160), 256, 0, stream>>>(QKV, KV2, VT, RS, scal + 7, scal + 4,
                                            AO, H, Nseq, 77, 128, 3840, 2560, CS);
  k_gemm8<<<dim3(320), 512, 0, stream>>>(AO, C, Wo2T, C, out, nullptr, C,
                                         bo2, out, nullptr, NR, C, C, C);

  // ================= stage 3: GEGLU FF (fused, 8-phase) =================
  k_ln<<<NR, 256, 0, stream>>>(out, ln3g, ln3b, LN);
  k_ff1_8p<<<dim3(1280), 512, 0, stream>>>(LN, WF1T, bff1, GG);
  k_gemm8<<<dim3(320), 512, 0, stream>>>(GG, 5120, WF2T, 5120, out, nullptr, C,
                                         bff2, out, nullptr, NR, C, 5120, C);
}